// Round 11
// baseline (3240.547 us; speedup 1.0000x reference)
//
#include <hip/hip_runtime.h>
#include <math.h>

#define D_    2048
#define H_    16
#define DH_   128
#define FF_   8192
#define PFF_  1024
#define B_    2
#define T_    2048
#define NTOK_ 4096
#define T2_   1024
#define NSEL_ 2048
#define EPS_  1e-6f
#define SCALE_QK 0.08838834764831845f  // 1/sqrt(128)

typedef __attribute__((ext_vector_type(8))) short bf16x8;
typedef __attribute__((ext_vector_type(4))) float f32x4;
typedef __attribute__((ext_vector_type(16))) float f32x16;
typedef __attribute__((ext_vector_type(8))) unsigned short ushort8;

__device__ __forceinline__ float silu_f(float x) {
    return x / (1.0f + expf(-x));
}

__device__ __forceinline__ unsigned short bf16_rne(float f) {
    unsigned int u = __float_as_uint(f);
    unsigned int r = (u + 0x7fffu + ((u >> 16) & 1u)) >> 16;
    return (unsigned short)r;
}
__device__ __forceinline__ float bf16_tof(unsigned short h) {
    return __uint_as_float(((unsigned int)h) << 16);
}

// ---------------- RMSNorm: one block per row ----------------
__global__ __launch_bounds__(256) void rms_kernel(const float* __restrict__ x,
                                                  const float* __restrict__ w,
                                                  float* __restrict__ out) {
    int row = blockIdx.x;
    int tid = threadIdx.x;
    const float4* xr = (const float4*)(x + (size_t)row * D_);
    float4* orow = (float4*)(out + (size_t)row * D_);
    const float4* w4 = (const float4*)w;
    float4 v0 = xr[tid], v1 = xr[tid + 256];
    float s = v0.x*v0.x + v0.y*v0.y + v0.z*v0.z + v0.w*v0.w
            + v1.x*v1.x + v1.y*v1.y + v1.z*v1.z + v1.w*v1.w;
    __shared__ float red[256];
    red[tid] = s; __syncthreads();
    for (int off = 128; off > 0; off >>= 1) {
        if (tid < off) red[tid] += red[tid + off];
        __syncthreads();
    }
    float r = 1.0f / sqrtf(red[0] * (1.0f/2048.0f) + EPS_);
    float4 w0 = w4[tid], w1 = w4[tid + 256];
    float4 o0, o1;
    o0.x = v0.x*r*w0.x; o0.y = v0.y*r*w0.y; o0.z = v0.z*r*w0.z; o0.w = v0.w*r*w0.w;
    o1.x = v1.x*r*w1.x; o1.y = v1.y*r*w1.y; o1.z = v1.z*r*w1.z; o1.w = v1.w*r*w1.w;
    orow[tid] = o0; orow[tid + 256] = o1;
}

// ---------------- weight transpose+split: B[K][N] f32 -> Phi(/Plo)[k/8][n][8] bf16 ----------------
template<int WLO>
__global__ __launch_bounds__(256) void splitw_kernel(const float* __restrict__ W,
                                                     unsigned short* __restrict__ phi,
                                                     unsigned short* __restrict__ plo,
                                                     int K, int N) {
    __shared__ float Ts[64][68];
    int n0 = blockIdx.x << 6, k0 = blockIdx.y << 6;
    int tid = threadIdx.x;
#pragma unroll
    for (int it = 0; it < 4; ++it) {
        int idx = tid + (it << 8);
        int kr = idx >> 4, c4 = idx & 15;
        float4 v = *(const float4*)(W + (size_t)(k0 + kr) * N + n0 + (c4 << 2));
        Ts[kr][c4*4+0] = v.x; Ts[kr][c4*4+1] = v.y; Ts[kr][c4*4+2] = v.z; Ts[kr][c4*4+3] = v.w;
    }
    __syncthreads();
#pragma unroll
    for (int h = 0; h < 2; ++h) {
        int c = tid + (h << 8);              // [0,512)
        int kc = c >> 6, n = c & 63;
        ushort8 hi, lo;
#pragma unroll
        for (int q = 0; q < 8; ++q) {
            float v = Ts[kc*8 + q][n];
            unsigned short hb = bf16_rne(v);
            hi[q] = hb;
            if (WLO) lo[q] = bf16_rne(v - bf16_tof(hb));
        }
        size_t off = ((size_t)((k0 >> 3) + kc) * N + (n0 + n)) * 8;
        *(ushort8*)(phi + off) = hi;
        if (WLO) *(ushort8*)(plo + off) = lo;
    }
}

// ---------------- activation split: A[M][K] f32 -> Phi(/Plo)[k/8][m][8] bf16 ----------------
template<int WLO>
__global__ __launch_bounds__(256) void splita_kernel(const float* __restrict__ A,
                                                     unsigned short* __restrict__ phi,
                                                     unsigned short* __restrict__ plo,
                                                     int M, int K) {
    __shared__ float Ts[64][68];
    int m0 = blockIdx.x << 6, k0 = blockIdx.y << 6;
    int tid = threadIdx.x;
#pragma unroll
    for (int it = 0; it < 4; ++it) {
        int idx = tid + (it << 8);
        int mr = idx >> 4, c4 = idx & 15;
        float4 v = *(const float4*)(A + (size_t)(m0 + mr) * K + k0 + (c4 << 2));
        Ts[mr][c4*4+0] = v.x; Ts[mr][c4*4+1] = v.y; Ts[mr][c4*4+2] = v.z; Ts[mr][c4*4+3] = v.w;
    }
    __syncthreads();
#pragma unroll
    for (int h = 0; h < 2; ++h) {
        int c = tid + (h << 8);
        int kc = c >> 6, m = c & 63;
        const float* src = &Ts[m][kc << 3];
        ushort8 hi, lo;
#pragma unroll
        for (int q = 0; q < 8; ++q) {
            float v = src[q];
            unsigned short hb = bf16_rne(v);
            hi[q] = hb;
            if (WLO) lo[q] = bf16_rne(v - bf16_tof(hb));
        }
        size_t off = ((size_t)((k0 >> 3) + kc) * M + (m0 + m)) * 8;
        *(ushort8*)(phi + off) = hi;
        if (WLO) *(ushort8*)(plo + off) = lo;
    }
}

// ---------------- bf16(x3) MFMA GEMM, 128x128 tile, BK=32, 2-phase dbuf, 32x32x16 MFMA ----------------
// Block map: XCD-chunked + column-major decode (B-panel L2 residency).
// EPI 0: C=acc ; 1: C=acc+Rg ; 2: C=silu(Rg)*acc ;
// EPI 3: packed hi/lo panels = silu(Rg)*acc ; EPI 4: packed hi panel only.
__device__ __forceinline__ void stage_panel(unsigned short* lds,
                                            const unsigned short* __restrict__ panel,
                                            int ktile, int R, int brow, int tid) {
#pragma unroll
    for (int h = 0; h < 2; ++h) {
        int c = tid + (h << 8);              // [0,512): kc = c>>7, row = c&127
        const unsigned short* g = panel + ((size_t)((ktile << 2) + (c >> 7)) * R + (brow + (c & 127))) * 8;
        __builtin_amdgcn_global_load_lds((const __attribute__((address_space(1))) void*)g,
                                         (__attribute__((address_space(3))) void*)(lds + (size_t)c * 8),
                                         16, 0, 0);
    }
}

template<int NP, int EPI>
__global__ __launch_bounds__(256) void gemm_mfma(const unsigned short* __restrict__ pah,
                                                 const unsigned short* __restrict__ pal,
                                                 const unsigned short* __restrict__ pbh,
                                                 const unsigned short* __restrict__ pbl,
                                                 float* __restrict__ C,
                                                 const float* __restrict__ Rg,
                                                 unsigned short* __restrict__ Cph,
                                                 unsigned short* __restrict__ Cpl,
                                                 int M, int N, int K) {
    constexpr int NPAN = (NP == 3) ? 2 : 1;
    __shared__ __align__(16) unsigned short As[2][NPAN][4][128][8];
    __shared__ __align__(16) unsigned short Bs[2][NPAN][4][128][8];
    const int tid = threadIdx.x;
    // T1: XCD-aware bijective block swizzle (all grids here have nwg % 8 == 0)
    int nwg = gridDim.x * gridDim.y;
    int wg = blockIdx.y * gridDim.x + blockIdx.x;
    if ((nwg & 7) == 0) {
        int cpx = nwg >> 3;
        wg = (wg & 7) * cpx + (wg >> 3);
    }
    // column-major decode: each XCD chunk = contiguous bn-columns; blocks within
    // a column share one B panel (L2-resident) while streaming A.
    const int bxs = wg / gridDim.y, bys = wg % gridDim.y;
    const int bm = bys << 7, bn = bxs << 7;
    const int lane = tid & 63, wave = tid >> 6;
    const int wm = (wave >> 1) << 6, wn = (wave & 1) << 6;
    const int l31 = lane & 31, l5 = lane >> 5;

    f32x16 acc[2][2];
#pragma unroll
    for (int i = 0; i < 2; ++i)
#pragma unroll
        for (int j = 0; j < 2; ++j) acc[i][j] = (f32x16)0.0f;

    const int nkt = K >> 5;

    // prologue stage tile 0 into buf 0
    stage_panel(&As[0][0][0][0][0], pah, 0, M, bm, tid);
    if (NP == 3) stage_panel(&As[0][1][0][0][0], pal, 0, M, bm, tid);
    stage_panel(&Bs[0][0][0][0][0], pbh, 0, N, bn, tid);
    if (NP == 3) stage_panel(&Bs[0][1][0][0][0], pbl, 0, N, bn, tid);
    __syncthreads();

    int cur = 0;
    for (int kt = 0; kt < nkt; ++kt) {
        // T3 minimum 2-phase: issue next-tile stage BEFORE ds_read+MFMA
        if (kt + 1 < nkt) {
            int nxt = cur ^ 1;
            stage_panel(&As[nxt][0][0][0][0], pah, kt + 1, M, bm, tid);
            if (NP == 3) stage_panel(&As[nxt][1][0][0][0], pal, kt + 1, M, bm, tid);
            stage_panel(&Bs[nxt][0][0][0][0], pbh, kt + 1, N, bn, tid);
            if (NP == 3) stage_panel(&Bs[nxt][1][0][0][0], pbl, kt + 1, N, bn, tid);
        }

        // 32x32x16 fragments: A row = wm + i*32 + l31, k-chunk kc = ks*2 + l5
        bf16x8 ah[2][2], bh[2][2], al[2][2], bl[2][2];
#pragma unroll
        for (int i = 0; i < 2; ++i)
#pragma unroll
            for (int ks = 0; ks < 2; ++ks) {
                int kc = ks * 2 + l5;
                ah[i][ks] = *(const bf16x8*)&As[cur][0][kc][wm + (i << 5) + l31][0];
                if (NP == 3) al[i][ks] = *(const bf16x8*)&As[cur][NPAN-1][kc][wm + (i << 5) + l31][0];
            }
#pragma unroll
        for (int j = 0; j < 2; ++j)
#pragma unroll
            for (int ks = 0; ks < 2; ++ks) {
                int kc = ks * 2 + l5;
                bh[j][ks] = *(const bf16x8*)&Bs[cur][0][kc][wn + (j << 5) + l31][0];
                if (NP == 3) bl[j][ks] = *(const bf16x8*)&Bs[cur][NPAN-1][kc][wn + (j << 5) + l31][0];
            }
#pragma unroll
        for (int i = 0; i < 2; ++i)
#pragma unroll
            for (int j = 0; j < 2; ++j)
#pragma unroll
                for (int ks = 0; ks < 2; ++ks) {
                    acc[i][j] = __builtin_amdgcn_mfma_f32_32x32x16_bf16(ah[i][ks], bh[j][ks], acc[i][j], 0, 0, 0);
                    if (NP == 3) {
                        acc[i][j] = __builtin_amdgcn_mfma_f32_32x32x16_bf16(ah[i][ks], bl[j][ks], acc[i][j], 0, 0, 0);
                        acc[i][j] = __builtin_amdgcn_mfma_f32_32x32x16_bf16(al[i][ks], bh[j][ks], acc[i][j], 0, 0, 0);
                    }
                }
        __syncthreads();   // next-tile stage complete; buf[cur] reads all drained
        cur ^= 1;
    }

    // C/D layout (m74/m101 verified): col = lane&31, row = (r&3) + 8*(r>>2) + 4*(lane>>5)
#pragma unroll
    for (int i = 0; i < 2; ++i)
#pragma unroll
        for (int j = 0; j < 2; ++j) {
            int col = bn + wn + (j << 5) + l31;
#pragma unroll
            for (int r = 0; r < 16; ++r) {
                int row = bm + wm + (i << 5) + (r & 3) + ((r >> 2) << 3) + (l5 << 2);
                size_t off = (size_t)row * N + col;
                float v = acc[i][j][r];
                if (EPI == 0) {
                    C[off] = v;
                } else if (EPI == 1) {
                    C[off] = v + Rg[off];
                } else if (EPI == 2) {
                    C[off] = silu_f(Rg[off]) * v;
                } else {
                    v = silu_f(Rg[off]) * v;
                    unsigned short hb = bf16_rne(v);
                    size_t poff = (((size_t)(col >> 3)) * M + row) * 8 + (col & 7);
                    Cph[poff] = hb;
                    if (EPI == 3) Cpl[poff] = bf16_rne(v - bf16_tof(hb));
                }
            }
        }
}

// ---------------- fused RoPE + scale + hi/lo split ----------------
__global__ __launch_bounds__(256) void rope_split_kernel(const float* __restrict__ X,
                                                         unsigned short* __restrict__ xh,
                                                         unsigned short* __restrict__ xl,
                                                         int seqmask, float scale) {
    int tok = blockIdx.x;
    int tid = threadIdx.x;
    int h = tid >> 4, d0 = (tid & 15) << 3;
    int pos = tok & seqmask;
    const float* src = X + (size_t)tok * D_ + h * DH_;
    bool lohalf = d0 < 64;
    float out[8];
#pragma unroll
    for (int q = 0; q < 8; ++q) {
        int d = d0 + q;
        int i = lohalf ? d : (d - 64);
        float e = (float)(2 * i) * (1.0f / 128.0f);
        float inv = 1.0f / powf(10000.0f, e);
        float ang = (float)pos * inv;
        float c = cosf(ang), s = sinf(ang);
        float x1 = src[i], x2 = src[i + 64];
        out[q] = lohalf ? (x1 * c - x2 * s) : (x2 * c + x1 * s);
    }
    ushort8 hi, lo;
#pragma unroll
    for (int q = 0; q < 8; ++q) {
        float v = out[q] * scale;
        unsigned short hb = bf16_rne(v);
        hi[q] = hb;
        lo[q] = bf16_rne(v - bf16_tof(hb));
    }
    size_t off = (size_t)tok * D_ + h * DH_ + d0;
    *(ushort8*)(xh + off) = hi;
    *(ushort8*)(xl + off) = lo;
}

// ---------------- V pack: f32 [b*T+t][2048] -> Vt[bh][T/8][128][8] bf16 hi/lo ----------------
__global__ __launch_bounds__(256) void vpack_kernel(const float* __restrict__ V,
                                                    unsigned short* __restrict__ vth,
                                                    unsigned short* __restrict__ vtl,
                                                    int T) {
    __shared__ float Ts[64][132];
    int kt = blockIdx.x, bh = blockIdx.y;
    int b = bh >> 4, h = bh & 15;
    int tid = threadIdx.x;
#pragma unroll
    for (int it = 0; it < 8; ++it) {
        int idx = tid + (it << 8);          // [0,2048)
        int r = idx >> 5, c4 = idx & 31;    // r in [0,64), c4 in [0,32)
        float4 v = *(const float4*)(V + ((size_t)(b * T + kt * 64 + r)) * D_ + h * DH_ + (c4 << 2));
        Ts[r][c4*4+0] = v.x; Ts[r][c4*4+1] = v.y; Ts[r][c4*4+2] = v.z; Ts[r][c4*4+3] = v.w;
    }
    __syncthreads();
    size_t obase = ((size_t)bh * (size_t)(T >> 3) + (size_t)kt * 8) * 1024;
#pragma unroll
    for (int it = 0; it < 4; ++it) {
        int c = tid + (it << 8);            // [0,1024): kc = c>>7, dh = c&127
        int kc = c >> 7, dh = c & 127;
        ushort8 hi, lo;
#pragma unroll
        for (int q = 0; q < 8; ++q) {
            float v = Ts[kc * 8 + q][dh];
            unsigned short hb = bf16_rne(v);
            hi[q] = hb;
            lo[q] = bf16_rne(v - bf16_tof(hb));
        }
        *(ushort8*)(vth + obase + (size_t)kc * 1024 + dh * 8) = hi;
        *(ushort8*)(vtl + obase + (size_t)kc * 1024 + dh * 8) = lo;
    }
}

// ---------------- bf16x3 MFMA flash attention ----------------
// grid: (T/64, B_*H_), block 256 (4 waves, each owns 16 q-rows)
__global__ __launch_bounds__(256) void attn_mfma(const unsigned short* __restrict__ QH,
                                                 const unsigned short* __restrict__ QL,
                                                 const unsigned short* __restrict__ KH,
                                                 const unsigned short* __restrict__ KL,
                                                 const unsigned short* __restrict__ VTH,
                                                 const unsigned short* __restrict__ VTL,
                                                 float* __restrict__ O, int T) {
    __shared__ __align__(16) unsigned short KV[16384];
    __shared__ __align__(16) float Ss[4096];
    __shared__ __align__(16) float mrow[64];
    __shared__ __align__(16) float lrow[64];
    __shared__ __align__(16) float crow[64];

    const int tid = threadIdx.x;
    const int qt = blockIdx.x, bh = blockIdx.y;
    const int b = bh >> 4, h = bh & 15;
    const int lane = tid & 63, w = tid >> 6;
    const int fr = lane & 15, fk = lane >> 4;
    const size_t tok0 = (size_t)b * T;

    char* lds_kv = (char*)&KV[0];
    char* lds_sp = (char*)&Ss[0];

    bf16x8 qfh[4], qfl[4];
    {
        const size_t qoff = (tok0 + (size_t)qt * 64 + w * 16 + fr) * D_ + h * DH_ + fk * 8;
#pragma unroll
        for (int ks = 0; ks < 4; ++ks) {
            qfh[ks] = *(const bf16x8*)(QH + qoff + ks * 32);
            qfl[ks] = *(const bf16x8*)(QL + qoff + ks * 32);
        }
    }
    if (tid < 64) { mrow[tid] = -1e30f; lrow[tid] = 0.f; }

    f32x4 acc[8];
#pragma unroll
    for (int nt = 0; nt < 8; ++nt) acc[nt] = (f32x4)0.f;

    const int srow = tid >> 2, sslot = tid & 3;
    const size_t vbase = (size_t)bh * (size_t)(T >> 3) * 1024;

    for (int kt = 0; kt <= qt; ++kt) {
        __syncthreads();
#pragma unroll
        for (int it = 0; it < 4; ++it) {
            int c = tid + (it << 8);
            int t = c >> 4;
            int sp = (c & 15) ^ (t & 7);
            size_t goff = (tok0 + (size_t)kt * 64 + t) * D_ + h * DH_ + sp * 8;
            __builtin_amdgcn_global_load_lds((const __attribute__((address_space(1))) void*)(KH + goff),
                (__attribute__((address_space(3))) void*)(lds_kv + c * 16), 16, 0, 0);
            __builtin_amdgcn_global_load_lds((const __attribute__((address_space(1))) void*)(KL + goff),
                (__attribute__((address_space(3))) void*)(lds_kv + 16384 + c * 16), 16, 0, 0);
        }
        __syncthreads();
        {
            f32x4 s[4];
#pragma unroll
            for (int nt = 0; nt < 4; ++nt) s[nt] = (f32x4)0.f;
#pragma unroll
            for (int ks = 0; ks < 4; ++ks) {
#pragma unroll
                for (int nt = 0; nt < 4; ++nt) {
                    int n = nt * 16 + fr;
                    int offk = (n * 256 + ks * 64 + fk * 16) ^ ((n & 7) << 4);
                    bf16x8 kfh = *(const bf16x8*)(lds_kv + offk);
                    bf16x8 kfl = *(const bf16x8*)(lds_kv + 16384 + offk);
                    s[nt] = __builtin_amdgcn_mfma_f32_16x16x32_bf16(qfh[ks], kfh, s[nt], 0, 0, 0);
                    s[nt] = __builtin_amdgcn_mfma_f32_16x16x32_bf16(qfh[ks], kfl, s[nt], 0, 0, 0);
                    s[nt] = __builtin_amdgcn_mfma_f32_16x16x32_bf16(qfl[ks], kfh, s[nt], 0, 0, 0);
                }
            }
#pragma unroll
            for (int nt = 0; nt < 4; ++nt)
#pragma unroll
                for (int r = 0; r < 4; ++r) {
                    int row = w * 16 + fk * 4 + r;
                    int col = nt * 16 + fr;
                    *(float*)(lds_sp + ((row * 256 + col * 4) ^ ((row & 7) << 4))) = s[nt][r];
                }
        }
        __syncthreads();
#pragma unroll
        for (int it = 0; it < 4; ++it) {
            int c = tid + (it << 8);
            size_t goff = vbase + (size_t)kt * 8192 + (size_t)c * 8;
            __builtin_amdgcn_global_load_lds((const __attribute__((address_space(1))) void*)(VTH + goff),
                (__attribute__((address_space(3))) void*)(lds_kv + c * 16), 16, 0, 0);
            __builtin_amdgcn_global_load_lds((const __attribute__((address_space(1))) void*)(VTL + goff),
                (__attribute__((address_space(3))) void*)(lds_kv + 16384 + c * 16), 16, 0, 0);
        }
        float p[16];
        float newm, psum, cr, oldl;
        {
            float tmax = -1e30f;
            int colbase = sslot * 16;
#pragma unroll
            for (int q4 = 0; q4 < 4; ++q4) {
                f32x4 sv = *(const f32x4*)(lds_sp + ((srow * 256 + sslot * 64 + q4 * 16) ^ ((srow & 7) << 4)));
#pragma unroll
                for (int e = 0; e < 4; ++e) {
                    float v = sv[e];
                    if (kt == qt && (colbase + q4 * 4 + e) > srow) v = -1e30f;
                    p[q4 * 4 + e] = v;
                    tmax = fmaxf(tmax, v);
                }
            }
            tmax = fmaxf(tmax, __shfl_xor(tmax, 1, 64));
            tmax = fmaxf(tmax, __shfl_xor(tmax, 2, 64));
            float oldm = mrow[srow];
            oldl = lrow[srow];
            newm = fmaxf(oldm, tmax);
            psum = 0.f;
#pragma unroll
            for (int e = 0; e < 16; ++e) { p[e] = expf(p[e] - newm); psum += p[e]; }
            psum += __shfl_xor(psum, 1, 64);
            psum += __shfl_xor(psum, 2, 64);
            cr = expf(oldm - newm);
        }
        __syncthreads();
        {
            ushort8 h0, h1, l0, l1;
#pragma unroll
            for (int e = 0; e < 8; ++e) {
                unsigned short hb = bf16_rne(p[e]);
                h0[e] = hb; l0[e] = bf16_rne(p[e] - bf16_tof(hb));
                unsigned short hb2 = bf16_rne(p[8 + e]);
                h1[e] = hb2; l1[e] = bf16_rne(p[8 + e] - bf16_tof(hb2));
            }
            int base = srow * 128 + sslot * 32;
            int swz = (srow & 7) << 4;
            *(ushort8*)(lds_sp + (base ^ swz)) = h0;
            *(ushort8*)(lds_sp + ((base + 16) ^ swz)) = h1;
            *(ushort8*)(lds_sp + 8192 + (base ^ swz)) = l0;
            *(ushort8*)(lds_sp + 8192 + ((base + 16) ^ swz)) = l1;
            if (sslot == 0) { mrow[srow] = newm; lrow[srow] = oldl * cr + psum; crow[srow] = cr; }
        }
        __syncthreads();
        {
            f32x4 crv = *(const f32x4*)&crow[w * 16 + fk * 4];
#pragma unroll
            for (int nt = 0; nt < 8; ++nt)
#pragma unroll
                for (int r = 0; r < 4; ++r) acc[nt][r] *= crv[r];
            int m = w * 16 + fr;
#pragma unroll
            for (int ks = 0; ks < 2; ++ks) {
                int offp = (m * 128 + ks * 64 + fk * 16) ^ ((m & 7) << 4);
                bf16x8 pfh = *(const bf16x8*)(lds_sp + offp);
                bf16x8 pfl = *(const bf16x8*)(lds_sp + 8192 + offp);
#pragma unroll
                for (int nt = 0; nt < 8; ++nt) {
                    int offv = (ks * 4 + fk) * 2048 + (nt * 16 + fr) * 16;
                    bf16x8 vfh = *(const bf16x8*)(lds_kv + offv);
                    bf16x8 vfl = *(const bf16x8*)(lds_kv + 16384 + offv);
                    acc[nt] = __builtin_amdgcn_mfma_f32_16x16x32_bf16(pfh, vfh, acc[nt], 0, 0, 0);
                    acc[nt] = __builtin_amdgcn_mfma_f32_16x16x32_bf16(pfh, vfl, acc[nt], 0, 0, 0);
                    acc[nt] = __builtin_amdgcn_mfma_f32_16x16x32_bf16(pfl, vfh, acc[nt], 0, 0, 0);
                }
            }
        }
    }
    __syncthreads();
    {
        f32x4 lv = *(const f32x4*)&lrow[w * 16 + fk * 4];
        float* orow = O + (tok0 + (size_t)qt * 64 + w * 16 + fk * 4) * D_ + h * DH_;
#pragma unroll
        for (int r = 0; r < 4; ++r) {
            float inv = 1.0f / lv[r];
#pragma unroll
            for (int nt = 0; nt < 8; ++nt)
                orow[(size_t)r * D_ + nt * 16 + fr] = acc[nt][r] * inv;
        }
    }
}

// ---------------- f32 GEMM (fallback path) ----------------
template<int EPI>
__global__ __launch_bounds__(256) void gemm128(const float* __restrict__ A,
                                               const float* __restrict__ Bm,
                                               float* __restrict__ C,
                                               const float* __restrict__ Rg,
                                               int M, int N, int K) {
    __shared__ float Ast[16][132];
    __shared__ float Bs[16][132];
    int bm = blockIdx.y << 7, bn = blockIdx.x << 7;
    int tid = threadIdx.x;
    int ty = tid >> 4, tx = tid & 15;
    float acc[8][8];
#pragma unroll
    for (int i = 0; i < 8; ++i)
#pragma unroll
        for (int j = 0; j < 8; ++j) acc[i][j] = 0.f;

    for (int k0 = 0; k0 < K; k0 += 16) {
#pragma unroll
        for (int it = 0; it < 2; ++it) {
            int idx = tid + (it << 8);
            int ar = idx >> 2, ac = idx & 3;
            float4 av = *(const float4*)(A + (size_t)(bm + ar) * K + k0 + (ac << 2));
            Ast[ac*4+0][ar] = av.x; Ast[ac*4+1][ar] = av.y;
            Ast[ac*4+2][ar] = av.z; Ast[ac*4+3][ar] = av.w;
            int br = idx >> 5, bc = idx & 31;
            float4 bv = *(const float4*)(Bm + (size_t)(k0 + br) * N + bn + (bc << 2));
            *(float4*)&Bs[br][bc << 2] = bv;
        }
        __syncthreads();
#pragma unroll
        for (int kk = 0; kk < 16; ++kk) {
            float a[8], b[8];
            *(float4*)&a[0] = *(const float4*)&Ast[kk][ty*4];
            *(float4*)&a[4] = *(const float4*)&Ast[kk][64 + ty*4];
            *(float4*)&b[0] = *(const float4*)&Bs[kk][tx*4];
            *(float4*)&b[4] = *(const float4*)&Bs[kk][64 + tx*4];
#pragma unroll
            for (int i = 0; i < 8; ++i)
#pragma unroll
                for (int j = 0; j < 8; ++j)
                    acc[i][j] += a[i] * b[j];
        }
        __syncthreads();
    }
#pragma unroll
    for (int i = 0; i < 8; ++i) {
        int row = bm + ((i < 4) ? (ty*4 + i) : (64 + ty*4 + (i - 4)));
#pragma unroll
        for (int half = 0; half < 2; ++half) {
            int col = bn + half*64 + tx*4;
            size_t off = (size_t)row * N + col;
            const float* ap = &acc[i][half*4];
            float4 r;
            if (EPI == 0) {
                r.x = ap[0]; r.y = ap[1]; r.z = ap[2]; r.w = ap[3];
            } else if (EPI == 1) {
                float4 rv = *(const float4*)(Rg + off);
                r.x = ap[0] + rv.x; r.y = ap[1] + rv.y;
                r.z = ap[2] + rv.z; r.w = ap[3] + rv.w;
            } else {
                float4 gv = *(const float4*)(Rg + off);
                r.x = silu_f(gv.x) * ap[0]; r.y = silu_f(gv.y) * ap[1];
                r.z = silu_f(gv.z) * ap[2]; r.w = silu_f(gv.w) * ap[3];
            }
            *(float4*)(C + off) = r;
        }
    }
}

// ---------------- RoPE in place (f32, fallback) ----------------
__global__ __launch_bounds__(256) void rope_kernel(float* __restrict__ q, int nrows, int seqlen) {
    int gid = blockIdx.x * 256 + threadIdx.x;
    int tok = gid >> 10;
    if (tok >= nrows) return;
    int rest = gid & 1023;
    int h = rest >> 6, i = rest & 63;
    int pos = tok % seqlen;
    float e = (float)(2 * i) * (1.0f / 128.0f);
    float inv = 1.0f / powf(10000.0f, e);
    float ang = (float)pos * inv;
    float c = cosf(ang), s = sinf(ang);
    size_t base = (size_t)tok * D_ + h * 128 + i;
    float x1 = q[base], x2 = q[base + 64];
    q[base]      = x1 * c - x2 * s;
    q[base + 64] = x2 * c + x1 * s;
}

// ---------------- flash attention f32 (fallback) ----------------
__global__ __launch_bounds__(256) void attn_kernel(const float* __restrict__ Q,
                                                   const float* __restrict__ K,
                                                   const float* __restrict__ V,
                                                   float* __restrict__ O,
                                                   int T) {
    int qt = blockIdx.x;
    int bh = blockIdx.y;
    int b = bh >> 4, h = bh & 15;
    int tid = threadIdx.x;

    __shared__ float4 Qs[32][32];
    __shared__ float4 KVs[64][32];
    __shared__ float Sst[32][65];
    __shared__ float mrow[32], lrow[32], crow[32];

    const size_t headoff = (size_t)h * DH_;
    const size_t bbase = (size_t)b * T * D_;

#pragma unroll
    for (int i = 0; i < 4; ++i) {
        int idx = tid + i * 256;
        int r = idx >> 5, ch = idx & 31;
        const float4* src = (const float4*)(Q + bbase + (size_t)(qt*32 + r) * D_ + headoff);
        Qs[r][ch ^ ((r >> 2) & 7)] = src[ch];
    }
    if (tid < 32) { mrow[tid] = -1e30f; lrow[tid] = 0.f; }

    int ty16 = tid >> 4, tx16 = tid & 15;
    int r8 = tid >> 3, q8 = tid & 7;
    float o[2][8];
#pragma unroll
    for (int i = 0; i < 2; ++i)
#pragma unroll
        for (int j = 0; j < 8; ++j) o[i][j] = 0.f;

    int ktmax = (qt * 32 + 31) >> 6;
    for (int kt = 0; kt <= ktmax; ++kt) {
        __syncthreads();
#pragma unroll
        for (int i = 0; i < 8; ++i) {
            int idx = tid + i * 256;
            int r = idx >> 5, ch = idx & 31;
            const float4* src = (const float4*)(K + bbase + (size_t)(kt*64 + r) * D_ + headoff);
            KVs[r][ch ^ ((r >> 2) & 7)] = src[ch];
        }
        __syncthreads();
        {
            float s[2][4];
#pragma unroll
            for (int i = 0; i < 2; ++i)
#pragma unroll
                for (int j = 0; j < 4; ++j) s[i][j] = 0.f;
#pragma unroll
            for (int ch = 0; ch < 32; ++ch) {
                float4 qv[2], kv[4];
#pragma unroll
                for (int i = 0; i < 2; ++i) { int r = ty16*2 + i; qv[i] = Qs[r][ch ^ ((r >> 2) & 7)]; }
#pragma unroll
                for (int j = 0; j < 4; ++j) { int c = tx16*4 + j; kv[j] = KVs[c][ch ^ ((c >> 2) & 7)]; }
#pragma unroll
                for (int i = 0; i < 2; ++i)
#pragma unroll
                    for (int j = 0; j < 4; ++j)
                        s[i][j] += qv[i].x*kv[j].x + qv[i].y*kv[j].y + qv[i].z*kv[j].z + qv[i].w*kv[j].w;
            }
#pragma unroll
            for (int i = 0; i < 2; ++i) {
                int grow = qt*32 + ty16*2 + i;
#pragma unroll
                for (int j = 0; j < 4; ++j) {
                    int gcol = kt*64 + tx16*4 + j;
                    float sv = s[i][j] * SCALE_QK;
                    if (gcol > grow) sv = -1e30f;
                    Sst[ty16*2 + i][tx16*4 + j] = sv;
                }
            }
        }
        __syncthreads();
#pragma unroll
        for (int i = 0; i < 8; ++i) {
            int idx = tid + i * 256;
            int r = idx >> 5, ch = idx & 31;
            const float4* src = (const float4*)(V + bbase + (size_t)(kt*64 + r) * D_ + headoff);
            KVs[r][ch ^ ((r >> 2) & 7)] = src[ch];
        }
        {
            float pv[8];
            float tmax = -1e30f;
#pragma unroll
            for (int c = 0; c < 8; ++c) { pv[c] = Sst[r8][q8*8 + c]; tmax = fmaxf(tmax, pv[c]); }
#pragma unroll
            for (int m = 1; m < 8; m <<= 1) tmax = fmaxf(tmax, __shfl_xor(tmax, m, 64));
            float oldm = mrow[r8];
            float newm = fmaxf(oldm, tmax);
            float psum = 0.f;
#pragma unroll
            for (int c = 0; c < 8; ++c) {
                float p = expf(pv[c] - newm);
                Sst[r8][q8*8 + c] = p;
                psum += p;
            }
#pragma unroll
            for (int m = 1; m < 8; m <<= 1) psum += __shfl_xor(psum, m, 64);
            if (q8 == 0) {
                float crv = expf(oldm - newm);
                crow[r8] = crv;
                lrow[r8] = lrow[r8] * crv + psum;
                mrow[r8] = newm;
            }
        }
        __syncthreads();
        {
            float crv[2];
#pragma unroll
            for (int i = 0; i < 2; ++i) {
                crv[i] = crow[ty16*2 + i];
#pragma unroll
                for (int j = 0; j < 8; ++j) o[i][j] *= crv[i];
            }
#pragma unroll
            for (int kc = 0; kc < 64; ++kc) {
                int swz = (kc >> 2) & 7;
                float4 v0 = KVs[kc][tx16 ^ swz];
                float4 v1 = KVs[kc][(16 + tx16) ^ swz];
#pragma unroll
                for (int i = 0; i < 2; ++i) {
                    float p = Sst[ty16*2 + i][kc];
                    o[i][0] += p*v0.x; o[i][1] += p*v0.y; o[i][2] += p*v0.z; o[i][3] += p*v0.w;
                    o[i][4] += p*v1.x; o[i][5] += p*v1.y; o[i][6] += p*v1.z; o[i][7] += p*v1.w;
                }
            }
        }
    }
#pragma unroll
    for (int i = 0; i < 2; ++i) {
        int r = ty16*2 + i;
        float inv = 1.0f / lrow[r];
        float4 a, bb;
        a.x = o[i][0]*inv; a.y = o[i][1]*inv; a.z = o[i][2]*inv; a.w = o[i][3]*inv;
        bb.x = o[i][4]*inv; bb.y = o[i][5]*inv; bb.z = o[i][6]*inv; bb.w = o[i][7]*inv;
        float* dst = O + bbase + (size_t)(qt*32 + r) * D_ + headoff;
        ((float4*)dst)[tx16] = a;
        ((float4*)dst)[16 + tx16] = bb;
    }
}

// ---------------- router / loss / topk / gather / copy / scatter ----------------
__global__ __launch_bounds__(256) void router_kernel(const float* __restrict__ x,
                                                     const float* __restrict__ proc,
                                                     const float* __restrict__ prior,
                                                     float* __restrict__ gbuf,
                                                     float* __restrict__ dchbuf,
                                                     float* __restrict__ gout) {
    int row = blockIdx.x, tid = threadIdx.x;
    const float4* x4 = (const float4*)(x + (size_t)row * D_);
    const float4* p4 = (const float4*)(proc + (size_t)row * D_);
    const float4* r4 = (const float4*)(prior + (size_t)row * D_);
    float sst = 0.f, sch = 0.f;
#pragma unroll
    for (int it = 0; it < 2; ++it) {
        int i = tid + it * 256;
        float4 xv = x4[i], pv = p4[i], rv = r4[i];
        float a0 = pv.x - xv.x, a1 = pv.y - xv.y, a2 = pv.z - xv.z, a3 = pv.w - xv.w;
        sst += a0*a0 + a1*a1 + a2*a2 + a3*a3;
        float d0 = a0 - rv.x, d1 = a1 - rv.y, d2 = a2 - rv.z, d3 = a3 - rv.w;
        sch += d0*d0 + d1*d1 + d2*d2 + d3*d3;
    }
    __shared__ float rs[256], rc[256];
    rs[tid] = sst; rc[tid] = sch; __syncthreads();
    for (int off = 128; off > 0; off >>= 1) {
        if (tid < off) { rs[tid] += rs[tid + off]; rc[tid] += rc[tid + off]; }
        __syncthreads();
    }
    if (tid == 0) {
        float Dst = rs[0] * (1.0f/2048.0f);
        float Dch = rc[0] * (1.0f/2048.0f);
        float g = 1.0f / (1.0f + expf(-(Dch - Dst)));
        gbuf[row] = g; dchbuf[row] = Dch; gout[row] = g;
    }
}

__global__ __launch_bounds__(1024) void loss_kernel(const float* __restrict__ dch, float* __restrict__ out) {
    __shared__ float red[1024];
    int tid = threadIdx.x;
    red[tid] = dch[tid] + dch[tid + 1024] + dch[tid + 2048] + dch[tid + 3072];
    __syncthreads();
    for (int off = 512; off > 0; off >>= 1) {
        if (tid < off) red[tid] += red[tid + off];
        __syncthreads();
    }
    if (tid == 0) out[0] = red[0] * (1.0f / 4096.0f);
}

__global__ __launch_bounds__(1024) void topk_kernel(const float* __restrict__ gbuf,
                                                    int* __restrict__ idxout,
                                                    float* __restrict__ gateout) {
    int b = blockIdx.x, tid = threadIdx.x;
    __shared__ float val[2048];
    __shared__ int idx[2048];
    val[tid] = gbuf[b*2048 + tid];           idx[tid] = tid;
    val[tid + 1024] = gbuf[b*2048 + tid + 1024]; idx[tid + 1024] = tid + 1024;
    __syncthreads();
    for (int kk = 2; kk <= 2048; kk <<= 1) {
        for (int j = kk >> 1; j > 0; j >>= 1) {
            for (int i = tid; i < 2048; i += 1024) {
                int ixj = i ^ j;
                if (ixj > i) {
                    bool up = ((i & kk) == 0);
                    float v1 = val[i], v2 = val[ixj];
                    int i1 = idx[i], i2 = idx[ixj];
                    bool sw = up ? ((v2 > v1) || (v2 == v1 && i2 < i1))
                                 : ((v1 > v2) || (v1 == v2 && i1 < i2));
                    if (sw) { val[i] = v2; val[ixj] = v1; idx[i] = i2; idx[ixj] = i1; }
                }
            }
            __syncthreads();
        }
    }
    if (tid < 1024) {
        idxout[b*1024 + tid] = idx[tid];
        gateout[b*1024 + tid] = val[tid];
    }
}

__global__ __launch_bounds__(256) void gather_kernel(const float* __restrict__ proc,
                                                     const int* __restrict__ idx,
                                                     float* __restrict__ sel) {
    int r = blockIdx.x;
    int b = r >> 10, rr = r & 1023;
    int tok = idx[b*1024 + rr];
    const float4* src = (const float4*)(proc + ((size_t)(b*2048 + tok)) * D_);
    float4* dst = (float4*)(sel + (size_t)r * D_);
    dst[threadIdx.x] = src[threadIdx.x];
    dst[threadIdx.x + 256] = src[threadIdx.x + 256];
}

__global__ __launch_bounds__(256) void copy_kernel(const float* __restrict__ src,
                                                   float* __restrict__ dst, int n4) {
    int i = blockIdx.x * 256 + threadIdx.x;
    if (i < n4) ((float4*)dst)[i] = ((const float4*)src)[i];
}

__global__ __launch_bounds__(256) void scatter_kernel(const float* __restrict__ sel,
                                                      const float* __restrict__ selout,
                                                      const int* __restrict__ idx,
                                                      const float* __restrict__ gate,
                                                      float* __restrict__ outp) {
    int r = blockIdx.x;
    int b = r >> 10, rr = r & 1023;
    int tok = idx[b*1024 + rr];
    float g = gate[b*1024 + rr];
    const float4* s4 = (const float4*)(sel + (size_t)r * D_);
    const float4* o4 = (const float4*)(selout + (size_t)r * D_);
    float4* d4 = (float4*)(outp + ((size_t)(b*2048 + tok)) * D_);
#pragma unroll
    for (int it = 0; it < 2; ++it) {
        int i = threadIdx.x + it * 256;
        float4 a = s4[i], o = o4[i];
        float4 w;
        w.x = a.x + g*(o.x - a.x); w.y = a.y + g*(o.y - a.y);
        w.z = a.z + g*(o.z - a.z); w.w = a.w + g*(o.w - a.w);
        d4[i] = w;
    }
}

extern "C" void kernel_launch(void* const* d_in, const int* in_sizes, int n_in,
                              void* d_out, int out_size, void* d_ws, size_t ws_size,
                              hipStream_t stream) {
    const float* X      = (const float*)d_in[0];
    const float* d1_ln1 = (const float*)d_in[1];
    const float* d1_ln2 = (const float*)d_in[2];
    const float* d1_wq  = (const float*)d_in[3];
    const float* d1_wk  = (const float*)d_in[4];
    const float* d1_wv  = (const float*)d_in[5];
    const float* d1_wo  = (const float*)d_in[6];
    const float* d1_wg  = (const float*)d_in[7];
    const float* d1_wu  = (const float*)d_in[8];
    const float* d1_wd  = (const float*)d_in[9];
    const float* d2_ln1 = (const float*)d_in[10];
    const float* d2_ln2 = (const float*)d_in[11];
    const float* d2_wq  = (const float*)d_in[12];
    const float* d2_wk  = (const float*)d_in[13];
    const float* d2_wv  = (const float*)d_in[14];
    const float* d2_wo  = (const float*)d_in[15];
    const float* d2_wg  = (const float*)d_in[16];
    const float* d2_wu  = (const float*)d_in[17];
    const float* d2_wd  = (const float*)d_in[18];
    const float* p_ln   = (const float*)d_in[19];
    const float* p_wg   = (const float*)d_in[20];
    const float* p_wu   = (const float*)d_in[21];
    const float* p_wd   = (const float*)d_in[22];

    float* out = (float*)d_out;
    float* ws  = (float*)d_ws;

    const size_t BIG = (size_t)NTOK_ * D_;           // 8M f32
    const size_t MEG = 1024 * 1024;

    const size_t NEED_NEW = (128 * MEG + 16384) * 4;  // ~512 MB
    const size_t NEED_OLD = ((5*BIG + (size_t)NTOK_*FF_ + 12288) * 4);

    if (ws_size >= NEED_NEW) {
        float* BUF0 = ws;                 // 8M f32
        float* BUF1 = ws + 8*MEG;         // q
        float* BUF2 = ws + 16*MEG;        // k / h
        float* BUF3 = ws + 24*MEG;        // v / prior_out / sel_out
        float* BUF4 = ws + 32*MEG;        // attnout / sel (+V2)
        float* BUFF = ws + 40*MEG;        // 32M f32 FF
        unsigned short* PWhi  = (unsigned short*)(ws + 72*MEG);
        unsigned short* PWlo  = (unsigned short*)(ws + 80*MEG);
        unsigned short* PAhi  = (unsigned short*)(ws + 88*MEG);
        unsigned short* PAlo  = (unsigned short*)(ws + 92*MEG);
        unsigned short* PFhi  = (unsigned short*)(ws + 96*MEG);
        unsigned short* PFlo  = (unsigned short*)(ws + 112*MEG);
        // attention packed buffers (overlay PF region; disjoint in time)
        unsigned short* U   = (unsigned short*)(ws + 96*MEG);
        const size_t PK = (size_t)NTOK_ * D_;         // 8.39M ushorts
        unsigned short* QHp = U;
        unsigned short* QLp = U + PK;
        unsigned short* KHp = U + 2*PK;
        unsigned short* KLp = U + 3*PK;
        unsigned short* VTH = U + 4*PK;
        unsigned short* VTL = U + 5*PK;
        float* SM   = ws + 128*MEG;
        float* gbuf = SM;
        float* dch  = SM + 4096;
        float* gate = SM + 8192;
        int*   idxb = (int*)(SM + 10240);

        float* PROC = out;                // processed lives directly in out

        // ---- decision decoder layer (bf16x3 GEMMs + bf16x3 MFMA attention) ----
        rms_kernel<<<NTOK_, 256, 0, stream>>>(X, d1_ln1, BUF0);
        splita_kernel<1><<<dim3(64, 32), 256, 0, stream>>>(BUF0, PAhi, PAlo, NTOK_, D_);
        splitw_kernel<1><<<dim3(32, 32), 256, 0, stream>>>(d1_wq, PWhi, PWlo, D_, D_);
        gemm_mfma<3,0><<<dim3(16, 32), 256, 0, stream>>>(PAhi, PAlo, PWhi, PWlo, BUF1, nullptr, nullptr, nullptr, NTOK_, D_, D_);
        splitw_kernel<1><<<dim3(32, 32), 256, 0, stream>>>(d1_wk, PWhi, PWlo, D_, D_);
        gemm_mfma<3,0><<<dim3(16, 32), 256, 0, stream>>>(PAhi, PAlo, PWhi, PWlo, BUF2, nullptr, nullptr, nullptr, NTOK_, D_, D_);
        splitw_kernel<1><<<dim3(32, 32), 256, 0, stream>>>(d1_wv, PWhi, PWlo, D_, D_);
        gemm_mfma<3,0><<<dim3(16, 32), 256, 0, stream>>>(PAhi, PAlo, PWhi, PWlo, BUF3, nullptr, nullptr, nullptr, NTOK_, D_, D_);
        rope_split_kernel<<<NTOK_, 256, 0, stream>>>(BUF1, QHp, QLp, T_ - 1, SCALE_QK);
        rope_split_kernel<<<NTOK_, 256, 0, stream>>>(BUF2, KHp, KLp, T_ - 1, 1.0f);
        vpack_kernel<<<dim3(T_/64, B_*H_), 256, 0, stream>>>(BUF3, VTH, VTL, T_);
        attn_mfma<<<dim3(T_/64, B_*H_), 256, 0, stream>>>(QHp, QLp, KHp, KLp, VTH, VTL, BUF4, T_);
        splita_kernel<1><<<dim3(64, 32), 256, 0, stream>>>(BUF4, PAhi, PAlo, NTOK_, D_);
        splitw_kernel<1><<<dim3(32, 32), 256, 0, stream>>>(d1_wo, PWhi, PWlo, D_, D_);
        gemm_mfma<3,1><<<dim3(16, 32), 256, 0, stream>>>(PAhi, PAlo, PWhi, PWlo, BUF2, X, nullptr, nullptr, NTOK_, D_, D_);  // h
        rms_kernel<<<NTOK_, 256, 0, stream>>>(BUF2, d1_ln2, BUF0);
        splita_kernel<1><<<dim3(64, 32), 256, 0, stream>>>(BUF0, PAhi, PAlo, NTOK_, D_);
        splitw_kernel<1><<<dim3(128, 32), 256, 0, stream>>>(d1_wg, PWhi, PWlo, D_, FF_);
        gemm_mfma<3,0><<<dim3(64, 32), 256, 0, stream>>>(PAhi, PAlo, PWhi, PWlo, BUFF, nullptr, nullptr, nullptr, NTOK_, FF_, D_);
        splitw_kernel<1><<<dim3(128, 32), 256, 0, stream>>>(d1_wu, PWhi, PWlo, D_, FF_);
        gemm_mfma<3,3><<<dim3(64, 32), 256, 0, stream>>>(PAhi, PAlo, PWhi, PWlo, nullptr, BUFF, PFhi, PFlo, NTOK_, FF_, D_);  // silu(wg)*wu -> packed
        splitw_kernel<1><<<dim3(32, 128), 256, 0, stream>>>(d1_wd, PWhi, PWlo, FF_, D_);
        gemm_mfma<3,1><<<dim3(16, 32), 256, 0, stream>>>(PFhi, PFlo, PWhi, PWlo, PROC, BUF2, nullptr, nullptr, NTOK_, D_, FF_); // processed -> out

        // ---- prior network (bf16x3) ----
        rms_kernel<<<NTOK_, 256, 0, stream>>>(X, p_ln, BUF0);
        splita_kernel<1><<<dim3(64, 32), 256, 0, stream>>>(BUF0, PAhi, PAlo, NTOK_, D_);
        splitw_kernel<1><<<dim3(16, 32), 256, 0, stream>>>(p_wg, PWhi, PWlo, D_, PFF_);
        gemm_mfma<3,0><<<dim3(8, 32), 256, 0, stream>>>(PAhi, PAlo, PWhi, PWlo, BUFF, nullptr, nullptr, nullptr, NTOK_, PFF_, D_);
        splitw_kernel<1><<<dim3(16, 32), 256, 0, stream>>>(p_wu, PWhi, PWlo, D_, PFF_);
        gemm_mfma<3,3><<<dim3(8, 32), 256, 0, stream>>>(PAhi, PAlo, PWhi, PWlo, nullptr, BUFF, PFhi, PFlo, NTOK_, PFF_, D_);
        splitw_kernel<1><<<dim3(32, 16), 256, 0, stream>>>(p_wd, PWhi, PWlo, PFF_, D_);
        gemm_mfma<3,0><<<dim3(16, 32), 256, 0, stream>>>(PFhi, PFlo, PWhi, PWlo, BUF3, nullptr, nullptr, nullptr, NTOK_, D_, PFF_); // prior_out

        // ---- router + loss + top-k + gather ----
        router_kernel<<<NTOK_, 256, 0, stream>>>(X, PROC, BUF3, gbuf, dch, out + 8388609);
        loss_kernel<<<1, 1024, 0, stream>>>(dch, out + 8388608);
        topk_kernel<<<B_, 1024, 0, stream>>>(gbuf, idxb, gate);
        gather_kernel<<<NSEL_, 256, 0, stream>>>(PROC, idxb, BUF4);   // sel

        // ---- dynamic decoder layer (bf16 NP=1 GEMMs, x3 MFMA attention) ----
        float* V2 = BUF4 + (size_t)NSEL_ * D_;
        rms_kernel<<<NSEL_, 256, 0, stream>>>(BUF4, d2_ln1, BUF0);
        splita_kernel<0><<<dim3(32, 32), 256, 0, stream>>>(BUF0, PAhi, PAlo, NSEL_, D_);
        splitw_kernel<0><<<dim3(32, 32), 256, 0, stream>>>(d2_wq, PWhi, PWlo, D_, D_);
        gemm_mfma<1,0><<<dim3(16, 16), 256, 0, stream>>>(PAhi, PAlo, PWhi, PWlo, BUF2, nullptr, nullptr, nullptr, NSEL_, D_, D_);
        splitw_kernel<0><<<dim3(32, 32), 256, 0, stream>>>(d2_wk, PWhi, PWlo, D_, D_);
        gemm_mfma<1,0><<<dim3(16, 16), 256, 0, stream>>>(PAhi, PAlo, PWhi, PWlo, BUF3, nullptr, nullptr, nullptr, NSEL_, D_, D_);
        splitw_kernel<0><<<dim3(32, 32), 256, 0, stream>>>(d2_wv, PWhi, PWlo, D_, D_);
        gemm_mfma<1,0><<<dim3(16, 16), 256, 0, stream>>>(PAhi, PAlo, PWhi, PWlo, V2, nullptr, nullptr, nullptr, NSEL_, D_, D_);
        rope_split_kernel<<<NSEL_, 256, 0, stream>>>(BUF2, QHp, QLp, T2_ - 1, SCALE_QK);
        rope_split_kernel<<<NSEL_, 256, 0, stream>>>(BUF3, KHp, KLp, T2_ - 1, 1.0f);
        vpack_kernel<<<dim3(T2_/64, B_*H_), 256, 0, stream>>>(V2, VTH, VTL, T2_);
        attn_mfma<<<dim3(T2_/64, B_*H_), 256, 0, stream>>>(QHp, QLp, KHp, KLp, VTH, VTL, BUF0, T2_);
        splita_kernel<0><<<dim3(32, 32), 256, 0, stream>>>(BUF0, PAhi, PAlo, NSEL_, D_);
        splitw_kernel<0><<<dim3(32, 32), 256, 0, stream>>>(d2_wo, PWhi, PWlo, D_, D_);
        gemm_mfma<1,1><<<dim3(16, 16), 256, 0, stream>>>(PAhi, PAlo, PWhi, PWlo, BUF2, BUF4, nullptr, nullptr, NSEL_, D_, D_); // h2
        rms_kernel<<<NSEL_, 256, 0, stream>>>(BUF2, d2_ln2, BUF0);
        splita_kernel<0><<<dim3(32, 32), 256, 0, stream>>>(BUF0, PAhi, PAlo, NSEL_, D_);
        splitw_kernel<0><<<dim3(128, 32), 256, 0, stream>>>(d2_wg, PWhi, PWlo, D_, FF_);
        gemm_mfma<1,0><<<dim3(64, 16), 256, 0, stream>>>(PAhi, PAlo, PWhi, PWlo, BUFF, nullptr, nullptr, nullptr, NSEL_, FF_, D_);
        splitw_kernel<0><<<dim3(128, 32), 256, 0, stream>>>(d2_wu, PWhi, PWlo, D_, FF_);
        gemm_mfma<1,4><<<dim3(64, 16), 256, 0, stream>>>(PAhi, PAlo, PWhi, PWlo, nullptr, BUFF, PFhi, nullptr, NSEL_, FF_, D_);  // silu(wg)*wu -> packed hi
        splitw_kernel<0><<<dim3(32, 128), 256, 0, stream>>>(d2_wd, PWhi, PWlo, FF_, D_);
        gemm_mfma<1,1><<<dim3(16, 16), 256, 0, stream>>>(PFhi, PFlo, PWhi, PWlo, BUF3, BUF2, nullptr, nullptr, NSEL_, D_, FF_); // sel_out

        scatter_kernel<<<NSEL_, 256, 0, stream>>>(BUF4, BUF3, idxb, gate, out);
        return;
    }

    if (ws_size < NEED_OLD) return;

    // ================= fallback: f32 path =================
    float* BUF0 = ws;
    float* BUF1 = ws + BIG;
    float* BUF2 = ws + 2*BIG;
    float* BUF3 = ws + 3*BIG;
    float* BUF4 = ws + 4*BIG;
    float* BUFF = ws + 5*BIG;
    float* SM   = BUFF + (size_t)NTOK_ * FF_;
    float* gbuf = SM;
    float* dch  = SM + 4096;
    float* gate = SM + 8192;
    int*   idxb = (int*)(SM + 10240);

    rms_kernel<<<NTOK_, 256, 0, stream>>>(X, d1_ln1, BUF0);
    gemm128<0><<<dim3(16, 32), 256, 0, stream>>>(BUF0, d1_wq, BUF1, nullptr, NTOK_, D_, D_);
    gemm128<0><<<dim3(16, 32), 256, 0, stream>>>(BUF0, d1_wk, BUF2, nullptr, NTOK_, D_, D_);
    gemm128<0><<<dim3(16, 32), 256, 0, stream>>>(BUF0, d1_wv, BUF3, nullptr, NTOK_, D_, D_);
    rope_kernel<<<NTOK_*4, 256, 0, stream>>>(BUF1, NTOK_, T_);
    rope_kernel<<<NTOK_*4, 256, 0, stream>>>(BUF2, NTOK_, T_);
    attn_kernel<<<dim3(T_/32, B_*H_), 256, 0, stream>>>(BUF1, BUF2, BUF3, BUF4, T_);
    gemm128<1><<<dim3(16, 32), 256, 0, stream>>>(BUF4, d1_wo, BUF2, X, NTOK_, D_, D_);
    rms_kernel<<<NTOK_, 256, 0, stream>>>(BUF2, d1_ln2, BUF0);
    gemm128<0><<<dim3(64, 32), 256, 0, stream>>>(BUF0, d1_wg, BUFF, nullptr, NTOK_, FF_, D_);
    gemm128<2><<<dim3(64, 32), 256, 0, stream>>>(BUF0, d1_wu, BUFF, BUFF, NTOK_, FF_, D_);
    gemm128<1><<<dim3(16, 32), 256, 0, stream>>>(BUFF, d1_wd, BUF1, BUF2, NTOK_, D_, FF_);

    rms_kernel<<<NTOK_, 256, 0, stream>>>(X, p_ln, BUF0);
    gemm128<0><<<dim3(8, 32), 256, 0, stream>>>(BUF0, p_wg, BUF4, nullptr, NTOK_, PFF_, D_);
    gemm128<2><<<dim3(8, 32), 256, 0, stream>>>(BUF0, p_wu, BUF4, BUF4, NTOK_, PFF_, D_);
    gemm128<0><<<dim3(16, 32), 256, 0, stream>>>(BUF4, p_wd, BUF3, nullptr, NTOK_, D_, PFF_);

    router_kernel<<<NTOK_, 256, 0, stream>>>(X, BUF1, BUF3, gbuf, dch, out + 8388609);
    loss_kernel<<<1, 1024, 0, stream>>>(dch, out + 8388608);
    topk_kernel<<<B_, 1024, 0, stream>>>(gbuf, idxb, gate);
    gather_kernel<<<NSEL_, 256, 0, stream>>>(BUF1, idxb, BUF4);

    float* V2 = BUF4 + (size_t)NSEL_ * D_;
    rms_kernel<<<NSEL_, 256, 0, stream>>>(BUF4, d2_ln1, BUF0);
    gemm128<0><<<dim3(16, 16), 256, 0, stream>>>(BUF0, d2_wq, BUF2, nullptr, NSEL_, D_, D_);
    gemm128<0><<<dim3(16, 16), 256, 0, stream>>>(BUF0, d2_wk, BUF3, nullptr, NSEL_, D_, D_);
    gemm128<0><<<dim3(16, 16), 256, 0, stream>>>(BUF0, d2_wv, V2, nullptr, NSEL_, D_, D_);
    rope_kernel<<<NSEL_*4, 256, 0, stream>>>(BUF2, NSEL_, T2_);
    rope_kernel<<<NSEL_*4, 256, 0, stream>>>(BUF3, NSEL_, T2_);
    attn_kernel<<<dim3(T2_/32, B_*H_), 256, 0, stream>>>(BUF2, BUF3, V2, BUF0, T2_);
    gemm128<1><<<dim3(16, 16), 256, 0, stream>>>(BUF0, d2_wo, BUF2, BUF4, NSEL_, D_, D_);
    rms_kernel<<<NSEL_, 256, 0, stream>>>(BUF2, d2_ln2, BUF0);
    gemm128<0><<<dim3(64, 16), 256, 0, stream>>>(BUF0, d2_wg, BUFF, nullptr, NSEL_, FF_, D_);
    gemm128<2><<<dim3(64, 16), 256, 0, stream>>>(BUF0, d2_wu, BUFF, BUFF, NSEL_, FF_, D_);
    gemm128<1><<<dim3(16, 16), 256, 0, stream>>>(BUFF, d2_wd, BUF3, BUF2, NSEL_, D_, FF_);

    copy_kernel<<<8192, 256, 0, stream>>>(BUF1, out, (int)(BIG / 4));
    scatter_kernel<<<NSEL_, 256, 0, stream>>>(BUF4, BUF3, idxb, gate, out);
}

// Round 12
// 3076.939 us; speedup vs baseline: 1.0532x; 1.0532x over previous
//
#include <hip/hip_runtime.h>
#include <math.h>

#define D_    2048
#define H_    16
#define DH_   128
#define FF_   8192
#define PFF_  1024
#define B_    2
#define T_    2048
#define NTOK_ 4096
#define T2_   1024
#define NSEL_ 2048
#define EPS_  1e-6f
#define SCALE_QK 0.08838834764831845f  // 1/sqrt(128)

typedef __attribute__((ext_vector_type(8))) short bf16x8;
typedef __attribute__((ext_vector_type(4))) float f32x4;
typedef __attribute__((ext_vector_type(8))) unsigned short ushort8;

__device__ __forceinline__ float silu_f(float x) {
    return x / (1.0f + expf(-x));
}

__device__ __forceinline__ unsigned short bf16_rne(float f) {
    unsigned int u = __float_as_uint(f);
    unsigned int r = (u + 0x7fffu + ((u >> 16) & 1u)) >> 16;
    return (unsigned short)r;
}
__device__ __forceinline__ float bf16_tof(unsigned short h) {
    return __uint_as_float(((unsigned int)h) << 16);
}

// ---------------- RMSNorm: one block per row ----------------
__global__ __launch_bounds__(256) void rms_kernel(const float* __restrict__ x,
                                                  const float* __restrict__ w,
                                                  float* __restrict__ out) {
    int row = blockIdx.x;
    int tid = threadIdx.x;
    const float4* xr = (const float4*)(x + (size_t)row * D_);
    float4* orow = (float4*)(out + (size_t)row * D_);
    const float4* w4 = (const float4*)w;
    float4 v0 = xr[tid], v1 = xr[tid + 256];
    float s = v0.x*v0.x + v0.y*v0.y + v0.z*v0.z + v0.w*v0.w
            + v1.x*v1.x + v1.y*v1.y + v1.z*v1.z + v1.w*v1.w;
    __shared__ float red[256];
    red[tid] = s; __syncthreads();
    for (int off = 128; off > 0; off >>= 1) {
        if (tid < off) red[tid] += red[tid + off];
        __syncthreads();
    }
    float r = 1.0f / sqrtf(red[0] * (1.0f/2048.0f) + EPS_);
    float4 w0 = w4[tid], w1 = w4[tid + 256];
    float4 o0, o1;
    o0.x = v0.x*r*w0.x; o0.y = v0.y*r*w0.y; o0.z = v0.z*r*w0.z; o0.w = v0.w*r*w0.w;
    o1.x = v1.x*r*w1.x; o1.y = v1.y*r*w1.y; o1.z = v1.z*r*w1.z; o1.w = v1.w*r*w1.w;
    orow[tid] = o0; orow[tid + 256] = o1;
}

// ---------------- weight transpose+split: B[K][N] f32 -> Phi(/Plo)[k/8][n][8] bf16 ----------------
template<int WLO>
__global__ __launch_bounds__(256) void splitw_kernel(const float* __restrict__ W,
                                                     unsigned short* __restrict__ phi,
                                                     unsigned short* __restrict__ plo,
                                                     int K, int N) {
    __shared__ float Ts[64][68];
    int n0 = blockIdx.x << 6, k0 = blockIdx.y << 6;
    int tid = threadIdx.x;
#pragma unroll
    for (int it = 0; it < 4; ++it) {
        int idx = tid + (it << 8);
        int kr = idx >> 4, c4 = idx & 15;
        float4 v = *(const float4*)(W + (size_t)(k0 + kr) * N + n0 + (c4 << 2));
        Ts[kr][c4*4+0] = v.x; Ts[kr][c4*4+1] = v.y; Ts[kr][c4*4+2] = v.z; Ts[kr][c4*4+3] = v.w;
    }
    __syncthreads();
#pragma unroll
    for (int h = 0; h < 2; ++h) {
        int c = tid + (h << 8);              // [0,512)
        int kc = c >> 6, n = c & 63;
        ushort8 hi, lo;
#pragma unroll
        for (int q = 0; q < 8; ++q) {
            float v = Ts[kc*8 + q][n];
            unsigned short hb = bf16_rne(v);
            hi[q] = hb;
            if (WLO) lo[q] = bf16_rne(v - bf16_tof(hb));
        }
        size_t off = ((size_t)((k0 >> 3) + kc) * N + (n0 + n)) * 8;
        *(ushort8*)(phi + off) = hi;
        if (WLO) *(ushort8*)(plo + off) = lo;
    }
}

// ---------------- activation split: A[M][K] f32 -> Phi(/Plo)[k/8][m][8] bf16 ----------------
template<int WLO>
__global__ __launch_bounds__(256) void splita_kernel(const float* __restrict__ A,
                                                     unsigned short* __restrict__ phi,
                                                     unsigned short* __restrict__ plo,
                                                     int M, int K) {
    __shared__ float Ts[64][68];
    int m0 = blockIdx.x << 6, k0 = blockIdx.y << 6;
    int tid = threadIdx.x;
#pragma unroll
    for (int it = 0; it < 4; ++it) {
        int idx = tid + (it << 8);
        int mr = idx >> 4, c4 = idx & 15;
        float4 v = *(const float4*)(A + (size_t)(m0 + mr) * K + k0 + (c4 << 2));
        Ts[mr][c4*4+0] = v.x; Ts[mr][c4*4+1] = v.y; Ts[mr][c4*4+2] = v.z; Ts[mr][c4*4+3] = v.w;
    }
    __syncthreads();
#pragma unroll
    for (int h = 0; h < 2; ++h) {
        int c = tid + (h << 8);
        int kc = c >> 6, m = c & 63;
        const float* src = &Ts[m][kc << 3];
        ushort8 hi, lo;
#pragma unroll
        for (int q = 0; q < 8; ++q) {
            float v = src[q];
            unsigned short hb = bf16_rne(v);
            hi[q] = hb;
            if (WLO) lo[q] = bf16_rne(v - bf16_tof(hb));
        }
        size_t off = ((size_t)((k0 >> 3) + kc) * M + (m0 + m)) * 8;
        *(ushort8*)(phi + off) = hi;
        if (WLO) *(ushort8*)(plo + off) = lo;
    }
}

// ---------------- bf16(x3) MFMA GEMM, 128x128 tile, BK=32, 2-phase dbuf, 16x16x32 MFMA ----------------
// Block map: XCD-chunked + column-major decode (B-panel L2 residency).
// EPI 0: C=acc ; 1: C=acc+Rg ; 2: C=silu(Rg)*acc ;
// EPI 3: packed hi/lo panels = silu(Rg)*acc ; EPI 4: packed hi panel only.
__device__ __forceinline__ void stage_panel(unsigned short* lds,
                                            const unsigned short* __restrict__ panel,
                                            int ktile, int R, int brow, int tid) {
#pragma unroll
    for (int h = 0; h < 2; ++h) {
        int c = tid + (h << 8);              // [0,512): kc = c>>7, row = c&127
        const unsigned short* g = panel + ((size_t)((ktile << 2) + (c >> 7)) * R + (brow + (c & 127))) * 8;
        __builtin_amdgcn_global_load_lds((const __attribute__((address_space(1))) void*)g,
                                         (__attribute__((address_space(3))) void*)(lds + (size_t)c * 8),
                                         16, 0, 0);
    }
}

template<int NP, int EPI>
__global__ __launch_bounds__(256) void gemm_mfma(const unsigned short* __restrict__ pah,
                                                 const unsigned short* __restrict__ pal,
                                                 const unsigned short* __restrict__ pbh,
                                                 const unsigned short* __restrict__ pbl,
                                                 float* __restrict__ C,
                                                 const float* __restrict__ Rg,
                                                 unsigned short* __restrict__ Cph,
                                                 unsigned short* __restrict__ Cpl,
                                                 int M, int N, int K) {
    constexpr int NPAN = (NP == 3) ? 2 : 1;
    __shared__ __align__(16) unsigned short As[2][NPAN][4][128][8];
    __shared__ __align__(16) unsigned short Bs[2][NPAN][4][128][8];
    const int tid = threadIdx.x;
    // T1: XCD-aware bijective block swizzle (all grids here have nwg % 8 == 0)
    int nwg = gridDim.x * gridDim.y;
    int wg = blockIdx.y * gridDim.x + blockIdx.x;
    if ((nwg & 7) == 0) {
        int cpx = nwg >> 3;
        wg = (wg & 7) * cpx + (wg >> 3);
    }
    // column-major decode: each XCD chunk = contiguous bn-columns; blocks within
    // a column share one B panel (L2-resident) while streaming A.
    const int bxs = wg / gridDim.y, bys = wg % gridDim.y;
    const int bm = bys << 7, bn = bxs << 7;
    const int lane = tid & 63, wave = tid >> 6;
    const int wm = (wave >> 1) << 6, wn = (wave & 1) << 6;
    const int fr = lane & 15, fk = lane >> 4;

    f32x4 acc[4][4];
#pragma unroll
    for (int i = 0; i < 4; ++i)
#pragma unroll
        for (int j = 0; j < 4; ++j) acc[i][j] = (f32x4)0.0f;

    const int nkt = K >> 5;

    // prologue stage tile 0 into buf 0
    stage_panel(&As[0][0][0][0][0], pah, 0, M, bm, tid);
    if (NP == 3) stage_panel(&As[0][1][0][0][0], pal, 0, M, bm, tid);
    stage_panel(&Bs[0][0][0][0][0], pbh, 0, N, bn, tid);
    if (NP == 3) stage_panel(&Bs[0][1][0][0][0], pbl, 0, N, bn, tid);
    __syncthreads();

    int cur = 0;
    for (int kt = 0; kt < nkt; ++kt) {
        // T3 minimum 2-phase: issue next-tile stage BEFORE ds_read+MFMA
        if (kt + 1 < nkt) {
            int nxt = cur ^ 1;
            stage_panel(&As[nxt][0][0][0][0], pah, kt + 1, M, bm, tid);
            if (NP == 3) stage_panel(&As[nxt][1][0][0][0], pal, kt + 1, M, bm, tid);
            stage_panel(&Bs[nxt][0][0][0][0], pbh, kt + 1, N, bn, tid);
            if (NP == 3) stage_panel(&Bs[nxt][1][0][0][0], pbl, kt + 1, N, bn, tid);
        }

        bf16x8 ah[4], bh[4], al[4], bl[4];
#pragma unroll
        for (int i = 0; i < 4; ++i) {
            ah[i] = *(const bf16x8*)&As[cur][0][fk][wm + (i << 4) + fr][0];
            if (NP == 3) al[i] = *(const bf16x8*)&As[cur][NPAN-1][fk][wm + (i << 4) + fr][0];
        }
#pragma unroll
        for (int j = 0; j < 4; ++j) {
            bh[j] = *(const bf16x8*)&Bs[cur][0][fk][wn + (j << 4) + fr][0];
            if (NP == 3) bl[j] = *(const bf16x8*)&Bs[cur][NPAN-1][fk][wn + (j << 4) + fr][0];
        }
#pragma unroll
        for (int i = 0; i < 4; ++i)
#pragma unroll
            for (int j = 0; j < 4; ++j) {
                acc[i][j] = __builtin_amdgcn_mfma_f32_16x16x32_bf16(ah[i], bh[j], acc[i][j], 0, 0, 0);
                if (NP == 3) {
                    acc[i][j] = __builtin_amdgcn_mfma_f32_16x16x32_bf16(ah[i], bl[j], acc[i][j], 0, 0, 0);
                    acc[i][j] = __builtin_amdgcn_mfma_f32_16x16x32_bf16(al[i], bh[j], acc[i][j], 0, 0, 0);
                }
            }
        __syncthreads();   // next-tile stage complete; buf[cur] reads all drained
        cur ^= 1;
    }

#pragma unroll
    for (int i = 0; i < 4; ++i) {
        int row0 = bm + wm + (i << 4) + (fk << 2);
#pragma unroll
        for (int j = 0; j < 4; ++j) {
            int col = bn + wn + (j << 4) + fr;
#pragma unroll
            for (int r = 0; r < 4; ++r) {
                int row = row0 + r;
                size_t off = (size_t)row * N + col;
                float v = acc[i][j][r];
                if (EPI == 0) {
                    C[off] = v;
                } else if (EPI == 1) {
                    C[off] = v + Rg[off];
                } else if (EPI == 2) {
                    C[off] = silu_f(Rg[off]) * v;
                } else {
                    v = silu_f(Rg[off]) * v;
                    unsigned short hb = bf16_rne(v);
                    size_t poff = (((size_t)(col >> 3)) * M + row) * 8 + (col & 7);
                    Cph[poff] = hb;
                    if (EPI == 3) Cpl[poff] = bf16_rne(v - bf16_tof(hb));
                }
            }
        }
    }
}

// ---------------- fused RoPE + scale + hi/lo split ----------------
__global__ __launch_bounds__(256) void rope_split_kernel(const float* __restrict__ X,
                                                         unsigned short* __restrict__ xh,
                                                         unsigned short* __restrict__ xl,
                                                         int seqmask, float scale) {
    int tok = blockIdx.x;
    int tid = threadIdx.x;
    int h = tid >> 4, d0 = (tid & 15) << 3;
    int pos = tok & seqmask;
    const float* src = X + (size_t)tok * D_ + h * DH_;
    bool lohalf = d0 < 64;
    float out[8];
#pragma unroll
    for (int q = 0; q < 8; ++q) {
        int d = d0 + q;
        int i = lohalf ? d : (d - 64);
        float e = (float)(2 * i) * (1.0f / 128.0f);
        float inv = 1.0f / powf(10000.0f, e);
        float ang = (float)pos * inv;
        float c = cosf(ang), s = sinf(ang);
        float x1 = src[i], x2 = src[i + 64];
        out[q] = lohalf ? (x1 * c - x2 * s) : (x2 * c + x1 * s);
    }
    ushort8 hi, lo;
#pragma unroll
    for (int q = 0; q < 8; ++q) {
        float v = out[q] * scale;
        unsigned short hb = bf16_rne(v);
        hi[q] = hb;
        lo[q] = bf16_rne(v - bf16_tof(hb));
    }
    size_t off = (size_t)tok * D_ + h * DH_ + d0;
    *(ushort8*)(xh + off) = hi;
    *(ushort8*)(xl + off) = lo;
}

// ---------------- V pack: f32 [b*T+t][2048] -> Vt[bh][T/8][128][8] bf16 hi/lo ----------------
__global__ __launch_bounds__(256) void vpack_kernel(const float* __restrict__ V,
                                                    unsigned short* __restrict__ vth,
                                                    unsigned short* __restrict__ vtl,
                                                    int T) {
    __shared__ float Ts[64][132];
    int kt = blockIdx.x, bh = blockIdx.y;
    int b = bh >> 4, h = bh & 15;
    int tid = threadIdx.x;
#pragma unroll
    for (int it = 0; it < 8; ++it) {
        int idx = tid + (it << 8);          // [0,2048)
        int r = idx >> 5, c4 = idx & 31;    // r in [0,64), c4 in [0,32)
        float4 v = *(const float4*)(V + ((size_t)(b * T + kt * 64 + r)) * D_ + h * DH_ + (c4 << 2));
        Ts[r][c4*4+0] = v.x; Ts[r][c4*4+1] = v.y; Ts[r][c4*4+2] = v.z; Ts[r][c4*4+3] = v.w;
    }
    __syncthreads();
    size_t obase = ((size_t)bh * (size_t)(T >> 3) + (size_t)kt * 8) * 1024;
#pragma unroll
    for (int it = 0; it < 4; ++it) {
        int c = tid + (it << 8);            // [0,1024): kc = c>>7, dh = c&127
        int kc = c >> 7, dh = c & 127;
        ushort8 hi, lo;
#pragma unroll
        for (int q = 0; q < 8; ++q) {
            float v = Ts[kc * 8 + q][dh];
            unsigned short hb = bf16_rne(v);
            hi[q] = hb;
            lo[q] = bf16_rne(v - bf16_tof(hb));
        }
        *(ushort8*)(vth + obase + (size_t)kc * 1024 + dh * 8) = hi;
        *(ushort8*)(vtl + obase + (size_t)kc * 1024 + dh * 8) = lo;
    }
}

// ---------------- bf16x3 MFMA flash attention ----------------
// grid: (T/64, B_*H_), block 256 (4 waves, each owns 16 q-rows)
__global__ __launch_bounds__(256) void attn_mfma(const unsigned short* __restrict__ QH,
                                                 const unsigned short* __restrict__ QL,
                                                 const unsigned short* __restrict__ KH,
                                                 const unsigned short* __restrict__ KL,
                                                 const unsigned short* __restrict__ VTH,
                                                 const unsigned short* __restrict__ VTL,
                                                 float* __restrict__ O, int T) {
    __shared__ __align__(16) unsigned short KV[16384];
    __shared__ __align__(16) float Ss[4096];
    __shared__ __align__(16) float mrow[64];
    __shared__ __align__(16) float lrow[64];
    __shared__ __align__(16) float crow[64];

    const int tid = threadIdx.x;
    const int qt = blockIdx.x, bh = blockIdx.y;
    const int b = bh >> 4, h = bh & 15;
    const int lane = tid & 63, w = tid >> 6;
    const int fr = lane & 15, fk = lane >> 4;
    const size_t tok0 = (size_t)b * T;

    char* lds_kv = (char*)&KV[0];
    char* lds_sp = (char*)&Ss[0];

    bf16x8 qfh[4], qfl[4];
    {
        const size_t qoff = (tok0 + (size_t)qt * 64 + w * 16 + fr) * D_ + h * DH_ + fk * 8;
#pragma unroll
        for (int ks = 0; ks < 4; ++ks) {
            qfh[ks] = *(const bf16x8*)(QH + qoff + ks * 32);
            qfl[ks] = *(const bf16x8*)(QL + qoff + ks * 32);
        }
    }
    if (tid < 64) { mrow[tid] = -1e30f; lrow[tid] = 0.f; }

    f32x4 acc[8];
#pragma unroll
    for (int nt = 0; nt < 8; ++nt) acc[nt] = (f32x4)0.f;

    const int srow = tid >> 2, sslot = tid & 3;
    const size_t vbase = (size_t)bh * (size_t)(T >> 3) * 1024;

    for (int kt = 0; kt <= qt; ++kt) {
        __syncthreads();
#pragma unroll
        for (int it = 0; it < 4; ++it) {
            int c = tid + (it << 8);
            int t = c >> 4;
            int sp = (c & 15) ^ (t & 7);
            size_t goff = (tok0 + (size_t)kt * 64 + t) * D_ + h * DH_ + sp * 8;
            __builtin_amdgcn_global_load_lds((const __attribute__((address_space(1))) void*)(KH + goff),
                (__attribute__((address_space(3))) void*)(lds_kv + c * 16), 16, 0, 0);
            __builtin_amdgcn_global_load_lds((const __attribute__((address_space(1))) void*)(KL + goff),
                (__attribute__((address_space(3))) void*)(lds_kv + 16384 + c * 16), 16, 0, 0);
        }
        __syncthreads();
        {
            f32x4 s[4];
#pragma unroll
            for (int nt = 0; nt < 4; ++nt) s[nt] = (f32x4)0.f;
#pragma unroll
            for (int ks = 0; ks < 4; ++ks) {
#pragma unroll
                for (int nt = 0; nt < 4; ++nt) {
                    int n = nt * 16 + fr;
                    int offk = (n * 256 + ks * 64 + fk * 16) ^ ((n & 7) << 4);
                    bf16x8 kfh = *(const bf16x8*)(lds_kv + offk);
                    bf16x8 kfl = *(const bf16x8*)(lds_kv + 16384 + offk);
                    s[nt] = __builtin_amdgcn_mfma_f32_16x16x32_bf16(qfh[ks], kfh, s[nt], 0, 0, 0);
                    s[nt] = __builtin_amdgcn_mfma_f32_16x16x32_bf16(qfh[ks], kfl, s[nt], 0, 0, 0);
                    s[nt] = __builtin_amdgcn_mfma_f32_16x16x32_bf16(qfl[ks], kfh, s[nt], 0, 0, 0);
                }
            }
#pragma unroll
            for (int nt = 0; nt < 4; ++nt)
#pragma unroll
                for (int r = 0; r < 4; ++r) {
                    int row = w * 16 + fk * 4 + r;
                    int col = nt * 16 + fr;
                    *(float*)(lds_sp + ((row * 256 + col * 4) ^ ((row & 7) << 4))) = s[nt][r];
                }
        }
        __syncthreads();
#pragma unroll
        for (int it = 0; it < 4; ++it) {
            int c = tid + (it << 8);
            size_t goff = vbase + (size_t)kt * 8192 + (size_t)c * 8;
            __builtin_amdgcn_global_load_lds((const __attribute__((address_space(1))) void*)(VTH + goff),
                (__attribute__((address_space(3))) void*)(lds_kv + c * 16), 16, 0, 0);
            __builtin_amdgcn_global_load_lds((const __attribute__((address_space(1))) void*)(VTL + goff),
                (__attribute__((address_space(3))) void*)(lds_kv + 16384 + c * 16), 16, 0, 0);
        }
        float p[16];
        float newm, psum, cr, oldl;
        {
            float tmax = -1e30f;
            int colbase = sslot * 16;
#pragma unroll
            for (int q4 = 0; q4 < 4; ++q4) {
                f32x4 sv = *(const f32x4*)(lds_sp + ((srow * 256 + sslot * 64 + q4 * 16) ^ ((srow & 7) << 4)));
#pragma unroll
                for (int e = 0; e < 4; ++e) {
                    float v = sv[e];
                    if (kt == qt && (colbase + q4 * 4 + e) > srow) v = -1e30f;
                    p[q4 * 4 + e] = v;
                    tmax = fmaxf(tmax, v);
                }
            }
            tmax = fmaxf(tmax, __shfl_xor(tmax, 1, 64));
            tmax = fmaxf(tmax, __shfl_xor(tmax, 2, 64));
            float oldm = mrow[srow];
            oldl = lrow[srow];
            newm = fmaxf(oldm, tmax);
            psum = 0.f;
#pragma unroll
            for (int e = 0; e < 16; ++e) { p[e] = expf(p[e] - newm); psum += p[e]; }
            psum += __shfl_xor(psum, 1, 64);
            psum += __shfl_xor(psum, 2, 64);
            cr = expf(oldm - newm);
        }
        __syncthreads();
        {
            ushort8 h0, h1, l0, l1;
#pragma unroll
            for (int e = 0; e < 8; ++e) {
                unsigned short hb = bf16_rne(p[e]);
                h0[e] = hb; l0[e] = bf16_rne(p[e] - bf16_tof(hb));
                unsigned short hb2 = bf16_rne(p[8 + e]);
                h1[e] = hb2; l1[e] = bf16_rne(p[8 + e] - bf16_tof(hb2));
            }
            int base = srow * 128 + sslot * 32;
            int swz = (srow & 7) << 4;
            *(ushort8*)(lds_sp + (base ^ swz)) = h0;
            *(ushort8*)(lds_sp + ((base + 16) ^ swz)) = h1;
            *(ushort8*)(lds_sp + 8192 + (base ^ swz)) = l0;
            *(ushort8*)(lds_sp + 8192 + ((base + 16) ^ swz)) = l1;
            if (sslot == 0) { mrow[srow] = newm; lrow[srow] = oldl * cr + psum; crow[srow] = cr; }
        }
        __syncthreads();
        {
            f32x4 crv = *(const f32x4*)&crow[w * 16 + fk * 4];
#pragma unroll
            for (int nt = 0; nt < 8; ++nt)
#pragma unroll
                for (int r = 0; r < 4; ++r) acc[nt][r] *= crv[r];
            int m = w * 16 + fr;
#pragma unroll
            for (int ks = 0; ks < 2; ++ks) {
                int offp = (m * 128 + ks * 64 + fk * 16) ^ ((m & 7) << 4);
                bf16x8 pfh = *(const bf16x8*)(lds_sp + offp);
                bf16x8 pfl = *(const bf16x8*)(lds_sp + 8192 + offp);
#pragma unroll
                for (int nt = 0; nt < 8; ++nt) {
                    int offv = (ks * 4 + fk) * 2048 + (nt * 16 + fr) * 16;
                    bf16x8 vfh = *(const bf16x8*)(lds_kv + offv);
                    bf16x8 vfl = *(const bf16x8*)(lds_kv + 16384 + offv);
                    acc[nt] = __builtin_amdgcn_mfma_f32_16x16x32_bf16(pfh, vfh, acc[nt], 0, 0, 0);
                    acc[nt] = __builtin_amdgcn_mfma_f32_16x16x32_bf16(pfh, vfl, acc[nt], 0, 0, 0);
                    acc[nt] = __builtin_amdgcn_mfma_f32_16x16x32_bf16(pfl, vfh, acc[nt], 0, 0, 0);
                }
            }
        }
    }
    __syncthreads();
    {
        f32x4 lv = *(const f32x4*)&lrow[w * 16 + fk * 4];
        float* orow = O + (tok0 + (size_t)qt * 64 + w * 16 + fk * 4) * D_ + h * DH_;
#pragma unroll
        for (int r = 0; r < 4; ++r) {
            float inv = 1.0f / lv[r];
#pragma unroll
            for (int nt = 0; nt < 8; ++nt)
                orow[(size_t)r * D_ + nt * 16 + fr] = acc[nt][r] * inv;
        }
    }
}

// ---------------- f32 GEMM (fallback path) ----------------
template<int EPI>
__global__ __launch_bounds__(256) void gemm128(const float* __restrict__ A,
                                               const float* __restrict__ Bm,
                                               float* __restrict__ C,
                                               const float* __restrict__ Rg,
                                               int M, int N, int K) {
    __shared__ float Ast[16][132];
    __shared__ float Bs[16][132];
    int bm = blockIdx.y << 7, bn = blockIdx.x << 7;
    int tid = threadIdx.x;
    int ty = tid >> 4, tx = tid & 15;
    float acc[8][8];
#pragma unroll
    for (int i = 0; i < 8; ++i)
#pragma unroll
        for (int j = 0; j < 8; ++j) acc[i][j] = 0.f;

    for (int k0 = 0; k0 < K; k0 += 16) {
#pragma unroll
        for (int it = 0; it < 2; ++it) {
            int idx = tid + (it << 8);
            int ar = idx >> 2, ac = idx & 3;
            float4 av = *(const float4*)(A + (size_t)(bm + ar) * K + k0 + (ac << 2));
            Ast[ac*4+0][ar] = av.x; Ast[ac*4+1][ar] = av.y;
            Ast[ac*4+2][ar] = av.z; Ast[ac*4+3][ar] = av.w;
            int br = idx >> 5, bc = idx & 31;
            float4 bv = *(const float4*)(Bm + (size_t)(k0 + br) * N + bn + (bc << 2));
            *(float4*)&Bs[br][bc << 2] = bv;
        }
        __syncthreads();
#pragma unroll
        for (int kk = 0; kk < 16; ++kk) {
            float a[8], b[8];
            *(float4*)&a[0] = *(const float4*)&Ast[kk][ty*4];
            *(float4*)&a[4] = *(const float4*)&Ast[kk][64 + ty*4];
            *(float4*)&b[0] = *(const float4*)&Bs[kk][tx*4];
            *(float4*)&b[4] = *(const float4*)&Bs[kk][64 + tx*4];
#pragma unroll
            for (int i = 0; i < 8; ++i)
#pragma unroll
                for (int j = 0; j < 8; ++j)
                    acc[i][j] += a[i] * b[j];
        }
        __syncthreads();
    }
#pragma unroll
    for (int i = 0; i < 8; ++i) {
        int row = bm + ((i < 4) ? (ty*4 + i) : (64 + ty*4 + (i - 4)));
#pragma unroll
        for (int half = 0; half < 2; ++half) {
            int col = bn + half*64 + tx*4;
            size_t off = (size_t)row * N + col;
            const float* ap = &acc[i][half*4];
            float4 r;
            if (EPI == 0) {
                r.x = ap[0]; r.y = ap[1]; r.z = ap[2]; r.w = ap[3];
            } else if (EPI == 1) {
                float4 rv = *(const float4*)(Rg + off);
                r.x = ap[0] + rv.x; r.y = ap[1] + rv.y;
                r.z = ap[2] + rv.z; r.w = ap[3] + rv.w;
            } else {
                float4 gv = *(const float4*)(Rg + off);
                r.x = silu_f(gv.x) * ap[0]; r.y = silu_f(gv.y) * ap[1];
                r.z = silu_f(gv.z) * ap[2]; r.w = silu_f(gv.w) * ap[3];
            }
            *(float4*)(C + off) = r;
        }
    }
}

// ---------------- RoPE in place (f32, fallback) ----------------
__global__ __launch_bounds__(256) void rope_kernel(float* __restrict__ q, int nrows, int seqlen) {
    int gid = blockIdx.x * 256 + threadIdx.x;
    int tok = gid >> 10;
    if (tok >= nrows) return;
    int rest = gid & 1023;
    int h = rest >> 6, i = rest & 63;
    int pos = tok % seqlen;
    float e = (float)(2 * i) * (1.0f / 128.0f);
    float inv = 1.0f / powf(10000.0f, e);
    float ang = (float)pos * inv;
    float c = cosf(ang), s = sinf(ang);
    size_t base = (size_t)tok * D_ + h * 128 + i;
    float x1 = q[base], x2 = q[base + 64];
    q[base]      = x1 * c - x2 * s;
    q[base + 64] = x2 * c + x1 * s;
}

// ---------------- flash attention f32 (fallback) ----------------
__global__ __launch_bounds__(256) void attn_kernel(const float* __restrict__ Q,
                                                   const float* __restrict__ K,
                                                   const float* __restrict__ V,
                                                   float* __restrict__ O,
                                                   int T) {
    int qt = blockIdx.x;
    int bh = blockIdx.y;
    int b = bh >> 4, h = bh & 15;
    int tid = threadIdx.x;

    __shared__ float4 Qs[32][32];
    __shared__ float4 KVs[64][32];
    __shared__ float Sst[32][65];
    __shared__ float mrow[32], lrow[32], crow[32];

    const size_t headoff = (size_t)h * DH_;
    const size_t bbase = (size_t)b * T * D_;

#pragma unroll
    for (int i = 0; i < 4; ++i) {
        int idx = tid + i * 256;
        int r = idx >> 5, ch = idx & 31;
        const float4* src = (const float4*)(Q + bbase + (size_t)(qt*32 + r) * D_ + headoff);
        Qs[r][ch ^ ((r >> 2) & 7)] = src[ch];
    }
    if (tid < 32) { mrow[tid] = -1e30f; lrow[tid] = 0.f; }

    int ty16 = tid >> 4, tx16 = tid & 15;
    int r8 = tid >> 3, q8 = tid & 7;
    float o[2][8];
#pragma unroll
    for (int i = 0; i < 2; ++i)
#pragma unroll
        for (int j = 0; j < 8; ++j) o[i][j] = 0.f;

    int ktmax = (qt * 32 + 31) >> 6;
    for (int kt = 0; kt <= ktmax; ++kt) {
        __syncthreads();
#pragma unroll
        for (int i = 0; i < 8; ++i) {
            int idx = tid + i * 256;
            int r = idx >> 5, ch = idx & 31;
            const float4* src = (const float4*)(K + bbase + (size_t)(kt*64 + r) * D_ + headoff);
            KVs[r][ch ^ ((r >> 2) & 7)] = src[ch];
        }
        __syncthreads();
        {
            float s[2][4];
#pragma unroll
            for (int i = 0; i < 2; ++i)
#pragma unroll
                for (int j = 0; j < 4; ++j) s[i][j] = 0.f;
#pragma unroll
            for (int ch = 0; ch < 32; ++ch) {
                float4 qv[2], kv[4];
#pragma unroll
                for (int i = 0; i < 2; ++i) { int r = ty16*2 + i; qv[i] = Qs[r][ch ^ ((r >> 2) & 7)]; }
#pragma unroll
                for (int j = 0; j < 4; ++j) { int c = tx16*4 + j; kv[j] = KVs[c][ch ^ ((c >> 2) & 7)]; }
#pragma unroll
                for (int i = 0; i < 2; ++i)
#pragma unroll
                    for (int j = 0; j < 4; ++j)
                        s[i][j] += qv[i].x*kv[j].x + qv[i].y*kv[j].y + qv[i].z*kv[j].z + qv[i].w*kv[j].w;
            }
#pragma unroll
            for (int i = 0; i < 2; ++i) {
                int grow = qt*32 + ty16*2 + i;
#pragma unroll
                for (int j = 0; j < 4; ++j) {
                    int gcol = kt*64 + tx16*4 + j;
                    float sv = s[i][j] * SCALE_QK;
                    if (gcol > grow) sv = -1e30f;
                    Sst[ty16*2 + i][tx16*4 + j] = sv;
                }
            }
        }
        __syncthreads();
#pragma unroll
        for (int i = 0; i < 8; ++i) {
            int idx = tid + i * 256;
            int r = idx >> 5, ch = idx & 31;
            const float4* src = (const float4*)(V + bbase + (size_t)(kt*64 + r) * D_ + headoff);
            KVs[r][ch ^ ((r >> 2) & 7)] = src[ch];
        }
        {
            float pv[8];
            float tmax = -1e30f;
#pragma unroll
            for (int c = 0; c < 8; ++c) { pv[c] = Sst[r8][q8*8 + c]; tmax = fmaxf(tmax, pv[c]); }
#pragma unroll
            for (int m = 1; m < 8; m <<= 1) tmax = fmaxf(tmax, __shfl_xor(tmax, m, 64));
            float oldm = mrow[r8];
            float newm = fmaxf(oldm, tmax);
            float psum = 0.f;
#pragma unroll
            for (int c = 0; c < 8; ++c) {
                float p = expf(pv[c] - newm);
                Sst[r8][q8*8 + c] = p;
                psum += p;
            }
#pragma unroll
            for (int m = 1; m < 8; m <<= 1) psum += __shfl_xor(psum, m, 64);
            if (q8 == 0) {
                float crv = expf(oldm - newm);
                crow[r8] = crv;
                lrow[r8] = lrow[r8] * crv + psum;
                mrow[r8] = newm;
            }
        }
        __syncthreads();
        {
            float crv[2];
#pragma unroll
            for (int i = 0; i < 2; ++i) {
                crv[i] = crow[ty16*2 + i];
#pragma unroll
                for (int j = 0; j < 8; ++j) o[i][j] *= crv[i];
            }
#pragma unroll
            for (int kc = 0; kc < 64; ++kc) {
                int swz = (kc >> 2) & 7;
                float4 v0 = KVs[kc][tx16 ^ swz];
                float4 v1 = KVs[kc][(16 + tx16) ^ swz];
#pragma unroll
                for (int i = 0; i < 2; ++i) {
                    float p = Sst[ty16*2 + i][kc];
                    o[i][0] += p*v0.x; o[i][1] += p*v0.y; o[i][2] += p*v0.z; o[i][3] += p*v0.w;
                    o[i][4] += p*v1.x; o[i][5] += p*v1.y; o[i][6] += p*v1.z; o[i][7] += p*v1.w;
                }
            }
        }
    }
#pragma unroll
    for (int i = 0; i < 2; ++i) {
        int r = ty16*2 + i;
        float inv = 1.0f / lrow[r];
        float4 a, bb;
        a.x = o[i][0]*inv; a.y = o[i][1]*inv; a.z = o[i][2]*inv; a.w = o[i][3]*inv;
        bb.x = o[i][4]*inv; bb.y = o[i][5]*inv; bb.z = o[i][6]*inv; bb.w = o[i][7]*inv;
        float* dst = O + bbase + (size_t)(qt*32 + r) * D_ + headoff;
        ((float4*)dst)[tx16] = a;
        ((float4*)dst)[16 + tx16] = bb;
    }
}

// ---------------- router / loss / topk / gather / copy / scatter ----------------
__global__ __launch_bounds__(256) void router_kernel(const float* __restrict__ x,
                                                     const float* __restrict__ proc,
                                                     const float* __restrict__ prior,
                                                     float* __restrict__ gbuf,
                                                     float* __restrict__ dchbuf,
                                                     float* __restrict__ gout) {
    int row = blockIdx.x, tid = threadIdx.x;
    const float4* x4 = (const float4*)(x + (size_t)row * D_);
    const float4* p4 = (const float4*)(proc + (size_t)row * D_);
    const float4* r4 = (const float4*)(prior + (size_t)row * D_);
    float sst = 0.f, sch = 0.f;
#pragma unroll
    for (int it = 0; it < 2; ++it) {
        int i = tid + it * 256;
        float4 xv = x4[i], pv = p4[i], rv = r4[i];
        float a0 = pv.x - xv.x, a1 = pv.y - xv.y, a2 = pv.z - xv.z, a3 = pv.w - xv.w;
        sst += a0*a0 + a1*a1 + a2*a2 + a3*a3;
        float d0 = a0 - rv.x, d1 = a1 - rv.y, d2 = a2 - rv.z, d3 = a3 - rv.w;
        sch += d0*d0 + d1*d1 + d2*d2 + d3*d3;
    }
    __shared__ float rs[256], rc[256];
    rs[tid] = sst; rc[tid] = sch; __syncthreads();
    for (int off = 128; off > 0; off >>= 1) {
        if (tid < off) { rs[tid] += rs[tid + off]; rc[tid] += rc[tid + off]; }
        __syncthreads();
    }
    if (tid == 0) {
        float Dst = rs[0] * (1.0f/2048.0f);
        float Dch = rc[0] * (1.0f/2048.0f);
        float g = 1.0f / (1.0f + expf(-(Dch - Dst)));
        gbuf[row] = g; dchbuf[row] = Dch; gout[row] = g;
    }
}

__global__ __launch_bounds__(1024) void loss_kernel(const float* __restrict__ dch, float* __restrict__ out) {
    __shared__ float red[1024];
    int tid = threadIdx.x;
    red[tid] = dch[tid] + dch[tid + 1024] + dch[tid + 2048] + dch[tid + 3072];
    __syncthreads();
    for (int off = 512; off > 0; off >>= 1) {
        if (tid < off) red[tid] += red[tid + off];
        __syncthreads();
    }
    if (tid == 0) out[0] = red[0] * (1.0f / 4096.0f);
}

__global__ __launch_bounds__(1024) void topk_kernel(const float* __restrict__ gbuf,
                                                    int* __restrict__ idxout,
                                                    float* __restrict__ gateout) {
    int b = blockIdx.x, tid = threadIdx.x;
    __shared__ float val[2048];
    __shared__ int idx[2048];
    val[tid] = gbuf[b*2048 + tid];           idx[tid] = tid;
    val[tid + 1024] = gbuf[b*2048 + tid + 1024]; idx[tid + 1024] = tid + 1024;
    __syncthreads();
    for (int kk = 2; kk <= 2048; kk <<= 1) {
        for (int j = kk >> 1; j > 0; j >>= 1) {
            for (int i = tid; i < 2048; i += 1024) {
                int ixj = i ^ j;
                if (ixj > i) {
                    bool up = ((i & kk) == 0);
                    float v1 = val[i], v2 = val[ixj];
                    int i1 = idx[i], i2 = idx[ixj];
                    bool sw = up ? ((v2 > v1) || (v2 == v1 && i2 < i1))
                                 : ((v1 > v2) || (v1 == v2 && i1 < i2));
                    if (sw) { val[i] = v2; val[ixj] = v1; idx[i] = i2; idx[ixj] = i1; }
                }
            }
            __syncthreads();
        }
    }
    if (tid < 1024) {
        idxout[b*1024 + tid] = idx[tid];
        gateout[b*1024 + tid] = val[tid];
    }
}

__global__ __launch_bounds__(256) void gather_kernel(const float* __restrict__ proc,
                                                     const int* __restrict__ idx,
                                                     float* __restrict__ sel) {
    int r = blockIdx.x;
    int b = r >> 10, rr = r & 1023;
    int tok = idx[b*1024 + rr];
    const float4* src = (const float4*)(proc + ((size_t)(b*2048 + tok)) * D_);
    float4* dst = (float4*)(sel + (size_t)r * D_);
    dst[threadIdx.x] = src[threadIdx.x];
    dst[threadIdx.x + 256] = src[threadIdx.x + 256];
}

__global__ __launch_bounds__(256) void copy_kernel(const float* __restrict__ src,
                                                   float* __restrict__ dst, int n4) {
    int i = blockIdx.x * 256 + threadIdx.x;
    if (i < n4) ((float4*)dst)[i] = ((const float4*)src)[i];
}

__global__ __launch_bounds__(256) void scatter_kernel(const float* __restrict__ sel,
                                                      const float* __restrict__ selout,
                                                      const int* __restrict__ idx,
                                                      const float* __restrict__ gate,
                                                      float* __restrict__ outp) {
    int r = blockIdx.x;
    int b = r >> 10, rr = r & 1023;
    int tok = idx[b*1024 + rr];
    float g = gate[b*1024 + rr];
    const float4* s4 = (const float4*)(sel + (size_t)r * D_);
    const float4* o4 = (const float4*)(selout + (size_t)r * D_);
    float4* d4 = (float4*)(outp + ((size_t)(b*2048 + tok)) * D_);
#pragma unroll
    for (int it = 0; it < 2; ++it) {
        int i = threadIdx.x + it * 256;
        float4 a = s4[i], o = o4[i];
        float4 w;
        w.x = a.x + g*(o.x - a.x); w.y = a.y + g*(o.y - a.y);
        w.z = a.z + g*(o.z - a.z); w.w = a.w + g*(o.w - a.w);
        d4[i] = w;
    }
}

extern "C" void kernel_launch(void* const* d_in, const int* in_sizes, int n_in,
                              void* d_out, int out_size, void* d_ws, size_t ws_size,
                              hipStream_t stream) {
    const float* X      = (const float*)d_in[0];
    const float* d1_ln1 = (const float*)d_in[1];
    const float* d1_ln2 = (const float*)d_in[2];
    const float* d1_wq  = (const float*)d_in[3];
    const float* d1_wk  = (const float*)d_in[4];
    const float* d1_wv  = (const float*)d_in[5];
    const float* d1_wo  = (const float*)d_in[6];
    const float* d1_wg  = (const float*)d_in[7];
    const float* d1_wu  = (const float*)d_in[8];
    const float* d1_wd  = (const float*)d_in[9];
    const float* d2_ln1 = (const float*)d_in[10];
    const float* d2_ln2 = (const float*)d_in[11];
    const float* d2_wq  = (const float*)d_in[12];
    const float* d2_wk  = (const float*)d_in[13];
    const float* d2_wv  = (const float*)d_in[14];
    const float* d2_wo  = (const float*)d_in[15];
    const float* d2_wg  = (const float*)d_in[16];
    const float* d2_wu  = (const float*)d_in[17];
    const float* d2_wd  = (const float*)d_in[18];
    const float* p_ln   = (const float*)d_in[19];
    const float* p_wg   = (const float*)d_in[20];
    const float* p_wu   = (const float*)d_in[21];
    const float* p_wd   = (const float*)d_in[22];

    float* out = (float*)d_out;
    float* ws  = (float*)d_ws;

    const size_t BIG = (size_t)NTOK_ * D_;           // 8M f32
    const size_t MEG = 1024 * 1024;

    const size_t NEED_NEW = (128 * MEG + 16384) * 4;  // ~512 MB
    const size_t NEED_OLD = ((5*BIG + (size_t)NTOK_*FF_ + 12288) * 4);

    if (ws_size >= NEED_NEW) {
        float* BUF0 = ws;                 // 8M f32
        float* BUF1 = ws + 8*MEG;         // q
        float* BUF2 = ws + 16*MEG;        // k / h
        float* BUF3 = ws + 24*MEG;        // v / prior_out / sel_out
        float* BUF4 = ws + 32*MEG;        // attnout / sel (+V2)
        float* BUFF = ws + 40*MEG;        // 32M f32 FF
        unsigned short* PWhi  = (unsigned short*)(ws + 72*MEG);
        unsigned short* PWlo  = (unsigned short*)(ws + 80*MEG);
        unsigned short* PAhi  = (unsigned short*)(ws + 88*MEG);
        unsigned short* PAlo  = (unsigned short*)(ws + 92*MEG);
        unsigned short* PFhi  = (unsigned short*)(ws + 96*MEG);
        unsigned short* PFlo  = (unsigned short*)(ws + 112*MEG);
        // attention packed buffers (overlay PF region; disjoint in time)
        unsigned short* U   = (unsigned short*)(ws + 96*MEG);
        const size_t PK = (size_t)NTOK_ * D_;         // 8.39M ushorts
        unsigned short* QHp = U;
        unsigned short* QLp = U + PK;
        unsigned short* KHp = U + 2*PK;
        unsigned short* KLp = U + 3*PK;
        unsigned short* VTH = U + 4*PK;
        unsigned short* VTL = U + 5*PK;
        float* SM   = ws + 128*MEG;
        float* gbuf = SM;
        float* dch  = SM + 4096;
        float* gate = SM + 8192;
        int*   idxb = (int*)(SM + 10240);

        float* PROC = out;                // processed lives directly in out

        // ---- decision decoder layer (bf16x3 GEMMs + bf16x3 MFMA attention) ----
        rms_kernel<<<NTOK_, 256, 0, stream>>>(X, d1_ln1, BUF0);
        splita_kernel<1><<<dim3(64, 32), 256, 0, stream>>>(BUF0, PAhi, PAlo, NTOK_, D_);
        splitw_kernel<1><<<dim3(32, 32), 256, 0, stream>>>(d1_wq, PWhi, PWlo, D_, D_);
        gemm_mfma<3,0><<<dim3(16, 32), 256, 0, stream>>>(PAhi, PAlo, PWhi, PWlo, BUF1, nullptr, nullptr, nullptr, NTOK_, D_, D_);
        splitw_kernel<1><<<dim3(32, 32), 256, 0, stream>>>(d1_wk, PWhi, PWlo, D_, D_);
        gemm_mfma<3,0><<<dim3(16, 32), 256, 0, stream>>>(PAhi, PAlo, PWhi, PWlo, BUF2, nullptr, nullptr, nullptr, NTOK_, D_, D_);
        splitw_kernel<1><<<dim3(32, 32), 256, 0, stream>>>(d1_wv, PWhi, PWlo, D_, D_);
        gemm_mfma<3,0><<<dim3(16, 32), 256, 0, stream>>>(PAhi, PAlo, PWhi, PWlo, BUF3, nullptr, nullptr, nullptr, NTOK_, D_, D_);
        rope_split_kernel<<<NTOK_, 256, 0, stream>>>(BUF1, QHp, QLp, T_ - 1, SCALE_QK);
        rope_split_kernel<<<NTOK_, 256, 0, stream>>>(BUF2, KHp, KLp, T_ - 1, 1.0f);
        vpack_kernel<<<dim3(T_/64, B_*H_), 256, 0, stream>>>(BUF3, VTH, VTL, T_);
        attn_mfma<<<dim3(T_/64, B_*H_), 256, 0, stream>>>(QHp, QLp, KHp, KLp, VTH, VTL, BUF4, T_);
        splita_kernel<1><<<dim3(64, 32), 256, 0, stream>>>(BUF4, PAhi, PAlo, NTOK_, D_);
        splitw_kernel<1><<<dim3(32, 32), 256, 0, stream>>>(d1_wo, PWhi, PWlo, D_, D_);
        gemm_mfma<3,1><<<dim3(16, 32), 256, 0, stream>>>(PAhi, PAlo, PWhi, PWlo, BUF2, X, nullptr, nullptr, NTOK_, D_, D_);  // h
        rms_kernel<<<NTOK_, 256, 0, stream>>>(BUF2, d1_ln2, BUF0);
        splita_kernel<1><<<dim3(64, 32), 256, 0, stream>>>(BUF0, PAhi, PAlo, NTOK_, D_);
        splitw_kernel<1><<<dim3(128, 32), 256, 0, stream>>>(d1_wg, PWhi, PWlo, D_, FF_);
        gemm_mfma<3,0><<<dim3(64, 32), 256, 0, stream>>>(PAhi, PAlo, PWhi, PWlo, BUFF, nullptr, nullptr, nullptr, NTOK_, FF_, D_);
        splitw_kernel<1><<<dim3(128, 32), 256, 0, stream>>>(d1_wu, PWhi, PWlo, D_, FF_);
        gemm_mfma<3,3><<<dim3(64, 32), 256, 0, stream>>>(PAhi, PAlo, PWhi, PWlo, nullptr, BUFF, PFhi, PFlo, NTOK_, FF_, D_);  // silu(wg)*wu -> packed
        splitw_kernel<1><<<dim3(32, 128), 256, 0, stream>>>(d1_wd, PWhi, PWlo, FF_, D_);
        gemm_mfma<3,1><<<dim3(16, 32), 256, 0, stream>>>(PFhi, PFlo, PWhi, PWlo, PROC, BUF2, nullptr, nullptr, NTOK_, D_, FF_); // processed -> out

        // ---- prior network (bf16x3) ----
        rms_kernel<<<NTOK_, 256, 0, stream>>>(X, p_ln, BUF0);
        splita_kernel<1><<<dim3(64, 32), 256, 0, stream>>>(BUF0, PAhi, PAlo, NTOK_, D_);
        splitw_kernel<1><<<dim3(16, 32), 256, 0, stream>>>(p_wg, PWhi, PWlo, D_, PFF_);
        gemm_mfma<3,0><<<dim3(8, 32), 256, 0, stream>>>(PAhi, PAlo, PWhi, PWlo, BUFF, nullptr, nullptr, nullptr, NTOK_, PFF_, D_);
        splitw_kernel<1><<<dim3(16, 32), 256, 0, stream>>>(p_wu, PWhi, PWlo, D_, PFF_);
        gemm_mfma<3,3><<<dim3(8, 32), 256, 0, stream>>>(PAhi, PAlo, PWhi, PWlo, nullptr, BUFF, PFhi, PFlo, NTOK_, PFF_, D_);
        splitw_kernel<1><<<dim3(32, 16), 256, 0, stream>>>(p_wd, PWhi, PWlo, PFF_, D_);
        gemm_mfma<3,0><<<dim3(16, 32), 256, 0, stream>>>(PFhi, PFlo, PWhi, PWlo, BUF3, nullptr, nullptr, nullptr, NTOK_, D_, PFF_); // prior_out

        // ---- router + loss + top-k + gather ----
        router_kernel<<<NTOK_, 256, 0, stream>>>(X, PROC, BUF3, gbuf, dch, out + 8388609);
        loss_kernel<<<1, 1024, 0, stream>>>(dch, out + 8388608);
        topk_kernel<<<B_, 1024, 0, stream>>>(gbuf, idxb, gate);
        gather_kernel<<<NSEL_, 256, 0, stream>>>(PROC, idxb, BUF4);   // sel

        // ---- dynamic decoder layer (bf16 NP=1 GEMMs, x3 MFMA attention) ----
        float* V2 = BUF4 + (size_t)NSEL_ * D_;
        rms_kernel<<<NSEL_, 256, 0, stream>>>(BUF4, d2_ln1, BUF0);
        splita_kernel<0><<<dim3(32, 32), 256, 0, stream>>>(BUF0, PAhi, PAlo, NSEL_, D_);
        splitw_kernel<0><<<dim3(32, 32), 256, 0, stream>>>(d2_wq, PWhi, PWlo, D_, D_);
        gemm_mfma<1,0><<<dim3(16, 16), 256, 0, stream>>>(PAhi, PAlo, PWhi, PWlo, BUF2, nullptr, nullptr, nullptr, NSEL_, D_, D_);
        splitw_kernel<0><<<dim3(32, 32), 256, 0, stream>>>(d2_wk, PWhi, PWlo, D_, D_);
        gemm_mfma<1,0><<<dim3(16, 16), 256, 0, stream>>>(PAhi, PAlo, PWhi, PWlo, BUF3, nullptr, nullptr, nullptr, NSEL_, D_, D_);
        splitw_kernel<0><<<dim3(32, 32), 256, 0, stream>>>(d2_wv, PWhi, PWlo, D_, D_);
        gemm_mfma<1,0><<<dim3(16, 16), 256, 0, stream>>>(PAhi, PAlo, PWhi, PWlo, V2, nullptr, nullptr, nullptr, NSEL_, D_, D_);
        rope_split_kernel<<<NSEL_, 256, 0, stream>>>(BUF2, QHp, QLp, T2_ - 1, SCALE_QK);
        rope_split_kernel<<<NSEL_, 256, 0, stream>>>(BUF3, KHp, KLp, T2_ - 1, 1.0f);
        vpack_kernel<<<dim3(T2_/64, B_*H_), 256, 0, stream>>>(V2, VTH, VTL, T2_);
        attn_mfma<<<dim3(T2_/64, B_*H_), 256, 0, stream>>>(QHp, QLp, KHp, KLp, VTH, VTL, BUF0, T2_);
        splita_kernel<0><<<dim3(32, 32), 256, 0, stream>>>(BUF0, PAhi, PAlo, NSEL_, D_);
        splitw_kernel<0><<<dim3(32, 32), 256, 0, stream>>>(d2_wo, PWhi, PWlo, D_, D_);
        gemm_mfma<1,1><<<dim3(16, 16), 256, 0, stream>>>(PAhi, PAlo, PWhi, PWlo, BUF2, BUF4, nullptr, nullptr, NSEL_, D_, D_); // h2
        rms_kernel<<<NSEL_, 256, 0, stream>>>(BUF2, d2_ln2, BUF0);
        splita_kernel<0><<<dim3(32, 32), 256, 0, stream>>>(BUF0, PAhi, PAlo, NSEL_, D_);
        splitw_kernel<0><<<dim3(128, 32), 256, 0, stream>>>(d2_wg, PWhi, PWlo, D_, FF_);
        gemm_mfma<1,0><<<dim3(64, 16), 256, 0, stream>>>(PAhi, PAlo, PWhi, PWlo, BUFF, nullptr, nullptr, nullptr, NSEL_, FF_, D_);
        splitw_kernel<0><<<dim3(128, 32), 256, 0, stream>>>(d2_wu, PWhi, PWlo, D_, FF_);
        gemm_mfma<1,4><<<dim3(64, 16), 256, 0, stream>>>(PAhi, PAlo, PWhi, PWlo, nullptr, BUFF, PFhi, nullptr, NSEL_, FF_, D_);  // silu(wg)*wu -> packed hi
        splitw_kernel<0><<<dim3(32, 128), 256, 0, stream>>>(d2_wd, PWhi, PWlo, FF_, D_);
        gemm_mfma<1,1><<<dim3(16, 16), 256, 0, stream>>>(PFhi, PFlo, PWhi, PWlo, BUF3, BUF2, nullptr, nullptr, NSEL_, D_, FF_); // sel_out

        scatter_kernel<<<NSEL_, 256, 0, stream>>>(BUF4, BUF3, idxb, gate, out);
        return;
    }

    if (ws_size < NEED_OLD) return;

    // ================= fallback: f32 path =================
    float* BUF0 = ws;
    float* BUF1 = ws + BIG;
    float* BUF2 = ws + 2*BIG;
    float* BUF3 = ws + 3*BIG;
    float* BUF4 = ws + 4*BIG;
    float* BUFF = ws + 5*BIG;
    float* SM   = BUFF + (size_t)NTOK_ * FF_;
    float* gbuf = SM;
    float* dch  = SM + 4096;
    float* gate = SM + 8192;
    int*   idxb = (int*)(SM + 10240);

    rms_kernel<<<NTOK_, 256, 0, stream>>>(X, d1_ln1, BUF0);
    gemm128<0><<<dim3(16, 32), 256, 0, stream>>>(BUF0, d1_wq, BUF1, nullptr, NTOK_, D_, D_);
    gemm128<0><<<dim3(16, 32), 256, 0, stream>>>(BUF0, d1_wk, BUF2, nullptr, NTOK_, D_, D_);
    gemm128<0><<<dim3(16, 32), 256, 0, stream>>>(BUF0, d1_wv, BUF3, nullptr, NTOK_, D_, D_);
    rope_kernel<<<NTOK_*4, 256, 0, stream>>>(BUF1, NTOK_, T_);
    rope_kernel<<<NTOK_*4, 256, 0, stream>>>(BUF2, NTOK_, T_);
    attn_kernel<<<dim3(T_/32, B_*H_), 256, 0, stream>>>(BUF1, BUF2, BUF3, BUF4, T_);
    gemm128<1><<<dim3(16, 32), 256, 0, stream>>>(BUF4, d1_wo, BUF2, X, NTOK_, D_, D_);
    rms_kernel<<<NTOK_, 256, 0, stream>>>(BUF2, d1_ln2, BUF0);
    gemm128<0><<<dim3(64, 32), 256, 0, stream>>>(BUF0, d1_wg, BUFF, nullptr, NTOK_, FF_, D_);
    gemm128<2><<<dim3(64, 32), 256, 0, stream>>>(BUF0, d1_wu, BUFF, BUFF, NTOK_, FF_, D_);
    gemm128<1><<<dim3(16, 32), 256, 0, stream>>>(BUFF, d1_wd, BUF1, BUF2, NTOK_, D_, FF_);

    rms_kernel<<<NTOK_, 256, 0, stream>>>(X, p_ln, BUF0);
    gemm128<0><<<dim3(8, 32), 256, 0, stream>>>(BUF0, p_wg, BUF4, nullptr, NTOK_, PFF_, D_);
    gemm128<2><<<dim3(8, 32), 256, 0, stream>>>(BUF0, p_wu, BUF4, BUF4, NTOK_, PFF_, D_);
    gemm128<0><<<dim3(16, 32), 256, 0, stream>>>(BUF4, p_wd, BUF3, nullptr, NTOK_, D_, PFF_);

    router_kernel<<<NTOK_, 256, 0, stream>>>(X, BUF1, BUF3, gbuf, dch, out + 8388609);
    loss_kernel<<<1, 1024, 0, stream>>>(dch, out + 8388608);
    topk_kernel<<<B_, 1024, 0, stream>>>(gbuf, idxb, gate);
    gather_kernel<<<NSEL_, 256, 0, stream>>>(BUF1, idxb, BUF4);

    float* V2 = BUF4 + (size_t)NSEL_ * D_;
    rms_kernel<<<NSEL_, 256, 0, stream>>>(BUF4, d2_ln1, BUF0);
    gemm128<0><<<dim3(16, 16), 256, 0, stream>>>(BUF0, d2_wq, BUF2, nullptr, NSEL_, D_, D_);
    gemm128<0><<<dim3(16, 16), 256, 0, stream>>>(BUF0, d2_wk, BUF3, nullptr, NSEL_, D_, D_);
    gemm128<0><<<dim3(16, 16), 256, 0, stream>>>(BUF0, d2_wv, V2, nullptr, NSEL_, D_, D_);
    rope_kernel<<<NSEL_*4, 256, 0, stream>>>(BUF2, NSEL_, T2_);
    rope_kernel<<<NSEL_*4, 256, 0, stream>>>(BUF3, NSEL_, T2_);
    attn_kernel<<<dim3(T2_/32, B_*H_), 256, 0, stream>>>(BUF2, BUF3, V2, BUF0, T2_);
    gemm128<1><<<dim3(16, 16), 256, 0, stream>>>(BUF0, d2_wo, BUF2, BUF4, NSEL_, D_, D_);
    rms_kernel<<<NSEL_, 256, 0, stream>>>(BUF2, d2_ln2, BUF0);
    gemm128<0><<<dim3(64, 16), 256, 0, stream>>>(BUF0, d2_wg, BUFF, nullptr, NSEL_, FF_, D_);
    gemm128<2><<<dim3(64, 16), 256, 0, stream>>>(BUF0, d2_wu, BUFF, BUFF, NSEL_, FF_, D_);
    gemm128<1><<<dim3(16, 16), 256, 0, stream>>>(BUFF, d2_wd, BUF3, BUF2, NSEL_, D_, FF_);

    copy_kernel<<<8192, 256, 0, stream>>>(BUF1, out, (int)(BIG / 4));
    scatter_kernel<<<NSEL_, 256, 0, stream>>>(BUF4, BUF3, idxb, gate, out);
}

// Round 13
// 3076.883 us; speedup vs baseline: 1.0532x; 1.0000x over previous
//
#include <hip/hip_runtime.h>
#include <math.h>

#define D_    2048
#define H_    16
#define DH_   128
#define FF_   8192
#define PFF_  1024
#define B_    2
#define T_    2048
#define NTOK_ 4096
#define T2_   1024
#define NSEL_ 2048
#define EPS_  1e-6f
#define SCALE_QK 0.08838834764831845f  // 1/sqrt(128)

typedef __attribute__((ext_vector_type(8))) short bf16x8;
typedef __attribute__((ext_vector_type(4))) float f32x4;
typedef __attribute__((ext_vector_type(8))) unsigned short ushort8;

__device__ __forceinline__ float silu_f(float x) {
    return x / (1.0f + expf(-x));
}

__device__ __forceinline__ unsigned short bf16_rne(float f) {
    unsigned int u = __float_as_uint(f);
    unsigned int r = (u + 0x7fffu + ((u >> 16) & 1u)) >> 16;
    return (unsigned short)r;
}
__device__ __forceinline__ float bf16_tof(unsigned short h) {
    return __uint_as_float(((unsigned int)h) << 16);
}

// ---------------- RMSNorm: one block per row (fallback path only) ----------------
__global__ __launch_bounds__(256) void rms_kernel(const float* __restrict__ x,
                                                  const float* __restrict__ w,
                                                  float* __restrict__ out) {
    int row = blockIdx.x;
    int tid = threadIdx.x;
    const float4* xr = (const float4*)(x + (size_t)row * D_);
    float4* orow = (float4*)(out + (size_t)row * D_);
    const float4* w4 = (const float4*)w;
    float4 v0 = xr[tid], v1 = xr[tid + 256];
    float s = v0.x*v0.x + v0.y*v0.y + v0.z*v0.z + v0.w*v0.w
            + v1.x*v1.x + v1.y*v1.y + v1.z*v1.z + v1.w*v1.w;
    __shared__ float red[256];
    red[tid] = s; __syncthreads();
    for (int off = 128; off > 0; off >>= 1) {
        if (tid < off) red[tid] += red[tid + off];
        __syncthreads();
    }
    float r = 1.0f / sqrtf(red[0] * (1.0f/2048.0f) + EPS_);
    float4 w0 = w4[tid], w1 = w4[tid + 256];
    float4 o0, o1;
    o0.x = v0.x*r*w0.x; o0.y = v0.y*r*w0.y; o0.z = v0.z*r*w0.z; o0.w = v0.w*r*w0.w;
    o1.x = v1.x*r*w1.x; o1.y = v1.y*r*w1.y; o1.z = v1.z*r*w1.z; o1.w = v1.w*r*w1.w;
    orow[tid] = o0; orow[tid + 256] = o1;
}

// ---------------- fused RMSNorm + hi/lo split: x[M][2048] -> Phi(/Plo)[k/8][m][8] ----------------
// one block per row; thread t owns k-chunk t (elements [8t, 8t+8))
template<int WLO>
__global__ __launch_bounds__(256) void rms_split_kernel(const float* __restrict__ x,
                                                        const float* __restrict__ w,
                                                        unsigned short* __restrict__ phi,
                                                        unsigned short* __restrict__ plo,
                                                        int M) {
    int row = blockIdx.x;
    int tid = threadIdx.x;
    const float4* xr = (const float4*)(x + (size_t)row * D_);
    const float4* w4 = (const float4*)w;
    float4 v0 = xr[tid * 2], v1 = xr[tid * 2 + 1];
    float s = v0.x*v0.x + v0.y*v0.y + v0.z*v0.z + v0.w*v0.w
            + v1.x*v1.x + v1.y*v1.y + v1.z*v1.z + v1.w*v1.w;
    __shared__ float red[256];
    red[tid] = s; __syncthreads();
    for (int off = 128; off > 0; off >>= 1) {
        if (tid < off) red[tid] += red[tid + off];
        __syncthreads();
    }
    float r = 1.0f / sqrtf(red[0] * (1.0f/2048.0f) + EPS_);
    float4 w0 = w4[tid * 2], w1 = w4[tid * 2 + 1];
    float o[8];
    o[0] = v0.x*r*w0.x; o[1] = v0.y*r*w0.y; o[2] = v0.z*r*w0.z; o[3] = v0.w*r*w0.w;
    o[4] = v1.x*r*w1.x; o[5] = v1.y*r*w1.y; o[6] = v1.z*r*w1.z; o[7] = v1.w*r*w1.w;
    ushort8 hi, lo;
#pragma unroll
    for (int q = 0; q < 8; ++q) {
        unsigned short hb = bf16_rne(o[q]);
        hi[q] = hb;
        if (WLO) lo[q] = bf16_rne(o[q] - bf16_tof(hb));
    }
    size_t off = ((size_t)tid * M + row) * 8;
    *(ushort8*)(phi + off) = hi;
    if (WLO) *(ushort8*)(plo + off) = lo;
}

// ---------------- weight transpose+split: B[K][N] f32 -> Phi(/Plo)[k/8][n][8] bf16 ----------------
template<int WLO>
__global__ __launch_bounds__(256) void splitw_kernel(const float* __restrict__ W,
                                                     unsigned short* __restrict__ phi,
                                                     unsigned short* __restrict__ plo,
                                                     int K, int N) {
    __shared__ float Ts[64][68];
    int n0 = blockIdx.x << 6, k0 = blockIdx.y << 6;
    int tid = threadIdx.x;
#pragma unroll
    for (int it = 0; it < 4; ++it) {
        int idx = tid + (it << 8);
        int kr = idx >> 4, c4 = idx & 15;
        float4 v = *(const float4*)(W + (size_t)(k0 + kr) * N + n0 + (c4 << 2));
        Ts[kr][c4*4+0] = v.x; Ts[kr][c4*4+1] = v.y; Ts[kr][c4*4+2] = v.z; Ts[kr][c4*4+3] = v.w;
    }
    __syncthreads();
#pragma unroll
    for (int h = 0; h < 2; ++h) {
        int c = tid + (h << 8);              // [0,512)
        int kc = c >> 6, n = c & 63;
        ushort8 hi, lo;
#pragma unroll
        for (int q = 0; q < 8; ++q) {
            float v = Ts[kc*8 + q][n];
            unsigned short hb = bf16_rne(v);
            hi[q] = hb;
            if (WLO) lo[q] = bf16_rne(v - bf16_tof(hb));
        }
        size_t off = ((size_t)((k0 >> 3) + kc) * N + (n0 + n)) * 8;
        *(ushort8*)(phi + off) = hi;
        if (WLO) *(ushort8*)(plo + off) = lo;
    }
}

// ---------------- activation split: A[M][K] f32 -> Phi(/Plo)[k/8][m][8] bf16 ----------------
template<int WLO>
__global__ __launch_bounds__(256) void splita_kernel(const float* __restrict__ A,
                                                     unsigned short* __restrict__ phi,
                                                     unsigned short* __restrict__ plo,
                                                     int M, int K) {
    __shared__ float Ts[64][68];
    int m0 = blockIdx.x << 6, k0 = blockIdx.y << 6;
    int tid = threadIdx.x;
#pragma unroll
    for (int it = 0; it < 4; ++it) {
        int idx = tid + (it << 8);
        int mr = idx >> 4, c4 = idx & 15;
        float4 v = *(const float4*)(A + (size_t)(m0 + mr) * K + k0 + (c4 << 2));
        Ts[mr][c4*4+0] = v.x; Ts[mr][c4*4+1] = v.y; Ts[mr][c4*4+2] = v.z; Ts[mr][c4*4+3] = v.w;
    }
    __syncthreads();
#pragma unroll
    for (int h = 0; h < 2; ++h) {
        int c = tid + (h << 8);
        int kc = c >> 6, m = c & 63;
        const float* src = &Ts[m][kc << 3];
        ushort8 hi, lo;
#pragma unroll
        for (int q = 0; q < 8; ++q) {
            float v = src[q];
            unsigned short hb = bf16_rne(v);
            hi[q] = hb;
            if (WLO) lo[q] = bf16_rne(v - bf16_tof(hb));
        }
        size_t off = ((size_t)((k0 >> 3) + kc) * M + (m0 + m)) * 8;
        *(ushort8*)(phi + off) = hi;
        if (WLO) *(ushort8*)(plo + off) = lo;
    }
}

// ---------------- bf16(x3) MFMA GEMM, 128x128 tile, BK=32, 2-phase dbuf, 16x16x32 MFMA ----------------
// Block map: XCD-chunked + paired-column decode (2 B-panels L2-resident, A shared by pair).
// EPI 0: C=acc ; 1: C=acc+Rg ; 2: C=silu(Rg)*acc ;
// EPI 3: packed hi/lo panels = silu(Rg)*acc ; EPI 4: packed hi panel only.
__device__ __forceinline__ void stage_panel(unsigned short* lds,
                                            const unsigned short* __restrict__ panel,
                                            int ktile, int R, int brow, int tid) {
#pragma unroll
    for (int h = 0; h < 2; ++h) {
        int c = tid + (h << 8);              // [0,512): kc = c>>7, row = c&127
        const unsigned short* g = panel + ((size_t)((ktile << 2) + (c >> 7)) * R + (brow + (c & 127))) * 8;
        __builtin_amdgcn_global_load_lds((const __attribute__((address_space(1))) void*)g,
                                         (__attribute__((address_space(3))) void*)(lds + (size_t)c * 8),
                                         16, 0, 0);
    }
}

template<int NP, int EPI>
__global__ __launch_bounds__(256) void gemm_mfma(const unsigned short* __restrict__ pah,
                                                 const unsigned short* __restrict__ pal,
                                                 const unsigned short* __restrict__ pbh,
                                                 const unsigned short* __restrict__ pbl,
                                                 float* __restrict__ C,
                                                 const float* __restrict__ Rg,
                                                 unsigned short* __restrict__ Cph,
                                                 unsigned short* __restrict__ Cpl,
                                                 int M, int N, int K) {
    constexpr int NPAN = (NP == 3) ? 2 : 1;
    __shared__ __align__(16) unsigned short As[2][NPAN][4][128][8];
    __shared__ __align__(16) unsigned short Bs[2][NPAN][4][128][8];
    const int tid = threadIdx.x;
    // T1: XCD-aware bijective block swizzle (all grids here have nwg % 8 == 0)
    int nwg = gridDim.x * gridDim.y;
    int wg = blockIdx.y * gridDim.x + blockIdx.x;
    if ((nwg & 7) == 0) {
        int cpx = nwg >> 3;
        wg = (wg & 7) * cpx + (wg >> 3);
    }
    // paired-column decode: consecutive wg alternate between 2 adjacent bn-columns
    // at the same bm-row, so each streamed A panel serves both columns while the
    // two B panels stay L2-resident. Bijective for even gridDim.x.
    const int gy2 = gridDim.y << 1;
    const int sc = wg / gy2;
    const int wr = wg - sc * gy2;
    const int bxs = (sc << 1) + (wr & 1), bys = wr >> 1;
    const int bm = bys << 7, bn = bxs << 7;
    const int lane = tid & 63, wave = tid >> 6;
    const int wm = (wave >> 1) << 6, wn = (wave & 1) << 6;
    const int fr = lane & 15, fk = lane >> 4;

    f32x4 acc[4][4];
#pragma unroll
    for (int i = 0; i < 4; ++i)
#pragma unroll
        for (int j = 0; j < 4; ++j) acc[i][j] = (f32x4)0.0f;

    const int nkt = K >> 5;

    // prologue stage tile 0 into buf 0
    stage_panel(&As[0][0][0][0][0], pah, 0, M, bm, tid);
    if (NP == 3) stage_panel(&As[0][1][0][0][0], pal, 0, M, bm, tid);
    stage_panel(&Bs[0][0][0][0][0], pbh, 0, N, bn, tid);
    if (NP == 3) stage_panel(&Bs[0][1][0][0][0], pbl, 0, N, bn, tid);
    __syncthreads();

    int cur = 0;
    for (int kt = 0; kt < nkt; ++kt) {
        // T3 minimum 2-phase: issue next-tile stage BEFORE ds_read+MFMA
        if (kt + 1 < nkt) {
            int nxt = cur ^ 1;
            stage_panel(&As[nxt][0][0][0][0], pah, kt + 1, M, bm, tid);
            if (NP == 3) stage_panel(&As[nxt][1][0][0][0], pal, kt + 1, M, bm, tid);
            stage_panel(&Bs[nxt][0][0][0][0], pbh, kt + 1, N, bn, tid);
            if (NP == 3) stage_panel(&Bs[nxt][1][0][0][0], pbl, kt + 1, N, bn, tid);
        }

        bf16x8 ah[4], bh[4], al[4], bl[4];
#pragma unroll
        for (int i = 0; i < 4; ++i) {
            ah[i] = *(const bf16x8*)&As[cur][0][fk][wm + (i << 4) + fr][0];
            if (NP == 3) al[i] = *(const bf16x8*)&As[cur][NPAN-1][fk][wm + (i << 4) + fr][0];
        }
#pragma unroll
        for (int j = 0; j < 4; ++j) {
            bh[j] = *(const bf16x8*)&Bs[cur][0][fk][wn + (j << 4) + fr][0];
            if (NP == 3) bl[j] = *(const bf16x8*)&Bs[cur][NPAN-1][fk][wn + (j << 4) + fr][0];
        }
#pragma unroll
        for (int i = 0; i < 4; ++i)
#pragma unroll
            for (int j = 0; j < 4; ++j) {
                acc[i][j] = __builtin_amdgcn_mfma_f32_16x16x32_bf16(ah[i], bh[j], acc[i][j], 0, 0, 0);
                if (NP == 3) {
                    acc[i][j] = __builtin_amdgcn_mfma_f32_16x16x32_bf16(ah[i], bl[j], acc[i][j], 0, 0, 0);
                    acc[i][j] = __builtin_amdgcn_mfma_f32_16x16x32_bf16(al[i], bh[j], acc[i][j], 0, 0, 0);
                }
            }
        __syncthreads();   // next-tile stage complete; buf[cur] reads all drained
        cur ^= 1;
    }

#pragma unroll
    for (int i = 0; i < 4; ++i) {
        int row0 = bm + wm + (i << 4) + (fk << 2);
#pragma unroll
        for (int j = 0; j < 4; ++j) {
            int col = bn + wn + (j << 4) + fr;
#pragma unroll
            for (int r = 0; r < 4; ++r) {
                int row = row0 + r;
                size_t off = (size_t)row * N + col;
                float v = acc[i][j][r];
                if (EPI == 0) {
                    C[off] = v;
                } else if (EPI == 1) {
                    C[off] = v + Rg[off];
                } else if (EPI == 2) {
                    C[off] = silu_f(Rg[off]) * v;
                } else {
                    v = silu_f(Rg[off]) * v;
                    unsigned short hb = bf16_rne(v);
                    size_t poff = (((size_t)(col >> 3)) * M + row) * 8 + (col & 7);
                    Cph[poff] = hb;
                    if (EPI == 3) Cpl[poff] = bf16_rne(v - bf16_tof(hb));
                }
            }
        }
    }
}

// ---------------- fused RoPE + scale + hi/lo split ----------------
__global__ __launch_bounds__(256) void rope_split_kernel(const float* __restrict__ X,
                                                         unsigned short* __restrict__ xh,
                                                         unsigned short* __restrict__ xl,
                                                         int seqmask, float scale) {
    int tok = blockIdx.x;
    int tid = threadIdx.x;
    int h = tid >> 4, d0 = (tid & 15) << 3;
    int pos = tok & seqmask;
    const float* src = X + (size_t)tok * D_ + h * DH_;
    bool lohalf = d0 < 64;
    float out[8];
#pragma unroll
    for (int q = 0; q < 8; ++q) {
        int d = d0 + q;
        int i = lohalf ? d : (d - 64);
        float e = (float)(2 * i) * (1.0f / 128.0f);
        float inv = 1.0f / powf(10000.0f, e);
        float ang = (float)pos * inv;
        float c = cosf(ang), s = sinf(ang);
        float x1 = src[i], x2 = src[i + 64];
        out[q] = lohalf ? (x1 * c - x2 * s) : (x2 * c + x1 * s);
    }
    ushort8 hi, lo;
#pragma unroll
    for (int q = 0; q < 8; ++q) {
        float v = out[q] * scale;
        unsigned short hb = bf16_rne(v);
        hi[q] = hb;
        lo[q] = bf16_rne(v - bf16_tof(hb));
    }
    size_t off = (size_t)tok * D_ + h * DH_ + d0;
    *(ushort8*)(xh + off) = hi;
    *(ushort8*)(xl + off) = lo;
}

// ---------------- V pack: f32 [b*T+t][2048] -> Vt[bh][T/8][128][8] bf16 hi/lo ----------------
__global__ __launch_bounds__(256) void vpack_kernel(const float* __restrict__ V,
                                                    unsigned short* __restrict__ vth,
                                                    unsigned short* __restrict__ vtl,
                                                    int T) {
    __shared__ float Ts[64][132];
    int kt = blockIdx.x, bh = blockIdx.y;
    int b = bh >> 4, h = bh & 15;
    int tid = threadIdx.x;
#pragma unroll
    for (int it = 0; it < 8; ++it) {
        int idx = tid + (it << 8);          // [0,2048)
        int r = idx >> 5, c4 = idx & 31;    // r in [0,64), c4 in [0,32)
        float4 v = *(const float4*)(V + ((size_t)(b * T + kt * 64 + r)) * D_ + h * DH_ + (c4 << 2));
        Ts[r][c4*4+0] = v.x; Ts[r][c4*4+1] = v.y; Ts[r][c4*4+2] = v.z; Ts[r][c4*4+3] = v.w;
    }
    __syncthreads();
    size_t obase = ((size_t)bh * (size_t)(T >> 3) + (size_t)kt * 8) * 1024;
#pragma unroll
    for (int it = 0; it < 4; ++it) {
        int c = tid + (it << 8);            // [0,1024): kc = c>>7, dh = c&127
        int kc = c >> 7, dh = c & 127;
        ushort8 hi, lo;
#pragma unroll
        for (int q = 0; q < 8; ++q) {
            float v = Ts[kc * 8 + q][dh];
            unsigned short hb = bf16_rne(v);
            hi[q] = hb;
            lo[q] = bf16_rne(v - bf16_tof(hb));
        }
        *(ushort8*)(vth + obase + (size_t)kc * 1024 + dh * 8) = hi;
        *(ushort8*)(vtl + obase + (size_t)kc * 1024 + dh * 8) = lo;
    }
}

// ---------------- bf16x3 MFMA flash attention ----------------
// grid: (T/64, B_*H_), block 256 (4 waves, each owns 16 q-rows)
__global__ __launch_bounds__(256) void attn_mfma(const unsigned short* __restrict__ QH,
                                                 const unsigned short* __restrict__ QL,
                                                 const unsigned short* __restrict__ KH,
                                                 const unsigned short* __restrict__ KL,
                                                 const unsigned short* __restrict__ VTH,
                                                 const unsigned short* __restrict__ VTL,
                                                 float* __restrict__ O, int T) {
    __shared__ __align__(16) unsigned short KV[16384];
    __shared__ __align__(16) float Ss[4096];
    __shared__ __align__(16) float mrow[64];
    __shared__ __align__(16) float lrow[64];
    __shared__ __align__(16) float crow[64];

    const int tid = threadIdx.x;
    const int qt = blockIdx.x, bh = blockIdx.y;
    const int b = bh >> 4, h = bh & 15;
    const int lane = tid & 63, w = tid >> 6;
    const int fr = lane & 15, fk = lane >> 4;
    const size_t tok0 = (size_t)b * T;

    char* lds_kv = (char*)&KV[0];
    char* lds_sp = (char*)&Ss[0];

    bf16x8 qfh[4], qfl[4];
    {
        const size_t qoff = (tok0 + (size_t)qt * 64 + w * 16 + fr) * D_ + h * DH_ + fk * 8;
#pragma unroll
        for (int ks = 0; ks < 4; ++ks) {
            qfh[ks] = *(const bf16x8*)(QH + qoff + ks * 32);
            qfl[ks] = *(const bf16x8*)(QL + qoff + ks * 32);
        }
    }
    if (tid < 64) { mrow[tid] = -1e30f; lrow[tid] = 0.f; }

    f32x4 acc[8];
#pragma unroll
    for (int nt = 0; nt < 8; ++nt) acc[nt] = (f32x4)0.f;

    const int srow = tid >> 2, sslot = tid & 3;
    const size_t vbase = (size_t)bh * (size_t)(T >> 3) * 1024;

    for (int kt = 0; kt <= qt; ++kt) {
        __syncthreads();
#pragma unroll
        for (int it = 0; it < 4; ++it) {
            int c = tid + (it << 8);
            int t = c >> 4;
            int sp = (c & 15) ^ (t & 7);
            size_t goff = (tok0 + (size_t)kt * 64 + t) * D_ + h * DH_ + sp * 8;
            __builtin_amdgcn_global_load_lds((const __attribute__((address_space(1))) void*)(KH + goff),
                (__attribute__((address_space(3))) void*)(lds_kv + c * 16), 16, 0, 0);
            __builtin_amdgcn_global_load_lds((const __attribute__((address_space(1))) void*)(KL + goff),
                (__attribute__((address_space(3))) void*)(lds_kv + 16384 + c * 16), 16, 0, 0);
        }
        __syncthreads();
        {
            f32x4 s[4];
#pragma unroll
            for (int nt = 0; nt < 4; ++nt) s[nt] = (f32x4)0.f;
#pragma unroll
            for (int ks = 0; ks < 4; ++ks) {
#pragma unroll
                for (int nt = 0; nt < 4; ++nt) {
                    int n = nt * 16 + fr;
                    int offk = (n * 256 + ks * 64 + fk * 16) ^ ((n & 7) << 4);
                    bf16x8 kfh = *(const bf16x8*)(lds_kv + offk);
                    bf16x8 kfl = *(const bf16x8*)(lds_kv + 16384 + offk);
                    s[nt] = __builtin_amdgcn_mfma_f32_16x16x32_bf16(qfh[ks], kfh, s[nt], 0, 0, 0);
                    s[nt] = __builtin_amdgcn_mfma_f32_16x16x32_bf16(qfh[ks], kfl, s[nt], 0, 0, 0);
                    s[nt] = __builtin_amdgcn_mfma_f32_16x16x32_bf16(qfl[ks], kfh, s[nt], 0, 0, 0);
                }
            }
#pragma unroll
            for (int nt = 0; nt < 4; ++nt)
#pragma unroll
                for (int r = 0; r < 4; ++r) {
                    int row = w * 16 + fk * 4 + r;
                    int col = nt * 16 + fr;
                    *(float*)(lds_sp + ((row * 256 + col * 4) ^ ((row & 7) << 4))) = s[nt][r];
                }
        }
        __syncthreads();
#pragma unroll
        for (int it = 0; it < 4; ++it) {
            int c = tid + (it << 8);
            size_t goff = vbase + (size_t)kt * 8192 + (size_t)c * 8;
            __builtin_amdgcn_global_load_lds((const __attribute__((address_space(1))) void*)(VTH + goff),
                (__attribute__((address_space(3))) void*)(lds_kv + c * 16), 16, 0, 0);
            __builtin_amdgcn_global_load_lds((const __attribute__((address_space(1))) void*)(VTL + goff),
                (__attribute__((address_space(3))) void*)(lds_kv + 16384 + c * 16), 16, 0, 0);
        }
        float p[16];
        float newm, psum, cr, oldl;
        {
            float tmax = -1e30f;
            int colbase = sslot * 16;
#pragma unroll
            for (int q4 = 0; q4 < 4; ++q4) {
                f32x4 sv = *(const f32x4*)(lds_sp + ((srow * 256 + sslot * 64 + q4 * 16) ^ ((srow & 7) << 4)));
#pragma unroll
                for (int e = 0; e < 4; ++e) {
                    float v = sv[e];
                    if (kt == qt && (colbase + q4 * 4 + e) > srow) v = -1e30f;
                    p[q4 * 4 + e] = v;
                    tmax = fmaxf(tmax, v);
                }
            }
            tmax = fmaxf(tmax, __shfl_xor(tmax, 1, 64));
            tmax = fmaxf(tmax, __shfl_xor(tmax, 2, 64));
            float oldm = mrow[srow];
            oldl = lrow[srow];
            newm = fmaxf(oldm, tmax);
            psum = 0.f;
#pragma unroll
            for (int e = 0; e < 16; ++e) { p[e] = expf(p[e] - newm); psum += p[e]; }
            psum += __shfl_xor(psum, 1, 64);
            psum += __shfl_xor(psum, 2, 64);
            cr = expf(oldm - newm);
        }
        __syncthreads();
        {
            ushort8 h0, h1, l0, l1;
#pragma unroll
            for (int e = 0; e < 8; ++e) {
                unsigned short hb = bf16_rne(p[e]);
                h0[e] = hb; l0[e] = bf16_rne(p[e] - bf16_tof(hb));
                unsigned short hb2 = bf16_rne(p[8 + e]);
                h1[e] = hb2; l1[e] = bf16_rne(p[8 + e] - bf16_tof(hb2));
            }
            int base = srow * 128 + sslot * 32;
            int swz = (srow & 7) << 4;
            *(ushort8*)(lds_sp + (base ^ swz)) = h0;
            *(ushort8*)(lds_sp + ((base + 16) ^ swz)) = h1;
            *(ushort8*)(lds_sp + 8192 + (base ^ swz)) = l0;
            *(ushort8*)(lds_sp + 8192 + ((base + 16) ^ swz)) = l1;
            if (sslot == 0) { mrow[srow] = newm; lrow[srow] = oldl * cr + psum; crow[srow] = cr; }
        }
        __syncthreads();
        {
            f32x4 crv = *(const f32x4*)&crow[w * 16 + fk * 4];
#pragma unroll
            for (int nt = 0; nt < 8; ++nt)
#pragma unroll
                for (int r = 0; r < 4; ++r) acc[nt][r] *= crv[r];
            int m = w * 16 + fr;
#pragma unroll
            for (int ks = 0; ks < 2; ++ks) {
                int offp = (m * 128 + ks * 64 + fk * 16) ^ ((m & 7) << 4);
                bf16x8 pfh = *(const bf16x8*)(lds_sp + offp);
                bf16x8 pfl = *(const bf16x8*)(lds_sp + 8192 + offp);
#pragma unroll
                for (int nt = 0; nt < 8; ++nt) {
                    int offv = (ks * 4 + fk) * 2048 + (nt * 16 + fr) * 16;
                    bf16x8 vfh = *(const bf16x8*)(lds_kv + offv);
                    bf16x8 vfl = *(const bf16x8*)(lds_kv + 16384 + offv);
                    acc[nt] = __builtin_amdgcn_mfma_f32_16x16x32_bf16(pfh, vfh, acc[nt], 0, 0, 0);
                    acc[nt] = __builtin_amdgcn_mfma_f32_16x16x32_bf16(pfh, vfl, acc[nt], 0, 0, 0);
                    acc[nt] = __builtin_amdgcn_mfma_f32_16x16x32_bf16(pfl, vfh, acc[nt], 0, 0, 0);
                }
            }
        }
    }
    __syncthreads();
    {
        f32x4 lv = *(const f32x4*)&lrow[w * 16 + fk * 4];
        float* orow = O + (tok0 + (size_t)qt * 64 + w * 16 + fk * 4) * D_ + h * DH_;
#pragma unroll
        for (int r = 0; r < 4; ++r) {
            float inv = 1.0f / lv[r];
#pragma unroll
            for (int nt = 0; nt < 8; ++nt)
                orow[(size_t)r * D_ + nt * 16 + fr] = acc[nt][r] * inv;
        }
    }
}

// ---------------- f32 GEMM (fallback path) ----------------
template<int EPI>
__global__ __launch_bounds__(256) void gemm128(const float* __restrict__ A,
                                               const float* __restrict__ Bm,
                                               float* __restrict__ C,
                                               const float* __restrict__ Rg,
                                               int M, int N, int K) {
    __shared__ float Ast[16][132];
    __shared__ float Bs[16][132];
    int bm = blockIdx.y << 7, bn = blockIdx.x << 7;
    int tid = threadIdx.x;
    int ty = tid >> 4, tx = tid & 15;
    float acc[8][8];
#pragma unroll
    for (int i = 0; i < 8; ++i)
#pragma unroll
        for (int j = 0; j < 8; ++j) acc[i][j] = 0.f;

    for (int k0 = 0; k0 < K; k0 += 16) {
#pragma unroll
        for (int it = 0; it < 2; ++it) {
            int idx = tid + (it << 8);
            int ar = idx >> 2, ac = idx & 3;
            float4 av = *(const float4*)(A + (size_t)(bm + ar) * K + k0 + (ac << 2));
            Ast[ac*4+0][ar] = av.x; Ast[ac*4+1][ar] = av.y;
            Ast[ac*4+2][ar] = av.z; Ast[ac*4+3][ar] = av.w;
            int br = idx >> 5, bc = idx & 31;
            float4 bv = *(const float4*)(Bm + (size_t)(k0 + br) * N + bn + (bc << 2));
            *(float4*)&Bs[br][bc << 2] = bv;
        }
        __syncthreads();
#pragma unroll
        for (int kk = 0; kk < 16; ++kk) {
            float a[8], b[8];
            *(float4*)&a[0] = *(const float4*)&Ast[kk][ty*4];
            *(float4*)&a[4] = *(const float4*)&Ast[kk][64 + ty*4];
            *(float4*)&b[0] = *(const float4*)&Bs[kk][tx*4];
            *(float4*)&b[4] = *(const float4*)&Bs[kk][64 + tx*4];
#pragma unroll
            for (int i = 0; i < 8; ++i)
#pragma unroll
                for (int j = 0; j < 8; ++j)
                    acc[i][j] += a[i] * b[j];
        }
        __syncthreads();
    }
#pragma unroll
    for (int i = 0; i < 8; ++i) {
        int row = bm + ((i < 4) ? (ty*4 + i) : (64 + ty*4 + (i - 4)));
#pragma unroll
        for (int half = 0; half < 2; ++half) {
            int col = bn + half*64 + tx*4;
            size_t off = (size_t)row * N + col;
            const float* ap = &acc[i][half*4];
            float4 r;
            if (EPI == 0) {
                r.x = ap[0]; r.y = ap[1]; r.z = ap[2]; r.w = ap[3];
            } else if (EPI == 1) {
                float4 rv = *(const float4*)(Rg + off);
                r.x = ap[0] + rv.x; r.y = ap[1] + rv.y;
                r.z = ap[2] + rv.z; r.w = ap[3] + rv.w;
            } else {
                float4 gv = *(const float4*)(Rg + off);
                r.x = silu_f(gv.x) * ap[0]; r.y = silu_f(gv.y) * ap[1];
                r.z = silu_f(gv.z) * ap[2]; r.w = silu_f(gv.w) * ap[3];
            }
            *(float4*)(C + off) = r;
        }
    }
}

// ---------------- RoPE in place (f32, fallback) ----------------
__global__ __launch_bounds__(256) void rope_kernel(float* __restrict__ q, int nrows, int seqlen) {
    int gid = blockIdx.x * 256 + threadIdx.x;
    int tok = gid >> 10;
    if (tok >= nrows) return;
    int rest = gid & 1023;
    int h = rest >> 6, i = rest & 63;
    int pos = tok % seqlen;
    float e = (float)(2 * i) * (1.0f / 128.0f);
    float inv = 1.0f / powf(10000.0f, e);
    float ang = (float)pos * inv;
    float c = cosf(ang), s = sinf(ang);
    size_t base = (size_t)tok * D_ + h * 128 + i;
    float x1 = q[base], x2 = q[base + 64];
    q[base]      = x1 * c - x2 * s;
    q[base + 64] = x2 * c + x1 * s;
}

// ---------------- flash attention f32 (fallback) ----------------
__global__ __launch_bounds__(256) void attn_kernel(const float* __restrict__ Q,
                                                   const float* __restrict__ K,
                                                   const float* __restrict__ V,
                                                   float* __restrict__ O,
                                                   int T) {
    int qt = blockIdx.x;
    int bh = blockIdx.y;
    int b = bh >> 4, h = bh & 15;
    int tid = threadIdx.x;

    __shared__ float4 Qs[32][32];
    __shared__ float4 KVs[64][32];
    __shared__ float Sst[32][65];
    __shared__ float mrow[32], lrow[32], crow[32];

    const size_t headoff = (size_t)h * DH_;
    const size_t bbase = (size_t)b * T * D_;

#pragma unroll
    for (int i = 0; i < 4; ++i) {
        int idx = tid + i * 256;
        int r = idx >> 5, ch = idx & 31;
        const float4* src = (const float4*)(Q + bbase + (size_t)(qt*32 + r) * D_ + headoff);
        Qs[r][ch ^ ((r >> 2) & 7)] = src[ch];
    }
    if (tid < 32) { mrow[tid] = -1e30f; lrow[tid] = 0.f; }

    int ty16 = tid >> 4, tx16 = tid & 15;
    int r8 = tid >> 3, q8 = tid & 7;
    float o[2][8];
#pragma unroll
    for (int i = 0; i < 2; ++i)
#pragma unroll
        for (int j = 0; j < 8; ++j) o[i][j] = 0.f;

    int ktmax = (qt * 32 + 31) >> 6;
    for (int kt = 0; kt <= ktmax; ++kt) {
        __syncthreads();
#pragma unroll
        for (int i = 0; i < 8; ++i) {
            int idx = tid + i * 256;
            int r = idx >> 5, ch = idx & 31;
            const float4* src = (const float4*)(K + bbase + (size_t)(kt*64 + r) * D_ + headoff);
            KVs[r][ch ^ ((r >> 2) & 7)] = src[ch];
        }
        __syncthreads();
        {
            float s[2][4];
#pragma unroll
            for (int i = 0; i < 2; ++i)
#pragma unroll
                for (int j = 0; j < 4; ++j) s[i][j] = 0.f;
#pragma unroll
            for (int ch = 0; ch < 32; ++ch) {
                float4 qv[2], kv[4];
#pragma unroll
                for (int i = 0; i < 2; ++i) { int r = ty16*2 + i; qv[i] = Qs[r][ch ^ ((r >> 2) & 7)]; }
#pragma unroll
                for (int j = 0; j < 4; ++j) { int c = tx16*4 + j; kv[j] = KVs[c][ch ^ ((c >> 2) & 7)]; }
#pragma unroll
                for (int i = 0; i < 2; ++i)
#pragma unroll
                    for (int j = 0; j < 4; ++j)
                        s[i][j] += qv[i].x*kv[j].x + qv[i].y*kv[j].y + qv[i].z*kv[j].z + qv[i].w*kv[j].w;
            }
#pragma unroll
            for (int i = 0; i < 2; ++i) {
                int grow = qt*32 + ty16*2 + i;
#pragma unroll
                for (int j = 0; j < 4; ++j) {
                    int gcol = kt*64 + tx16*4 + j;
                    float sv = s[i][j] * SCALE_QK;
                    if (gcol > grow) sv = -1e30f;
                    Sst[ty16*2 + i][tx16*4 + j] = sv;
                }
            }
        }
        __syncthreads();
#pragma unroll
        for (int i = 0; i < 8; ++i) {
            int idx = tid + i * 256;
            int r = idx >> 5, ch = idx & 31;
            const float4* src = (const float4*)(V + bbase + (size_t)(kt*64 + r) * D_ + headoff);
            KVs[r][ch ^ ((r >> 2) & 7)] = src[ch];
        }
        {
            float pv[8];
            float tmax = -1e30f;
#pragma unroll
            for (int c = 0; c < 8; ++c) { pv[c] = Sst[r8][q8*8 + c]; tmax = fmaxf(tmax, pv[c]); }
#pragma unroll
            for (int m = 1; m < 8; m <<= 1) tmax = fmaxf(tmax, __shfl_xor(tmax, m, 64));
            float oldm = mrow[r8];
            float newm = fmaxf(oldm, tmax);
            float psum = 0.f;
#pragma unroll
            for (int c = 0; c < 8; ++c) {
                float p = expf(pv[c] - newm);
                Sst[r8][q8*8 + c] = p;
                psum += p;
            }
#pragma unroll
            for (int m = 1; m < 8; m <<= 1) psum += __shfl_xor(psum, m, 64);
            if (q8 == 0) {
                float crv = expf(oldm - newm);
                crow[r8] = crv;
                lrow[r8] = lrow[r8] * crv + psum;
                mrow[r8] = newm;
            }
        }
        __syncthreads();
        {
            float crv[2];
#pragma unroll
            for (int i = 0; i < 2; ++i) {
                crv[i] = crow[ty16*2 + i];
#pragma unroll
                for (int j = 0; j < 8; ++j) o[i][j] *= crv[i];
            }
#pragma unroll
            for (int kc = 0; kc < 64; ++kc) {
                int swz = (kc >> 2) & 7;
                float4 v0 = KVs[kc][tx16 ^ swz];
                float4 v1 = KVs[kc][(16 + tx16) ^ swz];
#pragma unroll
                for (int i = 0; i < 2; ++i) {
                    float p = Sst[ty16*2 + i][kc];
                    o[i][0] += p*v0.x; o[i][1] += p*v0.y; o[i][2] += p*v0.z; o[i][3] += p*v0.w;
                    o[i][4] += p*v1.x; o[i][5] += p*v1.y; o[i][6] += p*v1.z; o[i][7] += p*v1.w;
                }
            }
        }
    }
#pragma unroll
    for (int i = 0; i < 2; ++i) {
        int r = ty16*2 + i;
        float inv = 1.0f / lrow[r];
        float4 a, bb;
        a.x = o[i][0]*inv; a.y = o[i][1]*inv; a.z = o[i][2]*inv; a.w = o[i][3]*inv;
        bb.x = o[i][4]*inv; bb.y = o[i][5]*inv; bb.z = o[i][6]*inv; bb.w = o[i][7]*inv;
        float* dst = O + bbase + (size_t)(qt*32 + r) * D_ + headoff;
        ((float4*)dst)[tx16] = a;
        ((float4*)dst)[16 + tx16] = bb;
    }
}

// ---------------- router / loss / topk / gather / copy / scatter ----------------
__global__ __launch_bounds__(256) void router_kernel(const float* __restrict__ x,
                                                     const float* __restrict__ proc,
                                                     const float* __restrict__ prior,
                                                     float* __restrict__ gbuf,
                                                     float* __restrict__ dchbuf,
                                                     float* __restrict__ gout) {
    int row = blockIdx.x, tid = threadIdx.x;
    const float4* x4 = (const float4*)(x + (size_t)row * D_);
    const float4* p4 = (const float4*)(proc + (size_t)row * D_);
    const float4* r4 = (const float4*)(prior + (size_t)row * D_);
    float sst = 0.f, sch = 0.f;
#pragma unroll
    for (int it = 0; it < 2; ++it) {
        int i = tid + it * 256;
        float4 xv = x4[i], pv = p4[i], rv = r4[i];
        float a0 = pv.x - xv.x, a1 = pv.y - xv.y, a2 = pv.z - xv.z, a3 = pv.w - xv.w;
        sst += a0*a0 + a1*a1 + a2*a2 + a3*a3;
        float d0 = a0 - rv.x, d1 = a1 - rv.y, d2 = a2 - rv.z, d3 = a3 - rv.w;
        sch += d0*d0 + d1*d1 + d2*d2 + d3*d3;
    }
    __shared__ float rs[256], rc[256];
    rs[tid] = sst; rc[tid] = sch; __syncthreads();
    for (int off = 128; off > 0; off >>= 1) {
        if (tid < off) { rs[tid] += rs[tid + off]; rc[tid] += rc[tid + off]; }
        __syncthreads();
    }
    if (tid == 0) {
        float Dst = rs[0] * (1.0f/2048.0f);
        float Dch = rc[0] * (1.0f/2048.0f);
        float g = 1.0f / (1.0f + expf(-(Dch - Dst)));
        gbuf[row] = g; dchbuf[row] = Dch; gout[row] = g;
    }
}

__global__ __launch_bounds__(1024) void loss_kernel(const float* __restrict__ dch, float* __restrict__ out) {
    __shared__ float red[1024];
    int tid = threadIdx.x;
    red[tid] = dch[tid] + dch[tid + 1024] + dch[tid + 2048] + dch[tid + 3072];
    __syncthreads();
    for (int off = 512; off > 0; off >>= 1) {
        if (tid < off) red[tid] += red[tid + off];
        __syncthreads();
    }
    if (tid == 0) out[0] = red[0] * (1.0f / 4096.0f);
}

__global__ __launch_bounds__(1024) void topk_kernel(const float* __restrict__ gbuf,
                                                    int* __restrict__ idxout,
                                                    float* __restrict__ gateout) {
    int b = blockIdx.x, tid = threadIdx.x;
    __shared__ float val[2048];
    __shared__ int idx[2048];
    val[tid] = gbuf[b*2048 + tid];           idx[tid] = tid;
    val[tid + 1024] = gbuf[b*2048 + tid + 1024]; idx[tid + 1024] = tid + 1024;
    __syncthreads();
    for (int kk = 2; kk <= 2048; kk <<= 1) {
        for (int j = kk >> 1; j > 0; j >>= 1) {
            for (int i = tid; i < 2048; i += 1024) {
                int ixj = i ^ j;
                if (ixj > i) {
                    bool up = ((i & kk) == 0);
                    float v1 = val[i], v2 = val[ixj];
                    int i1 = idx[i], i2 = idx[ixj];
                    bool sw = up ? ((v2 > v1) || (v2 == v1 && i2 < i1))
                                 : ((v1 > v2) || (v1 == v2 && i1 < i2));
                    if (sw) { val[i] = v2; val[ixj] = v1; idx[i] = i2; idx[ixj] = i1; }
                }
            }
            __syncthreads();
        }
    }
    if (tid < 1024) {
        idxout[b*1024 + tid] = idx[tid];
        gateout[b*1024 + tid] = val[tid];
    }
}

__global__ __launch_bounds__(256) void gather_kernel(const float* __restrict__ proc,
                                                     const int* __restrict__ idx,
                                                     float* __restrict__ sel) {
    int r = blockIdx.x;
    int b = r >> 10, rr = r & 1023;
    int tok = idx[b*1024 + rr];
    const float4* src = (const float4*)(proc + ((size_t)(b*2048 + tok)) * D_);
    float4* dst = (float4*)(sel + (size_t)r * D_);
    dst[threadIdx.x] = src[threadIdx.x];
    dst[threadIdx.x + 256] = src[threadIdx.x + 256];
}

__global__ __launch_bounds__(256) void copy_kernel(const float* __restrict__ src,
                                                   float* __restrict__ dst, int n4) {
    int i = blockIdx.x * 256 + threadIdx.x;
    if (i < n4) ((float4*)dst)[i] = ((const float4*)src)[i];
}

__global__ __launch_bounds__(256) void scatter_kernel(const float* __restrict__ sel,
                                                      const float* __restrict__ selout,
                                                      const int* __restrict__ idx,
                                                      const float* __restrict__ gate,
                                                      float* __restrict__ outp) {
    int r = blockIdx.x;
    int b = r >> 10, rr = r & 1023;
    int tok = idx[b*1024 + rr];
    float g = gate[b*1024 + rr];
    const float4* s4 = (const float4*)(sel + (size_t)r * D_);
    const float4* o4 = (const float4*)(selout + (size_t)r * D_);
    float4* d4 = (float4*)(outp + ((size_t)(b*2048 + tok)) * D_);
#pragma unroll
    for (int it = 0; it < 2; ++it) {
        int i = threadIdx.x + it * 256;
        float4 a = s4[i], o = o4[i];
        float4 w;
        w.x = a.x + g*(o.x - a.x); w.y = a.y + g*(o.y - a.y);
        w.z = a.z + g*(o.z - a.z); w.w = a.w + g*(o.w - a.w);
        d4[i] = w;
    }
}

extern "C" void kernel_launch(void* const* d_in, const int* in_sizes, int n_in,
                              void* d_out, int out_size, void* d_ws, size_t ws_size,
                              hipStream_t stream) {
    const float* X      = (const float*)d_in[0];
    const float* d1_ln1 = (const float*)d_in[1];
    const float* d1_ln2 = (const float*)d_in[2];
    const float* d1_wq  = (const float*)d_in[3];
    const float* d1_wk  = (const float*)d_in[4];
    const float* d1_wv  = (const float*)d_in[5];
    const float* d1_wo  = (const float*)d_in[6];
    const float* d1_wg  = (const float*)d_in[7];
    const float* d1_wu  = (const float*)d_in[8];
    const float* d1_wd  = (const float*)d_in[9];
    const float* d2_ln1 = (const float*)d_in[10];
    const float* d2_ln2 = (const float*)d_in[11];
    const float* d2_wq  = (const float*)d_in[12];
    const float* d2_wk  = (const float*)d_in[13];
    const float* d2_wv  = (const float*)d_in[14];
    const float* d2_wo  = (const float*)d_in[15];
    const float* d2_wg  = (const float*)d_in[16];
    const float* d2_wu  = (const float*)d_in[17];
    const float* d2_wd  = (const float*)d_in[18];
    const float* p_ln   = (const float*)d_in[19];
    const float* p_wg   = (const float*)d_in[20];
    const float* p_wu   = (const float*)d_in[21];
    const float* p_wd   = (const float*)d_in[22];

    float* out = (float*)d_out;
    float* ws  = (float*)d_ws;

    const size_t BIG = (size_t)NTOK_ * D_;           // 8M f32
    const size_t MEG = 1024 * 1024;

    const size_t NEED_NEW = (128 * MEG + 16384) * 4;  // ~512 MB
    const size_t NEED_OLD = ((5*BIG + (size_t)NTOK_*FF_ + 12288) * 4);

    if (ws_size >= NEED_NEW) {
        float* BUF0 = ws;                 // 8M f32
        float* BUF1 = ws + 8*MEG;         // q
        float* BUF2 = ws + 16*MEG;        // k / h
        float* BUF3 = ws + 24*MEG;        // v / prior_out / sel_out
        float* BUF4 = ws + 32*MEG;        // attnout / sel (+V2)
        float* BUFF = ws + 40*MEG;        // 32M f32 FF
        unsigned short* PWhi  = (unsigned short*)(ws + 72*MEG);
        unsigned short* PWlo  = (unsigned short*)(ws + 80*MEG);
        unsigned short* PAhi  = (unsigned short*)(ws + 88*MEG);
        unsigned short* PAlo  = (unsigned short*)(ws + 92*MEG);
        unsigned short* PFhi  = (unsigned short*)(ws + 96*MEG);
        unsigned short* PFlo  = (unsigned short*)(ws + 112*MEG);
        // attention packed buffers (overlay PF region; disjoint in time)
        unsigned short* U   = (unsigned short*)(ws + 96*MEG);
        const size_t PK = (size_t)NTOK_ * D_;         // 8.39M ushorts
        unsigned short* QHp = U;
        unsigned short* QLp = U + PK;
        unsigned short* KHp = U + 2*PK;
        unsigned short* KLp = U + 3*PK;
        unsigned short* VTH = U + 4*PK;
        unsigned short* VTL = U + 5*PK;
        float* SM   = ws + 128*MEG;
        float* gbuf = SM;
        float* dch  = SM + 4096;
        float* gate = SM + 8192;
        int*   idxb = (int*)(SM + 10240);

        float* PROC = out;                // processed lives directly in out

        // ---- decision decoder layer (bf16x3 GEMMs + bf16x3 MFMA attention) ----
        rms_split_kernel<1><<<NTOK_, 256, 0, stream>>>(X, d1_ln1, PAhi, PAlo, NTOK_);
        splitw_kernel<1><<<dim3(32, 32), 256, 0, stream>>>(d1_wq, PWhi, PWlo, D_, D_);
        gemm_mfma<3,0><<<dim3(16, 32), 256, 0, stream>>>(PAhi, PAlo, PWhi, PWlo, BUF1, nullptr, nullptr, nullptr, NTOK_, D_, D_);
        splitw_kernel<1><<<dim3(32, 32), 256, 0, stream>>>(d1_wk, PWhi, PWlo, D_, D_);
        gemm_mfma<3,0><<<dim3(16, 32), 256, 0, stream>>>(PAhi, PAlo, PWhi, PWlo, BUF2, nullptr, nullptr, nullptr, NTOK_, D_, D_);
        splitw_kernel<1><<<dim3(32, 32), 256, 0, stream>>>(d1_wv, PWhi, PWlo, D_, D_);
        gemm_mfma<3,0><<<dim3(16, 32), 256, 0, stream>>>(PAhi, PAlo, PWhi, PWlo, BUF3, nullptr, nullptr, nullptr, NTOK_, D_, D_);
        rope_split_kernel<<<NTOK_, 256, 0, stream>>>(BUF1, QHp, QLp, T_ - 1, SCALE_QK);
        rope_split_kernel<<<NTOK_, 256, 0, stream>>>(BUF2, KHp, KLp, T_ - 1, 1.0f);
        vpack_kernel<<<dim3(T_/64, B_*H_), 256, 0, stream>>>(BUF3, VTH, VTL, T_);
        attn_mfma<<<dim3(T_/64, B_*H_), 256, 0, stream>>>(QHp, QLp, KHp, KLp, VTH, VTL, BUF4, T_);
        splita_kernel<1><<<dim3(64, 32), 256, 0, stream>>>(BUF4, PAhi, PAlo, NTOK_, D_);
        splitw_kernel<1><<<dim3(32, 32), 256, 0, stream>>>(d1_wo, PWhi, PWlo, D_, D_);
        gemm_mfma<3,1><<<dim3(16, 32), 256, 0, stream>>>(PAhi, PAlo, PWhi, PWlo, BUF2, X, nullptr, nullptr, NTOK_, D_, D_);  // h
        rms_split_kernel<1><<<NTOK_, 256, 0, stream>>>(BUF2, d1_ln2, PAhi, PAlo, NTOK_);
        splitw_kernel<1><<<dim3(128, 32), 256, 0, stream>>>(d1_wg, PWhi, PWlo, D_, FF_);
        gemm_mfma<3,0><<<dim3(64, 32), 256, 0, stream>>>(PAhi, PAlo, PWhi, PWlo, BUFF, nullptr, nullptr, nullptr, NTOK_, FF_, D_);
        splitw_kernel<1><<<dim3(128, 32), 256, 0, stream>>>(d1_wu, PWhi, PWlo, D_, FF_);
        gemm_mfma<3,3><<<dim3(64, 32), 256, 0, stream>>>(PAhi, PAlo, PWhi, PWlo, nullptr, BUFF, PFhi, PFlo, NTOK_, FF_, D_);  // silu(wg)*wu -> packed
        splitw_kernel<1><<<dim3(32, 128), 256, 0, stream>>>(d1_wd, PWhi, PWlo, FF_, D_);
        gemm_mfma<3,1><<<dim3(16, 32), 256, 0, stream>>>(PFhi, PFlo, PWhi, PWlo, PROC, BUF2, nullptr, nullptr, NTOK_, D_, FF_); // processed -> out

        // ---- prior network (bf16x3) ----
        rms_split_kernel<1><<<NTOK_, 256, 0, stream>>>(X, p_ln, PAhi, PAlo, NTOK_);
        splitw_kernel<1><<<dim3(16, 32), 256, 0, stream>>>(p_wg, PWhi, PWlo, D_, PFF_);
        gemm_mfma<3,0><<<dim3(8, 32), 256, 0, stream>>>(PAhi, PAlo, PWhi, PWlo, BUFF, nullptr, nullptr, nullptr, NTOK_, PFF_, D_);
        splitw_kernel<1><<<dim3(16, 32), 256, 0, stream>>>(p_wu, PWhi, PWlo, D_, PFF_);
        gemm_mfma<3,3><<<dim3(8, 32), 256, 0, stream>>>(PAhi, PAlo, PWhi, PWlo, nullptr, BUFF, PFhi, PFlo, NTOK_, PFF_, D_);
        splitw_kernel<1><<<dim3(32, 16), 256, 0, stream>>>(p_wd, PWhi, PWlo, PFF_, D_);
        gemm_mfma<3,0><<<dim3(16, 32), 256, 0, stream>>>(PFhi, PFlo, PWhi, PWlo, BUF3, nullptr, nullptr, nullptr, NTOK_, D_, PFF_); // prior_out

        // ---- router + loss + top-k + gather ----
        router_kernel<<<NTOK_, 256, 0, stream>>>(X, PROC, BUF3, gbuf, dch, out + 8388609);
        loss_kernel<<<1, 1024, 0, stream>>>(dch, out + 8388608);
        topk_kernel<<<B_, 1024, 0, stream>>>(gbuf, idxb, gate);
        gather_kernel<<<NSEL_, 256, 0, stream>>>(PROC, idxb, BUF4);   // sel

        // ---- dynamic decoder layer (bf16 NP=1 GEMMs, x3 MFMA attention) ----
        float* V2 = BUF4 + (size_t)NSEL_ * D_;
        rms_split_kernel<0><<<NSEL_, 256, 0, stream>>>(BUF4, d2_ln1, PAhi, PAlo, NSEL_);
        splitw_kernel<0><<<dim3(32, 32), 256, 0, stream>>>(d2_wq, PWhi, PWlo, D_, D_);
        gemm_mfma<1,0><<<dim3(16, 16), 256, 0, stream>>>(PAhi, PAlo, PWhi, PWlo, BUF2, nullptr, nullptr, nullptr, NSEL_, D_, D_);
        splitw_kernel<0><<<dim3(32, 32), 256, 0, stream>>>(d2_wk, PWhi, PWlo, D_, D_);
        gemm_mfma<1,0><<<dim3(16, 16), 256, 0, stream>>>(PAhi, PAlo, PWhi, PWlo, BUF3, nullptr, nullptr, nullptr, NSEL_, D_, D_);
        splitw_kernel<0><<<dim3(32, 32), 256, 0, stream>>>(d2_wv, PWhi, PWlo, D_, D_);
        gemm_mfma<1,0><<<dim3(16, 16), 256, 0, stream>>>(PAhi, PAlo, PWhi, PWlo, V2, nullptr, nullptr, nullptr, NSEL_, D_, D_);
        rope_split_kernel<<<NSEL_, 256, 0, stream>>>(BUF2, QHp, QLp, T2_ - 1, SCALE_QK);
        rope_split_kernel<<<NSEL_, 256, 0, stream>>>(BUF3, KHp, KLp, T2_ - 1, 1.0f);
        vpack_kernel<<<dim3(T2_/64, B_*H_), 256, 0, stream>>>(V2, VTH, VTL, T2_);
        attn_mfma<<<dim3(T2_/64, B_*H_), 256, 0, stream>>>(QHp, QLp, KHp, KLp, VTH, VTL, BUF0, T2_);
        splita_kernel<0><<<dim3(32, 32), 256, 0, stream>>>(BUF0, PAhi, PAlo, NSEL_, D_);
        splitw_kernel<0><<<dim3(32, 32), 256, 0, stream>>>(d2_wo, PWhi, PWlo, D_, D_);
        gemm_mfma<1,1><<<dim3(16, 16), 256, 0, stream>>>(PAhi, PAlo, PWhi, PWlo, BUF2, BUF4, nullptr, nullptr, NSEL_, D_, D_); // h2
        rms_split_kernel<0><<<NSEL_, 256, 0, stream>>>(BUF2, d2_ln2, PAhi, PAlo, NSEL_);
        splitw_kernel<0><<<dim3(128, 32), 256, 0, stream>>>(d2_wg, PWhi, PWlo, D_, FF_);
        gemm_mfma<1,0><<<dim3(64, 16), 256, 0, stream>>>(PAhi, PAlo, PWhi, PWlo, BUFF, nullptr, nullptr, nullptr, NSEL_, FF_, D_);
        splitw_kernel<0><<<dim3(128, 32), 256, 0, stream>>>(d2_wu, PWhi, PWlo, D_, FF_);
        gemm_mfma<1,4><<<dim3(64, 16), 256, 0, stream>>>(PAhi, PAlo, PWhi, PWlo, nullptr, BUFF, PFhi, nullptr, NSEL_, FF_, D_);  // silu(wg)*wu -> packed hi
        splitw_kernel<0><<<dim3(32, 128), 256, 0, stream>>>(d2_wd, PWhi, PWlo, FF_, D_);
        gemm_mfma<1,1><<<dim3(16, 16), 256, 0, stream>>>(PFhi, PFlo, PWhi, PWlo, BUF3, BUF2, nullptr, nullptr, NSEL_, D_, FF_); // sel_out

        scatter_kernel<<<NSEL_, 256, 0, stream>>>(BUF4, BUF3, idxb, gate, out);
        return;
    }

    if (ws_size < NEED_OLD) return;

    // ================= fallback: f32 path =================
    float* BUF0 = ws;
    float* BUF1 = ws + BIG;
    float* BUF2 = ws + 2*BIG;
    float* BUF3 = ws + 3*BIG;
    float* BUF4 = ws + 4*BIG;
    float* BUFF = ws + 5*BIG;
    float* SM   = BUFF + (size_t)NTOK_ * FF_;
    float* gbuf = SM;
    float* dch  = SM + 4096;
    float* gate = SM + 8192;
    int*   idxb = (int*)(SM + 10240);

    rms_kernel<<<NTOK_, 256, 0, stream>>>(X, d1_ln1, BUF0);
    gemm128<0><<<dim3(16, 32), 256, 0, stream>>>(BUF0, d1_wq, BUF1, nullptr, NTOK_, D_, D_);
    gemm128<0><<<dim3(16, 32), 256, 0, stream>>>(BUF0, d1_wk, BUF2, nullptr, NTOK_, D_, D_);
    gemm128<0><<<dim3(16, 32), 256, 0, stream>>>(BUF0, d1_wv, BUF3, nullptr, NTOK_, D_, D_);
    rope_kernel<<<NTOK_*4, 256, 0, stream>>>(BUF1, NTOK_, T_);
    rope_kernel<<<NTOK_*4, 256, 0, stream>>>(BUF2, NTOK_, T_);
    attn_kernel<<<dim3(T_/32, B_*H_), 256, 0, stream>>>(BUF1, BUF2, BUF3, BUF4, T_);
    gemm128<1><<<dim3(16, 32), 256, 0, stream>>>(BUF4, d1_wo, BUF2, X, NTOK_, D_, D_);
    rms_kernel<<<NTOK_, 256, 0, stream>>>(BUF2, d1_ln2, BUF0);
    gemm128<0><<<dim3(64, 32), 256, 0, stream>>>(BUF0, d1_wg, BUFF, nullptr, NTOK_, FF_, D_);
    gemm128<2><<<dim3(64, 32), 256, 0, stream>>>(BUF0, d1_wu, BUFF, BUFF, NTOK_, FF_, D_);
    gemm128<1><<<dim3(16, 32), 256, 0, stream>>>(BUFF, d1_wd, BUF1, BUF2, NTOK_, D_, FF_);

    rms_kernel<<<NTOK_, 256, 0, stream>>>(X, p_ln, BUF0);
    gemm128<0><<<dim3(8, 32), 256, 0, stream>>>(BUF0, p_wg, BUF4, nullptr, NTOK_, PFF_, D_);
    gemm128<2><<<dim3(8, 32), 256, 0, stream>>>(BUF0, p_wu, BUF4, BUF4, NTOK_, PFF_, D_);
    gemm128<0><<<dim3(16, 32), 256, 0, stream>>>(BUF4, p_wd, BUF3, nullptr, NTOK_, D_, PFF_);

    router_kernel<<<NTOK_, 256, 0, stream>>>(X, BUF1, BUF3, gbuf, dch, out + 8388609);
    loss_kernel<<<1, 1024, 0, stream>>>(dch, out + 8388608);
    topk_kernel<<<B_, 1024, 0, stream>>>(gbuf, idxb, gate);
    gather_kernel<<<NSEL_, 256, 0, stream>>>(BUF1, idxb, BUF4);

    float* V2 = BUF4 + (size_t)NSEL_ * D_;
    rms_kernel<<<NSEL_, 256, 0, stream>>>(BUF4, d2_ln1, BUF0);
    gemm128<0><<<dim3(16, 16), 256, 0, stream>>>(BUF0, d2_wq, BUF2, nullptr, NSEL_, D_, D_);
    gemm128<0><<<dim3(16, 16), 256, 0, stream>>>(BUF0, d2_wk, BUF3, nullptr, NSEL_, D_, D_);
    gemm128<0><<<dim3(16, 16), 256, 0, stream>>>(BUF0, d2_wv, V2, nullptr, NSEL_, D_, D_);
    rope_kernel<<<NSEL_*4, 256, 0, stream>>>(BUF2, NSEL_, T2_);
    rope_kernel<<<NSEL_*4, 256, 0, stream>>>(BUF3, NSEL_, T2_);
    attn_kernel<<<dim3(T2_/32, B_*H_), 256, 0, stream>>>(BUF2, BUF3, V2, BUF0, T2_);
    gemm128<1><<<dim3(16, 16), 256, 0, stream>>>(BUF0, d2_wo, BUF2, BUF4, NSEL_, D_, D_);
    rms_kernel<<<NSEL_, 256, 0, stream>>>(BUF2, d2_ln2, BUF0);
    gemm128<0><<<dim3(64, 16), 256, 0, stream>>>(BUF0, d2_wg, BUFF, nullptr, NSEL_, FF_, D_);
    gemm128<2><<<dim3(64, 16), 256, 0, stream>>>(BUF0, d2_wu, BUFF, BUFF, NSEL_, FF_, D_);
    gemm128<1><<<dim3(16, 16), 256, 0, stream>>>(BUFF, d2_wd, BUF3, BUF2, NSEL_, D_, FF_);

    copy_kernel<<<8192, 256, 0, stream>>>(BUF1, out, (int)(BIG / 4));
    scatter_kernel<<<NSEL_, 256, 0, stream>>>(BUF4, BUF3, idxb, gate, out);
}

// Round 14
// 3041.927 us; speedup vs baseline: 1.0653x; 1.0115x over previous
//
#include <hip/hip_runtime.h>
#include <math.h>

#define D_    2048
#define H_    16
#define DH_   128
#define FF_   8192
#define PFF_  1024
#define B_    2
#define T_    2048
#define NTOK_ 4096
#define T2_   1024
#define NSEL_ 2048
#define EPS_  1e-6f
#define SCALE_QK 0.08838834764831845f  // 1/sqrt(128)

typedef __attribute__((ext_vector_type(8))) short bf16x8;
typedef __attribute__((ext_vector_type(4))) float f32x4;
typedef __attribute__((ext_vector_type(8))) unsigned short ushort8;

__device__ __forceinline__ float silu_f(float x) {
    return x / (1.0f + expf(-x));
}

__device__ __forceinline__ unsigned short bf16_rne(float f) {
    unsigned int u = __float_as_uint(f);
    unsigned int r = (u + 0x7fffu + ((u >> 16) & 1u)) >> 16;
    return (unsigned short)r;
}
__device__ __forceinline__ float bf16_tof(unsigned short h) {
    return __uint_as_float(((unsigned int)h) << 16);
}

// ---------------- RMSNorm: one block per row ----------------
__global__ __launch_bounds__(256) void rms_kernel(const float* __restrict__ x,
                                                  const float* __restrict__ w,
                                                  float* __restrict__ out) {
    int row = blockIdx.x;
    int tid = threadIdx.x;
    const float4* xr = (const float4*)(x + (size_t)row * D_);
    float4* orow = (float4*)(out + (size_t)row * D_);
    const float4* w4 = (const float4*)w;
    float4 v0 = xr[tid], v1 = xr[tid + 256];
    float s = v0.x*v0.x + v0.y*v0.y + v0.z*v0.z + v0.w*v0.w
            + v1.x*v1.x + v1.y*v1.y + v1.z*v1.z + v1.w*v1.w;
    __shared__ float red[256];
    red[tid] = s; __syncthreads();
    for (int off = 128; off > 0; off >>= 1) {
        if (tid < off) red[tid] += red[tid + off];
        __syncthreads();
    }
    float r = 1.0f / sqrtf(red[0] * (1.0f/2048.0f) + EPS_);
    float4 w0 = w4[tid], w1 = w4[tid + 256];
    float4 o0, o1;
    o0.x = v0.x*r*w0.x; o0.y = v0.y*r*w0.y; o0.z = v0.z*r*w0.z; o0.w = v0.w*r*w0.w;
    o1.x = v1.x*r*w1.x; o1.y = v1.y*r*w1.y; o1.z = v1.z*r*w1.z; o1.w = v1.w*r*w1.w;
    orow[tid] = o0; orow[tid + 256] = o1;
}

// ---------------- weight transpose+split: B[K][N] f32 -> Phi(/Plo)[k/8][n][8] bf16 ----------------
template<int WLO>
__global__ __launch_bounds__(256) void splitw_kernel(const float* __restrict__ W,
                                                     unsigned short* __restrict__ phi,
                                                     unsigned short* __restrict__ plo,
                                                     int K, int N) {
    __shared__ float Ts[64][68];
    int n0 = blockIdx.x << 6, k0 = blockIdx.y << 6;
    int tid = threadIdx.x;
#pragma unroll
    for (int it = 0; it < 4; ++it) {
        int idx = tid + (it << 8);
        int kr = idx >> 4, c4 = idx & 15;
        float4 v = *(const float4*)(W + (size_t)(k0 + kr) * N + n0 + (c4 << 2));
        Ts[kr][c4*4+0] = v.x; Ts[kr][c4*4+1] = v.y; Ts[kr][c4*4+2] = v.z; Ts[kr][c4*4+3] = v.w;
    }
    __syncthreads();
#pragma unroll
    for (int h = 0; h < 2; ++h) {
        int c = tid + (h << 8);              // [0,512)
        int kc = c >> 6, n = c & 63;
        ushort8 hi, lo;
#pragma unroll
        for (int q = 0; q < 8; ++q) {
            float v = Ts[kc*8 + q][n];
            unsigned short hb = bf16_rne(v);
            hi[q] = hb;
            if (WLO) lo[q] = bf16_rne(v - bf16_tof(hb));
        }
        size_t off = ((size_t)((k0 >> 3) + kc) * N + (n0 + n)) * 8;
        *(ushort8*)(phi + off) = hi;
        if (WLO) *(ushort8*)(plo + off) = lo;
    }
}

// ---------------- activation split: A[M][K] f32 -> Phi(/Plo)[k/8][m][8] bf16 ----------------
template<int WLO>
__global__ __launch_bounds__(256) void splita_kernel(const float* __restrict__ A,
                                                     unsigned short* __restrict__ phi,
                                                     unsigned short* __restrict__ plo,
                                                     int M, int K) {
    __shared__ float Ts[64][68];
    int m0 = blockIdx.x << 6, k0 = blockIdx.y << 6;
    int tid = threadIdx.x;
#pragma unroll
    for (int it = 0; it < 4; ++it) {
        int idx = tid + (it << 8);
        int mr = idx >> 4, c4 = idx & 15;
        float4 v = *(const float4*)(A + (size_t)(m0 + mr) * K + k0 + (c4 << 2));
        Ts[mr][c4*4+0] = v.x; Ts[mr][c4*4+1] = v.y; Ts[mr][c4*4+2] = v.z; Ts[mr][c4*4+3] = v.w;
    }
    __syncthreads();
#pragma unroll
    for (int h = 0; h < 2; ++h) {
        int c = tid + (h << 8);
        int kc = c >> 6, m = c & 63;
        const float* src = &Ts[m][kc << 3];
        ushort8 hi, lo;
#pragma unroll
        for (int q = 0; q < 8; ++q) {
            float v = src[q];
            unsigned short hb = bf16_rne(v);
            hi[q] = hb;
            if (WLO) lo[q] = bf16_rne(v - bf16_tof(hb));
        }
        size_t off = ((size_t)((k0 >> 3) + kc) * M + (m0 + m)) * 8;
        *(ushort8*)(phi + off) = hi;
        if (WLO) *(ushort8*)(plo + off) = lo;
    }
}

// ---------------- bf16(x3) MFMA GEMM, 128x128 tile, BK=32, 2-phase dbuf, 16x16x32 MFMA ----------------
// Block map: XCD-chunked + paired-column decode (2 B-panels L2-resident, A shared by pair).
// EPI 0: C=acc ; 1: C=acc+Rg ; 2: C=silu(Rg)*acc ;
// EPI 3: packed hi/lo panels = silu(Rg)*acc ; EPI 4: packed hi panel only.
__device__ __forceinline__ void stage_panel(unsigned short* lds,
                                            const unsigned short* __restrict__ panel,
                                            int ktile, int R, int brow, int tid) {
#pragma unroll
    for (int h = 0; h < 2; ++h) {
        int c = tid + (h << 8);              // [0,512): kc = c>>7, row = c&127
        const unsigned short* g = panel + ((size_t)((ktile << 2) + (c >> 7)) * R + (brow + (c & 127))) * 8;
        __builtin_amdgcn_global_load_lds((const __attribute__((address_space(1))) void*)g,
                                         (__attribute__((address_space(3))) void*)(lds + (size_t)c * 8),
                                         16, 0, 0);
    }
}

template<int NP, int EPI>
__global__ __launch_bounds__(256) void gemm_mfma(const unsigned short* __restrict__ pah,
                                                 const unsigned short* __restrict__ pal,
                                                 const unsigned short* __restrict__ pbh,
                                                 const unsigned short* __restrict__ pbl,
                                                 float* __restrict__ C,
                                                 const float* __restrict__ Rg,
                                                 unsigned short* __restrict__ Cph,
                                                 unsigned short* __restrict__ Cpl,
                                                 int M, int N, int K) {
    constexpr int NPAN = (NP == 3) ? 2 : 1;
    __shared__ __align__(16) unsigned short As[2][NPAN][4][128][8];
    __shared__ __align__(16) unsigned short Bs[2][NPAN][4][128][8];
    const int tid = threadIdx.x;
    // T1: XCD-aware bijective block swizzle (all grids here have nwg % 8 == 0)
    int nwg = gridDim.x * gridDim.y;
    int wg = blockIdx.y * gridDim.x + blockIdx.x;
    if ((nwg & 7) == 0) {
        int cpx = nwg >> 3;
        wg = (wg & 7) * cpx + (wg >> 3);
    }
    // paired-column decode: consecutive wg alternate between 2 adjacent bn-columns
    // at the same bm-row, so each streamed A panel serves both columns while the
    // two B panels stay L2-resident. Bijective for even gridDim.x.
    const int gy2 = gridDim.y << 1;
    const int sc = wg / gy2;
    const int wr = wg - sc * gy2;
    const int bxs = (sc << 1) + (wr & 1), bys = wr >> 1;
    const int bm = bys << 7, bn = bxs << 7;
    const int lane = tid & 63, wave = tid >> 6;
    const int wm = (wave >> 1) << 6, wn = (wave & 1) << 6;
    const int fr = lane & 15, fk = lane >> 4;

    f32x4 acc[4][4];
#pragma unroll
    for (int i = 0; i < 4; ++i)
#pragma unroll
        for (int j = 0; j < 4; ++j) acc[i][j] = (f32x4)0.0f;

    const int nkt = K >> 5;

    // prologue stage tile 0 into buf 0
    stage_panel(&As[0][0][0][0][0], pah, 0, M, bm, tid);
    if (NP == 3) stage_panel(&As[0][1][0][0][0], pal, 0, M, bm, tid);
    stage_panel(&Bs[0][0][0][0][0], pbh, 0, N, bn, tid);
    if (NP == 3) stage_panel(&Bs[0][1][0][0][0], pbl, 0, N, bn, tid);
    __syncthreads();

    int cur = 0;
    for (int kt = 0; kt < nkt; ++kt) {
        // T3 minimum 2-phase: issue next-tile stage BEFORE ds_read+MFMA
        if (kt + 1 < nkt) {
            int nxt = cur ^ 1;
            stage_panel(&As[nxt][0][0][0][0], pah, kt + 1, M, bm, tid);
            if (NP == 3) stage_panel(&As[nxt][1][0][0][0], pal, kt + 1, M, bm, tid);
            stage_panel(&Bs[nxt][0][0][0][0], pbh, kt + 1, N, bn, tid);
            if (NP == 3) stage_panel(&Bs[nxt][1][0][0][0], pbl, kt + 1, N, bn, tid);
        }

        bf16x8 ah[4], bh[4], al[4], bl[4];
#pragma unroll
        for (int i = 0; i < 4; ++i) {
            ah[i] = *(const bf16x8*)&As[cur][0][fk][wm + (i << 4) + fr][0];
            if (NP == 3) al[i] = *(const bf16x8*)&As[cur][NPAN-1][fk][wm + (i << 4) + fr][0];
        }
#pragma unroll
        for (int j = 0; j < 4; ++j) {
            bh[j] = *(const bf16x8*)&Bs[cur][0][fk][wn + (j << 4) + fr][0];
            if (NP == 3) bl[j] = *(const bf16x8*)&Bs[cur][NPAN-1][fk][wn + (j << 4) + fr][0];
        }
#pragma unroll
        for (int i = 0; i < 4; ++i)
#pragma unroll
            for (int j = 0; j < 4; ++j) {
                acc[i][j] = __builtin_amdgcn_mfma_f32_16x16x32_bf16(ah[i], bh[j], acc[i][j], 0, 0, 0);
                if (NP == 3) {
                    acc[i][j] = __builtin_amdgcn_mfma_f32_16x16x32_bf16(ah[i], bl[j], acc[i][j], 0, 0, 0);
                    acc[i][j] = __builtin_amdgcn_mfma_f32_16x16x32_bf16(al[i], bh[j], acc[i][j], 0, 0, 0);
                }
            }
        __syncthreads();   // next-tile stage complete; buf[cur] reads all drained
        cur ^= 1;
    }

#pragma unroll
    for (int i = 0; i < 4; ++i) {
        int row0 = bm + wm + (i << 4) + (fk << 2);
#pragma unroll
        for (int j = 0; j < 4; ++j) {
            int col = bn + wn + (j << 4) + fr;
#pragma unroll
            for (int r = 0; r < 4; ++r) {
                int row = row0 + r;
                size_t off = (size_t)row * N + col;
                float v = acc[i][j][r];
                if (EPI == 0) {
                    C[off] = v;
                } else if (EPI == 1) {
                    C[off] = v + Rg[off];
                } else if (EPI == 2) {
                    C[off] = silu_f(Rg[off]) * v;
                } else {
                    v = silu_f(Rg[off]) * v;
                    unsigned short hb = bf16_rne(v);
                    size_t poff = (((size_t)(col >> 3)) * M + row) * 8 + (col & 7);
                    Cph[poff] = hb;
                    if (EPI == 3) Cpl[poff] = bf16_rne(v - bf16_tof(hb));
                }
            }
        }
    }
}

// ---------------- fused RoPE + scale + hi/lo split ----------------
__global__ __launch_bounds__(256) void rope_split_kernel(const float* __restrict__ X,
                                                         unsigned short* __restrict__ xh,
                                                         unsigned short* __restrict__ xl,
                                                         int seqmask, float scale) {
    int tok = blockIdx.x;
    int tid = threadIdx.x;
    int h = tid >> 4, d0 = (tid & 15) << 3;
    int pos = tok & seqmask;
    const float* src = X + (size_t)tok * D_ + h * DH_;
    bool lohalf = d0 < 64;
    float out[8];
#pragma unroll
    for (int q = 0; q < 8; ++q) {
        int d = d0 + q;
        int i = lohalf ? d : (d - 64);
        float e = (float)(2 * i) * (1.0f / 128.0f);
        float inv = 1.0f / powf(10000.0f, e);
        float ang = (float)pos * inv;
        float c = cosf(ang), s = sinf(ang);
        float x1 = src[i], x2 = src[i + 64];
        out[q] = lohalf ? (x1 * c - x2 * s) : (x2 * c + x1 * s);
    }
    ushort8 hi, lo;
#pragma unroll
    for (int q = 0; q < 8; ++q) {
        float v = out[q] * scale;
        unsigned short hb = bf16_rne(v);
        hi[q] = hb;
        lo[q] = bf16_rne(v - bf16_tof(hb));
    }
    size_t off = (size_t)tok * D_ + h * DH_ + d0;
    *(ushort8*)(xh + off) = hi;
    *(ushort8*)(xl + off) = lo;
}

// ---------------- V pack: f32 [b*T+t][2048] -> Vt[bh][T/8][128][8] bf16 hi/lo ----------------
__global__ __launch_bounds__(256) void vpack_kernel(const float* __restrict__ V,
                                                    unsigned short* __restrict__ vth,
                                                    unsigned short* __restrict__ vtl,
                                                    int T) {
    __shared__ float Ts[64][132];
    int kt = blockIdx.x, bh = blockIdx.y;
    int b = bh >> 4, h = bh & 15;
    int tid = threadIdx.x;
#pragma unroll
    for (int it = 0; it < 8; ++it) {
        int idx = tid + (it << 8);          // [0,2048)
        int r = idx >> 5, c4 = idx & 31;    // r in [0,64), c4 in [0,32)
        float4 v = *(const float4*)(V + ((size_t)(b * T + kt * 64 + r)) * D_ + h * DH_ + (c4 << 2));
        Ts[r][c4*4+0] = v.x; Ts[r][c4*4+1] = v.y; Ts[r][c4*4+2] = v.z; Ts[r][c4*4+3] = v.w;
    }
    __syncthreads();
    size_t obase = ((size_t)bh * (size_t)(T >> 3) + (size_t)kt * 8) * 1024;
#pragma unroll
    for (int it = 0; it < 4; ++it) {
        int c = tid + (it << 8);            // [0,1024): kc = c>>7, dh = c&127
        int kc = c >> 7, dh = c & 127;
        ushort8 hi, lo;
#pragma unroll
        for (int q = 0; q < 8; ++q) {
            float v = Ts[kc * 8 + q][dh];
            unsigned short hb = bf16_rne(v);
            hi[q] = hb;
            lo[q] = bf16_rne(v - bf16_tof(hb));
        }
        *(ushort8*)(vth + obase + (size_t)kc * 1024 + dh * 8) = hi;
        *(ushort8*)(vtl + obase + (size_t)kc * 1024 + dh * 8) = lo;
    }
}

// ---------------- bf16x3 MFMA flash attention ----------------
// grid: (T/64, B_*H_), block 256 (4 waves, each owns 16 q-rows)
__global__ __launch_bounds__(256) void attn_mfma(const unsigned short* __restrict__ QH,
                                                 const unsigned short* __restrict__ QL,
                                                 const unsigned short* __restrict__ KH,
                                                 const unsigned short* __restrict__ KL,
                                                 const unsigned short* __restrict__ VTH,
                                                 const unsigned short* __restrict__ VTL,
                                                 float* __restrict__ O, int T) {
    __shared__ __align__(16) unsigned short KV[16384];
    __shared__ __align__(16) float Ss[4096];
    __shared__ __align__(16) float mrow[64];
    __shared__ __align__(16) float lrow[64];
    __shared__ __align__(16) float crow[64];

    const int tid = threadIdx.x;
    const int qt = blockIdx.x, bh = blockIdx.y;
    const int b = bh >> 4, h = bh & 15;
    const int lane = tid & 63, w = tid >> 6;
    const int fr = lane & 15, fk = lane >> 4;
    const size_t tok0 = (size_t)b * T;

    char* lds_kv = (char*)&KV[0];
    char* lds_sp = (char*)&Ss[0];

    bf16x8 qfh[4], qfl[4];
    {
        const size_t qoff = (tok0 + (size_t)qt * 64 + w * 16 + fr) * D_ + h * DH_ + fk * 8;
#pragma unroll
        for (int ks = 0; ks < 4; ++ks) {
            qfh[ks] = *(const bf16x8*)(QH + qoff + ks * 32);
            qfl[ks] = *(const bf16x8*)(QL + qoff + ks * 32);
        }
    }
    if (tid < 64) { mrow[tid] = -1e30f; lrow[tid] = 0.f; }

    f32x4 acc[8];
#pragma unroll
    for (int nt = 0; nt < 8; ++nt) acc[nt] = (f32x4)0.f;

    const int srow = tid >> 2, sslot = tid & 3;
    const size_t vbase = (size_t)bh * (size_t)(T >> 3) * 1024;

    for (int kt = 0; kt <= qt; ++kt) {
        __syncthreads();
#pragma unroll
        for (int it = 0; it < 4; ++it) {
            int c = tid + (it << 8);
            int t = c >> 4;
            int sp = (c & 15) ^ (t & 7);
            size_t goff = (tok0 + (size_t)kt * 64 + t) * D_ + h * DH_ + sp * 8;
            __builtin_amdgcn_global_load_lds((const __attribute__((address_space(1))) void*)(KH + goff),
                (__attribute__((address_space(3))) void*)(lds_kv + c * 16), 16, 0, 0);
            __builtin_amdgcn_global_load_lds((const __attribute__((address_space(1))) void*)(KL + goff),
                (__attribute__((address_space(3))) void*)(lds_kv + 16384 + c * 16), 16, 0, 0);
        }
        __syncthreads();
        {
            f32x4 s[4];
#pragma unroll
            for (int nt = 0; nt < 4; ++nt) s[nt] = (f32x4)0.f;
#pragma unroll
            for (int ks = 0; ks < 4; ++ks) {
#pragma unroll
                for (int nt = 0; nt < 4; ++nt) {
                    int n = nt * 16 + fr;
                    int offk = (n * 256 + ks * 64 + fk * 16) ^ ((n & 7) << 4);
                    bf16x8 kfh = *(const bf16x8*)(lds_kv + offk);
                    bf16x8 kfl = *(const bf16x8*)(lds_kv + 16384 + offk);
                    s[nt] = __builtin_amdgcn_mfma_f32_16x16x32_bf16(qfh[ks], kfh, s[nt], 0, 0, 0);
                    s[nt] = __builtin_amdgcn_mfma_f32_16x16x32_bf16(qfh[ks], kfl, s[nt], 0, 0, 0);
                    s[nt] = __builtin_amdgcn_mfma_f32_16x16x32_bf16(qfl[ks], kfh, s[nt], 0, 0, 0);
                }
            }
#pragma unroll
            for (int nt = 0; nt < 4; ++nt)
#pragma unroll
                for (int r = 0; r < 4; ++r) {
                    int row = w * 16 + fk * 4 + r;
                    int col = nt * 16 + fr;
                    *(float*)(lds_sp + ((row * 256 + col * 4) ^ ((row & 7) << 4))) = s[nt][r];
                }
        }
        __syncthreads();
#pragma unroll
        for (int it = 0; it < 4; ++it) {
            int c = tid + (it << 8);
            size_t goff = vbase + (size_t)kt * 8192 + (size_t)c * 8;
            __builtin_amdgcn_global_load_lds((const __attribute__((address_space(1))) void*)(VTH + goff),
                (__attribute__((address_space(3))) void*)(lds_kv + c * 16), 16, 0, 0);
            __builtin_amdgcn_global_load_lds((const __attribute__((address_space(1))) void*)(VTL + goff),
                (__attribute__((address_space(3))) void*)(lds_kv + 16384 + c * 16), 16, 0, 0);
        }
        float p[16];
        float newm, psum, cr, oldl;
        {
            float tmax = -1e30f;
            int colbase = sslot * 16;
#pragma unroll
            for (int q4 = 0; q4 < 4; ++q4) {
                f32x4 sv = *(const f32x4*)(lds_sp + ((srow * 256 + sslot * 64 + q4 * 16) ^ ((srow & 7) << 4)));
#pragma unroll
                for (int e = 0; e < 4; ++e) {
                    float v = sv[e];
                    if (kt == qt && (colbase + q4 * 4 + e) > srow) v = -1e30f;
                    p[q4 * 4 + e] = v;
                    tmax = fmaxf(tmax, v);
                }
            }
            tmax = fmaxf(tmax, __shfl_xor(tmax, 1, 64));
            tmax = fmaxf(tmax, __shfl_xor(tmax, 2, 64));
            float oldm = mrow[srow];
            oldl = lrow[srow];
            newm = fmaxf(oldm, tmax);
            psum = 0.f;
#pragma unroll
            for (int e = 0; e < 16; ++e) { p[e] = expf(p[e] - newm); psum += p[e]; }
            psum += __shfl_xor(psum, 1, 64);
            psum += __shfl_xor(psum, 2, 64);
            cr = expf(oldm - newm);
        }
        __syncthreads();
        {
            ushort8 h0, h1, l0, l1;
#pragma unroll
            for (int e = 0; e < 8; ++e) {
                unsigned short hb = bf16_rne(p[e]);
                h0[e] = hb; l0[e] = bf16_rne(p[e] - bf16_tof(hb));
                unsigned short hb2 = bf16_rne(p[8 + e]);
                h1[e] = hb2; l1[e] = bf16_rne(p[8 + e] - bf16_tof(hb2));
            }
            int base = srow * 128 + sslot * 32;
            int swz = (srow & 7) << 4;
            *(ushort8*)(lds_sp + (base ^ swz)) = h0;
            *(ushort8*)(lds_sp + ((base + 16) ^ swz)) = h1;
            *(ushort8*)(lds_sp + 8192 + (base ^ swz)) = l0;
            *(ushort8*)(lds_sp + 8192 + ((base + 16) ^ swz)) = l1;
            if (sslot == 0) { mrow[srow] = newm; lrow[srow] = oldl * cr + psum; crow[srow] = cr; }
        }
        __syncthreads();
        {
            f32x4 crv = *(const f32x4*)&crow[w * 16 + fk * 4];
#pragma unroll
            for (int nt = 0; nt < 8; ++nt)
#pragma unroll
                for (int r = 0; r < 4; ++r) acc[nt][r] *= crv[r];
            int m = w * 16 + fr;
#pragma unroll
            for (int ks = 0; ks < 2; ++ks) {
                int offp = (m * 128 + ks * 64 + fk * 16) ^ ((m & 7) << 4);
                bf16x8 pfh = *(const bf16x8*)(lds_sp + offp);
                bf16x8 pfl = *(const bf16x8*)(lds_sp + 8192 + offp);
#pragma unroll
                for (int nt = 0; nt < 8; ++nt) {
                    int offv = (ks * 4 + fk) * 2048 + (nt * 16 + fr) * 16;
                    bf16x8 vfh = *(const bf16x8*)(lds_kv + offv);
                    bf16x8 vfl = *(const bf16x8*)(lds_kv + 16384 + offv);
                    acc[nt] = __builtin_amdgcn_mfma_f32_16x16x32_bf16(pfh, vfh, acc[nt], 0, 0, 0);
                    acc[nt] = __builtin_amdgcn_mfma_f32_16x16x32_bf16(pfh, vfl, acc[nt], 0, 0, 0);
                    acc[nt] = __builtin_amdgcn_mfma_f32_16x16x32_bf16(pfl, vfh, acc[nt], 0, 0, 0);
                }
            }
        }
    }
    __syncthreads();
    {
        f32x4 lv = *(const f32x4*)&lrow[w * 16 + fk * 4];
        float* orow = O + (tok0 + (size_t)qt * 64 + w * 16 + fk * 4) * D_ + h * DH_;
#pragma unroll
        for (int r = 0; r < 4; ++r) {
            float inv = 1.0f / lv[r];
#pragma unroll
            for (int nt = 0; nt < 8; ++nt)
                orow[(size_t)r * D_ + nt * 16 + fr] = acc[nt][r] * inv;
        }
    }
}

// ---------------- f32 GEMM (fallback path) ----------------
template<int EPI>
__global__ __launch_bounds__(256) void gemm128(const float* __restrict__ A,
                                               const float* __restrict__ Bm,
                                               float* __restrict__ C,
                                               const float* __restrict__ Rg,
                                               int M, int N, int K) {
    __shared__ float Ast[16][132];
    __shared__ float Bs[16][132];
    int bm = blockIdx.y << 7, bn = blockIdx.x << 7;
    int tid = threadIdx.x;
    int ty = tid >> 4, tx = tid & 15;
    float acc[8][8];
#pragma unroll
    for (int i = 0; i < 8; ++i)
#pragma unroll
        for (int j = 0; j < 8; ++j) acc[i][j] = 0.f;

    for (int k0 = 0; k0 < K; k0 += 16) {
#pragma unroll
        for (int it = 0; it < 2; ++it) {
            int idx = tid + (it << 8);
            int ar = idx >> 2, ac = idx & 3;
            float4 av = *(const float4*)(A + (size_t)(bm + ar) * K + k0 + (ac << 2));
            Ast[ac*4+0][ar] = av.x; Ast[ac*4+1][ar] = av.y;
            Ast[ac*4+2][ar] = av.z; Ast[ac*4+3][ar] = av.w;
            int br = idx >> 5, bc = idx & 31;
            float4 bv = *(const float4*)(Bm + (size_t)(k0 + br) * N + bn + (bc << 2));
            *(float4*)&Bs[br][bc << 2] = bv;
        }
        __syncthreads();
#pragma unroll
        for (int kk = 0; kk < 16; ++kk) {
            float a[8], b[8];
            *(float4*)&a[0] = *(const float4*)&Ast[kk][ty*4];
            *(float4*)&a[4] = *(const float4*)&Ast[kk][64 + ty*4];
            *(float4*)&b[0] = *(const float4*)&Bs[kk][tx*4];
            *(float4*)&b[4] = *(const float4*)&Bs[kk][64 + tx*4];
#pragma unroll
            for (int i = 0; i < 8; ++i)
#pragma unroll
                for (int j = 0; j < 8; ++j)
                    acc[i][j] += a[i] * b[j];
        }
        __syncthreads();
    }
#pragma unroll
    for (int i = 0; i < 8; ++i) {
        int row = bm + ((i < 4) ? (ty*4 + i) : (64 + ty*4 + (i - 4)));
#pragma unroll
        for (int half = 0; half < 2; ++half) {
            int col = bn + half*64 + tx*4;
            size_t off = (size_t)row * N + col;
            const float* ap = &acc[i][half*4];
            float4 r;
            if (EPI == 0) {
                r.x = ap[0]; r.y = ap[1]; r.z = ap[2]; r.w = ap[3];
            } else if (EPI == 1) {
                float4 rv = *(const float4*)(Rg + off);
                r.x = ap[0] + rv.x; r.y = ap[1] + rv.y;
                r.z = ap[2] + rv.z; r.w = ap[3] + rv.w;
            } else {
                float4 gv = *(const float4*)(Rg + off);
                r.x = silu_f(gv.x) * ap[0]; r.y = silu_f(gv.y) * ap[1];
                r.z = silu_f(gv.z) * ap[2]; r.w = silu_f(gv.w) * ap[3];
            }
            *(float4*)(C + off) = r;
        }
    }
}

// ---------------- RoPE in place (f32, fallback) ----------------
__global__ __launch_bounds__(256) void rope_kernel(float* __restrict__ q, int nrows, int seqlen) {
    int gid = blockIdx.x * 256 + threadIdx.x;
    int tok = gid >> 10;
    if (tok >= nrows) return;
    int rest = gid & 1023;
    int h = rest >> 6, i = rest & 63;
    int pos = tok % seqlen;
    float e = (float)(2 * i) * (1.0f / 128.0f);
    float inv = 1.0f / powf(10000.0f, e);
    float ang = (float)pos * inv;
    float c = cosf(ang), s = sinf(ang);
    size_t base = (size_t)tok * D_ + h * 128 + i;
    float x1 = q[base], x2 = q[base + 64];
    q[base]      = x1 * c - x2 * s;
    q[base + 64] = x2 * c + x1 * s;
}

// ---------------- flash attention f32 (fallback) ----------------
__global__ __launch_bounds__(256) void attn_kernel(const float* __restrict__ Q,
                                                   const float* __restrict__ K,
                                                   const float* __restrict__ V,
                                                   float* __restrict__ O,
                                                   int T) {
    int qt = blockIdx.x;
    int bh = blockIdx.y;
    int b = bh >> 4, h = bh & 15;
    int tid = threadIdx.x;

    __shared__ float4 Qs[32][32];
    __shared__ float4 KVs[64][32];
    __shared__ float Sst[32][65];
    __shared__ float mrow[32], lrow[32], crow[32];

    const size_t headoff = (size_t)h * DH_;
    const size_t bbase = (size_t)b * T * D_;

#pragma unroll
    for (int i = 0; i < 4; ++i) {
        int idx = tid + i * 256;
        int r = idx >> 5, ch = idx & 31;
        const float4* src = (const float4*)(Q + bbase + (size_t)(qt*32 + r) * D_ + headoff);
        Qs[r][ch ^ ((r >> 2) & 7)] = src[ch];
    }
    if (tid < 32) { mrow[tid] = -1e30f; lrow[tid] = 0.f; }

    int ty16 = tid >> 4, tx16 = tid & 15;
    int r8 = tid >> 3, q8 = tid & 7;
    float o[2][8];
#pragma unroll
    for (int i = 0; i < 2; ++i)
#pragma unroll
        for (int j = 0; j < 8; ++j) o[i][j] = 0.f;

    int ktmax = (qt * 32 + 31) >> 6;
    for (int kt = 0; kt <= ktmax; ++kt) {
        __syncthreads();
#pragma unroll
        for (int i = 0; i < 8; ++i) {
            int idx = tid + i * 256;
            int r = idx >> 5, ch = idx & 31;
            const float4* src = (const float4*)(K + bbase + (size_t)(kt*64 + r) * D_ + headoff);
            KVs[r][ch ^ ((r >> 2) & 7)] = src[ch];
        }
        __syncthreads();
        {
            float s[2][4];
#pragma unroll
            for (int i = 0; i < 2; ++i)
#pragma unroll
                for (int j = 0; j < 4; ++j) s[i][j] = 0.f;
#pragma unroll
            for (int ch = 0; ch < 32; ++ch) {
                float4 qv[2], kv[4];
#pragma unroll
                for (int i = 0; i < 2; ++i) { int r = ty16*2 + i; qv[i] = Qs[r][ch ^ ((r >> 2) & 7)]; }
#pragma unroll
                for (int j = 0; j < 4; ++j) { int c = tx16*4 + j; kv[j] = KVs[c][ch ^ ((c >> 2) & 7)]; }
#pragma unroll
                for (int i = 0; i < 2; ++i)
#pragma unroll
                    for (int j = 0; j < 4; ++j)
                        s[i][j] += qv[i].x*kv[j].x + qv[i].y*kv[j].y + qv[i].z*kv[j].z + qv[i].w*kv[j].w;
            }
#pragma unroll
            for (int i = 0; i < 2; ++i) {
                int grow = qt*32 + ty16*2 + i;
#pragma unroll
                for (int j = 0; j < 4; ++j) {
                    int gcol = kt*64 + tx16*4 + j;
                    float sv = s[i][j] * SCALE_QK;
                    if (gcol > grow) sv = -1e30f;
                    Sst[ty16*2 + i][tx16*4 + j] = sv;
                }
            }
        }
        __syncthreads();
#pragma unroll
        for (int i = 0; i < 8; ++i) {
            int idx = tid + i * 256;
            int r = idx >> 5, ch = idx & 31;
            const float4* src = (const float4*)(V + bbase + (size_t)(kt*64 + r) * D_ + headoff);
            KVs[r][ch ^ ((r >> 2) & 7)] = src[ch];
        }
        {
            float pv[8];
            float tmax = -1e30f;
#pragma unroll
            for (int c = 0; c < 8; ++c) { pv[c] = Sst[r8][q8*8 + c]; tmax = fmaxf(tmax, pv[c]); }
#pragma unroll
            for (int m = 1; m < 8; m <<= 1) tmax = fmaxf(tmax, __shfl_xor(tmax, m, 64));
            float oldm = mrow[r8];
            float newm = fmaxf(oldm, tmax);
            float psum = 0.f;
#pragma unroll
            for (int c = 0; c < 8; ++c) {
                float p = expf(pv[c] - newm);
                Sst[r8][q8*8 + c] = p;
                psum += p;
            }
#pragma unroll
            for (int m = 1; m < 8; m <<= 1) psum += __shfl_xor(psum, m, 64);
            if (q8 == 0) {
                float crv = expf(oldm - newm);
                crow[r8] = crv;
                lrow[r8] = lrow[r8] * crv + psum;
                mrow[r8] = newm;
            }
        }
        __syncthreads();
        {
            float crv[2];
#pragma unroll
            for (int i = 0; i < 2; ++i) {
                crv[i] = crow[ty16*2 + i];
#pragma unroll
                for (int j = 0; j < 8; ++j) o[i][j] *= crv[i];
            }
#pragma unroll
            for (int kc = 0; kc < 64; ++kc) {
                int swz = (kc >> 2) & 7;
                float4 v0 = KVs[kc][tx16 ^ swz];
                float4 v1 = KVs[kc][(16 + tx16) ^ swz];
#pragma unroll
                for (int i = 0; i < 2; ++i) {
                    float p = Sst[ty16*2 + i][kc];
                    o[i][0] += p*v0.x; o[i][1] += p*v0.y; o[i][2] += p*v0.z; o[i][3] += p*v0.w;
                    o[i][4] += p*v1.x; o[i][5] += p*v1.y; o[i][6] += p*v1.z; o[i][7] += p*v1.w;
                }
            }
        }
    }
#pragma unroll
    for (int i = 0; i < 2; ++i) {
        int r = ty16*2 + i;
        float inv = 1.0f / lrow[r];
        float4 a, bb;
        a.x = o[i][0]*inv; a.y = o[i][1]*inv; a.z = o[i][2]*inv; a.w = o[i][3]*inv;
        bb.x = o[i][4]*inv; bb.y = o[i][5]*inv; bb.z = o[i][6]*inv; bb.w = o[i][7]*inv;
        float* dst = O + bbase + (size_t)(qt*32 + r) * D_ + headoff;
        ((float4*)dst)[tx16] = a;
        ((float4*)dst)[16 + tx16] = bb;
    }
}

// ---------------- router / loss / topk / gather / copy / scatter ----------------
__global__ __launch_bounds__(256) void router_kernel(const float* __restrict__ x,
                                                     const float* __restrict__ proc,
                                                     const float* __restrict__ prior,
                                                     float* __restrict__ gbuf,
                                                     float* __restrict__ dchbuf,
                                                     float* __restrict__ gout) {
    int row = blockIdx.x, tid = threadIdx.x;
    const float4* x4 = (const float4*)(x + (size_t)row * D_);
    const float4* p4 = (const float4*)(proc + (size_t)row * D_);
    const float4* r4 = (const float4*)(prior + (size_t)row * D_);
    float sst = 0.f, sch = 0.f;
#pragma unroll
    for (int it = 0; it < 2; ++it) {
        int i = tid + it * 256;
        float4 xv = x4[i], pv = p4[i], rv = r4[i];
        float a0 = pv.x - xv.x, a1 = pv.y - xv.y, a2 = pv.z - xv.z, a3 = pv.w - xv.w;
        sst += a0*a0 + a1*a1 + a2*a2 + a3*a3;
        float d0 = a0 - rv.x, d1 = a1 - rv.y, d2 = a2 - rv.z, d3 = a3 - rv.w;
        sch += d0*d0 + d1*d1 + d2*d2 + d3*d3;
    }
    __shared__ float rs[256], rc[256];
    rs[tid] = sst; rc[tid] = sch; __syncthreads();
    for (int off = 128; off > 0; off >>= 1) {
        if (tid < off) { rs[tid] += rs[tid + off]; rc[tid] += rc[tid + off]; }
        __syncthreads();
    }
    if (tid == 0) {
        float Dst = rs[0] * (1.0f/2048.0f);
        float Dch = rc[0] * (1.0f/2048.0f);
        float g = 1.0f / (1.0f + expf(-(Dch - Dst)));
        gbuf[row] = g; dchbuf[row] = Dch; gout[row] = g;
    }
}

__global__ __launch_bounds__(1024) void loss_kernel(const float* __restrict__ dch, float* __restrict__ out) {
    __shared__ float red[1024];
    int tid = threadIdx.x;
    red[tid] = dch[tid] + dch[tid + 1024] + dch[tid + 2048] + dch[tid + 3072];
    __syncthreads();
    for (int off = 512; off > 0; off >>= 1) {
        if (tid < off) red[tid] += red[tid + off];
        __syncthreads();
    }
    if (tid == 0) out[0] = red[0] * (1.0f / 4096.0f);
}

__global__ __launch_bounds__(1024) void topk_kernel(const float* __restrict__ gbuf,
                                                    int* __restrict__ idxout,
                                                    float* __restrict__ gateout) {
    int b = blockIdx.x, tid = threadIdx.x;
    __shared__ float val[2048];
    __shared__ int idx[2048];
    val[tid] = gbuf[b*2048 + tid];           idx[tid] = tid;
    val[tid + 1024] = gbuf[b*2048 + tid + 1024]; idx[tid + 1024] = tid + 1024;
    __syncthreads();
    for (int kk = 2; kk <= 2048; kk <<= 1) {
        for (int j = kk >> 1; j > 0; j >>= 1) {
            for (int i = tid; i < 2048; i += 1024) {
                int ixj = i ^ j;
                if (ixj > i) {
                    bool up = ((i & kk) == 0);
                    float v1 = val[i], v2 = val[ixj];
                    int i1 = idx[i], i2 = idx[ixj];
                    bool sw = up ? ((v2 > v1) || (v2 == v1 && i2 < i1))
                                 : ((v1 > v2) || (v1 == v2 && i1 < i2));
                    if (sw) { val[i] = v2; val[ixj] = v1; idx[i] = i2; idx[ixj] = i1; }
                }
            }
            __syncthreads();
        }
    }
    if (tid < 1024) {
        idxout[b*1024 + tid] = idx[tid];
        gateout[b*1024 + tid] = val[tid];
    }
}

__global__ __launch_bounds__(256) void gather_kernel(const float* __restrict__ proc,
                                                     const int* __restrict__ idx,
                                                     float* __restrict__ sel) {
    int r = blockIdx.x;
    int b = r >> 10, rr = r & 1023;
    int tok = idx[b*1024 + rr];
    const float4* src = (const float4*)(proc + ((size_t)(b*2048 + tok)) * D_);
    float4* dst = (float4*)(sel + (size_t)r * D_);
    dst[threadIdx.x] = src[threadIdx.x];
    dst[threadIdx.x + 256] = src[threadIdx.x + 256];
}

__global__ __launch_bounds__(256) void copy_kernel(const float* __restrict__ src,
                                                   float* __restrict__ dst, int n4) {
    int i = blockIdx.x * 256 + threadIdx.x;
    if (i < n4) ((float4*)dst)[i] = ((const float4*)src)[i];
}

__global__ __launch_bounds__(256) void scatter_kernel(const float* __restrict__ sel,
                                                      const float* __restrict__ selout,
                                                      const int* __restrict__ idx,
                                                      const float* __restrict__ gate,
                                                      float* __restrict__ outp) {
    int r = blockIdx.x;
    int b = r >> 10, rr = r & 1023;
    int tok = idx[b*1024 + rr];
    float g = gate[b*1024 + rr];
    const float4* s4 = (const float4*)(sel + (size_t)r * D_);
    const float4* o4 = (const float4*)(selout + (size_t)r * D_);
    float4* d4 = (float4*)(outp + ((size_t)(b*2048 + tok)) * D_);
#pragma unroll
    for (int it = 0; it < 2; ++it) {
        int i = threadIdx.x + it * 256;
        float4 a = s4[i], o = o4[i];
        float4 w;
        w.x = a.x + g*(o.x - a.x); w.y = a.y + g*(o.y - a.y);
        w.z = a.z + g*(o.z - a.z); w.w = a.w + g*(o.w - a.w);
        d4[i] = w;
    }
}

extern "C" void kernel_launch(void* const* d_in, const int* in_sizes, int n_in,
                              void* d_out, int out_size, void* d_ws, size_t ws_size,
                              hipStream_t stream) {
    const float* X      = (const float*)d_in[0];
    const float* d1_ln1 = (const float*)d_in[1];
    const float* d1_ln2 = (const float*)d_in[2];
    const float* d1_wq  = (const float*)d_in[3];
    const float* d1_wk  = (const float*)d_in[4];
    const float* d1_wv  = (const float*)d_in[5];
    const float* d1_wo  = (const float*)d_in[6];
    const float* d1_wg  = (const float*)d_in[7];
    const float* d1_wu  = (const float*)d_in[8];
    const float* d1_wd  = (const float*)d_in[9];
    const float* d2_ln1 = (const float*)d_in[10];
    const float* d2_ln2 = (const float*)d_in[11];
    const float* d2_wq  = (const float*)d_in[12];
    const float* d2_wk  = (const float*)d_in[13];
    const float* d2_wv  = (const float*)d_in[14];
    const float* d2_wo  = (const float*)d_in[15];
    const float* d2_wg  = (const float*)d_in[16];
    const float* d2_wu  = (const float*)d_in[17];
    const float* d2_wd  = (const float*)d_in[18];
    const float* p_ln   = (const float*)d_in[19];
    const float* p_wg   = (const float*)d_in[20];
    const float* p_wu   = (const float*)d_in[21];
    const float* p_wd   = (const float*)d_in[22];

    float* out = (float*)d_out;
    float* ws  = (float*)d_ws;

    const size_t BIG = (size_t)NTOK_ * D_;           // 8M f32
    const size_t MEG = 1024 * 1024;

    const size_t NEED_NEW = (128 * MEG + 16384) * 4;  // ~512 MB
    const size_t NEED_OLD = ((5*BIG + (size_t)NTOK_*FF_ + 12288) * 4);

    if (ws_size >= NEED_NEW) {
        float* BUF0 = ws;                 // 8M f32
        float* BUF1 = ws + 8*MEG;         // q
        float* BUF2 = ws + 16*MEG;        // k / h
        float* BUF3 = ws + 24*MEG;        // v / prior_out / sel_out
        float* BUF4 = ws + 32*MEG;        // attnout / sel (+V2)
        float* BUFF = ws + 40*MEG;        // 32M f32 FF
        unsigned short* PWhi  = (unsigned short*)(ws + 72*MEG);
        unsigned short* PWlo  = (unsigned short*)(ws + 80*MEG);
        unsigned short* PAhi  = (unsigned short*)(ws + 88*MEG);
        unsigned short* PAlo  = (unsigned short*)(ws + 92*MEG);
        unsigned short* PFhi  = (unsigned short*)(ws + 96*MEG);
        unsigned short* PFlo  = (unsigned short*)(ws + 112*MEG);
        // attention packed buffers (overlay PF region; disjoint in time)
        unsigned short* U   = (unsigned short*)(ws + 96*MEG);
        const size_t PK = (size_t)NTOK_ * D_;         // 8.39M ushorts
        unsigned short* QHp = U;
        unsigned short* QLp = U + PK;
        unsigned short* KHp = U + 2*PK;
        unsigned short* KLp = U + 3*PK;
        unsigned short* VTH = U + 4*PK;
        unsigned short* VTL = U + 5*PK;
        float* SM   = ws + 128*MEG;
        float* gbuf = SM;
        float* dch  = SM + 4096;
        float* gate = SM + 8192;
        int*   idxb = (int*)(SM + 10240);

        float* PROC = out;                // processed lives directly in out

        // ---- decision decoder layer (bf16x3 GEMMs + bf16x3 MFMA attention) ----
        rms_kernel<<<NTOK_, 256, 0, stream>>>(X, d1_ln1, BUF0);
        splita_kernel<1><<<dim3(64, 32), 256, 0, stream>>>(BUF0, PAhi, PAlo, NTOK_, D_);
        splitw_kernel<1><<<dim3(32, 32), 256, 0, stream>>>(d1_wq, PWhi, PWlo, D_, D_);
        gemm_mfma<3,0><<<dim3(16, 32), 256, 0, stream>>>(PAhi, PAlo, PWhi, PWlo, BUF1, nullptr, nullptr, nullptr, NTOK_, D_, D_);
        splitw_kernel<1><<<dim3(32, 32), 256, 0, stream>>>(d1_wk, PWhi, PWlo, D_, D_);
        gemm_mfma<3,0><<<dim3(16, 32), 256, 0, stream>>>(PAhi, PAlo, PWhi, PWlo, BUF2, nullptr, nullptr, nullptr, NTOK_, D_, D_);
        splitw_kernel<1><<<dim3(32, 32), 256, 0, stream>>>(d1_wv, PWhi, PWlo, D_, D_);
        gemm_mfma<3,0><<<dim3(16, 32), 256, 0, stream>>>(PAhi, PAlo, PWhi, PWlo, BUF3, nullptr, nullptr, nullptr, NTOK_, D_, D_);
        rope_split_kernel<<<NTOK_, 256, 0, stream>>>(BUF1, QHp, QLp, T_ - 1, SCALE_QK);
        rope_split_kernel<<<NTOK_, 256, 0, stream>>>(BUF2, KHp, KLp, T_ - 1, 1.0f);
        vpack_kernel<<<dim3(T_/64, B_*H_), 256, 0, stream>>>(BUF3, VTH, VTL, T_);
        attn_mfma<<<dim3(T_/64, B_*H_), 256, 0, stream>>>(QHp, QLp, KHp, KLp, VTH, VTL, BUF4, T_);
        splita_kernel<1><<<dim3(64, 32), 256, 0, stream>>>(BUF4, PAhi, PAlo, NTOK_, D_);
        splitw_kernel<1><<<dim3(32, 32), 256, 0, stream>>>(d1_wo, PWhi, PWlo, D_, D_);
        gemm_mfma<3,1><<<dim3(16, 32), 256, 0, stream>>>(PAhi, PAlo, PWhi, PWlo, BUF2, X, nullptr, nullptr, NTOK_, D_, D_);  // h
        rms_kernel<<<NTOK_, 256, 0, stream>>>(BUF2, d1_ln2, BUF0);
        splita_kernel<1><<<dim3(64, 32), 256, 0, stream>>>(BUF0, PAhi, PAlo, NTOK_, D_);
        splitw_kernel<1><<<dim3(128, 32), 256, 0, stream>>>(d1_wg, PWhi, PWlo, D_, FF_);
        gemm_mfma<3,0><<<dim3(64, 32), 256, 0, stream>>>(PAhi, PAlo, PWhi, PWlo, BUFF, nullptr, nullptr, nullptr, NTOK_, FF_, D_);
        splitw_kernel<1><<<dim3(128, 32), 256, 0, stream>>>(d1_wu, PWhi, PWlo, D_, FF_);
        gemm_mfma<3,3><<<dim3(64, 32), 256, 0, stream>>>(PAhi, PAlo, PWhi, PWlo, nullptr, BUFF, PFhi, PFlo, NTOK_, FF_, D_);  // silu(wg)*wu -> packed
        splitw_kernel<1><<<dim3(32, 128), 256, 0, stream>>>(d1_wd, PWhi, PWlo, FF_, D_);
        gemm_mfma<3,1><<<dim3(16, 32), 256, 0, stream>>>(PFhi, PFlo, PWhi, PWlo, PROC, BUF2, nullptr, nullptr, NTOK_, D_, FF_); // processed -> out

        // ---- prior network (bf16x3) ----
        rms_kernel<<<NTOK_, 256, 0, stream>>>(X, p_ln, BUF0);
        splita_kernel<1><<<dim3(64, 32), 256, 0, stream>>>(BUF0, PAhi, PAlo, NTOK_, D_);
        splitw_kernel<1><<<dim3(16, 32), 256, 0, stream>>>(p_wg, PWhi, PWlo, D_, PFF_);
        gemm_mfma<3,0><<<dim3(8, 32), 256, 0, stream>>>(PAhi, PAlo, PWhi, PWlo, BUFF, nullptr, nullptr, nullptr, NTOK_, PFF_, D_);
        splitw_kernel<1><<<dim3(16, 32), 256, 0, stream>>>(p_wu, PWhi, PWlo, D_, PFF_);
        gemm_mfma<3,3><<<dim3(8, 32), 256, 0, stream>>>(PAhi, PAlo, PWhi, PWlo, nullptr, BUFF, PFhi, PFlo, NTOK_, PFF_, D_);
        splitw_kernel<1><<<dim3(32, 16), 256, 0, stream>>>(p_wd, PWhi, PWlo, PFF_, D_);
        gemm_mfma<3,0><<<dim3(16, 32), 256, 0, stream>>>(PFhi, PFlo, PWhi, PWlo, BUF3, nullptr, nullptr, nullptr, NTOK_, D_, PFF_); // prior_out

        // ---- router + loss + top-k + gather ----
        router_kernel<<<NTOK_, 256, 0, stream>>>(X, PROC, BUF3, gbuf, dch, out + 8388609);
        loss_kernel<<<1, 1024, 0, stream>>>(dch, out + 8388608);
        topk_kernel<<<B_, 1024, 0, stream>>>(gbuf, idxb, gate);
        gather_kernel<<<NSEL_, 256, 0, stream>>>(PROC, idxb, BUF4);   // sel

        // ---- dynamic decoder layer (bf16 NP=1 GEMMs, x3 MFMA attention) ----
        float* V2 = BUF4 + (size_t)NSEL_ * D_;
        rms_kernel<<<NSEL_, 256, 0, stream>>>(BUF4, d2_ln1, BUF0);
        splita_kernel<0><<<dim3(32, 32), 256, 0, stream>>>(BUF0, PAhi, PAlo, NSEL_, D_);
        splitw_kernel<0><<<dim3(32, 32), 256, 0, stream>>>(d2_wq, PWhi, PWlo, D_, D_);
        gemm_mfma<1,0><<<dim3(16, 16), 256, 0, stream>>>(PAhi, PAlo, PWhi, PWlo, BUF2, nullptr, nullptr, nullptr, NSEL_, D_, D_);
        splitw_kernel<0><<<dim3(32, 32), 256, 0, stream>>>(d2_wk, PWhi, PWlo, D_, D_);
        gemm_mfma<1,0><<<dim3(16, 16), 256, 0, stream>>>(PAhi, PAlo, PWhi, PWlo, BUF3, nullptr, nullptr, nullptr, NSEL_, D_, D_);
        splitw_kernel<0><<<dim3(32, 32), 256, 0, stream>>>(d2_wv, PWhi, PWlo, D_, D_);
        gemm_mfma<1,0><<<dim3(16, 16), 256, 0, stream>>>(PAhi, PAlo, PWhi, PWlo, V2, nullptr, nullptr, nullptr, NSEL_, D_, D_);
        rope_split_kernel<<<NSEL_, 256, 0, stream>>>(BUF2, QHp, QLp, T2_ - 1, SCALE_QK);
        rope_split_kernel<<<NSEL_, 256, 0, stream>>>(BUF3, KHp, KLp, T2_ - 1, 1.0f);
        vpack_kernel<<<dim3(T2_/64, B_*H_), 256, 0, stream>>>(V2, VTH, VTL, T2_);
        attn_mfma<<<dim3(T2_/64, B_*H_), 256, 0, stream>>>(QHp, QLp, KHp, KLp, VTH, VTL, BUF0, T2_);
        splita_kernel<0><<<dim3(32, 32), 256, 0, stream>>>(BUF0, PAhi, PAlo, NSEL_, D_);
        splitw_kernel<0><<<dim3(32, 32), 256, 0, stream>>>(d2_wo, PWhi, PWlo, D_, D_);
        gemm_mfma<1,1><<<dim3(16, 16), 256, 0, stream>>>(PAhi, PAlo, PWhi, PWlo, BUF2, BUF4, nullptr, nullptr, NSEL_, D_, D_); // h2
        rms_kernel<<<NSEL_, 256, 0, stream>>>(BUF2, d2_ln2, BUF0);
        splita_kernel<0><<<dim3(32, 32), 256, 0, stream>>>(BUF0, PAhi, PAlo, NSEL_, D_);
        splitw_kernel<0><<<dim3(128, 32), 256, 0, stream>>>(d2_wg, PWhi, PWlo, D_, FF_);
        gemm_mfma<1,0><<<dim3(64, 16), 256, 0, stream>>>(PAhi, PAlo, PWhi, PWlo, BUFF, nullptr, nullptr, nullptr, NSEL_, FF_, D_);
        splitw_kernel<0><<<dim3(128, 32), 256, 0, stream>>>(d2_wu, PWhi, PWlo, D_, FF_);
        gemm_mfma<1,4><<<dim3(64, 16), 256, 0, stream>>>(PAhi, PAlo, PWhi, PWlo, nullptr, BUFF, PFhi, nullptr, NSEL_, FF_, D_);  // silu(wg)*wu -> packed hi
        splitw_kernel<0><<<dim3(32, 128), 256, 0, stream>>>(d2_wd, PWhi, PWlo, FF_, D_);
        gemm_mfma<1,1><<<dim3(16, 16), 256, 0, stream>>>(PFhi, PFlo, PWhi, PWlo, BUF3, BUF2, nullptr, nullptr, NSEL_, D_, FF_); // sel_out

        scatter_kernel<<<NSEL_, 256, 0, stream>>>(BUF4, BUF3, idxb, gate, out);
        return;
    }

    if (ws_size < NEED_OLD) return;

    // ================= fallback: f32 path =================
    float* BUF0 = ws;
    float* BUF1 = ws + BIG;
    float* BUF2 = ws + 2*BIG;
    float* BUF3 = ws + 3*BIG;
    float* BUF4 = ws + 4*BIG;
    float* BUFF = ws + 5*BIG;
    float* SM   = BUFF + (size_t)NTOK_ * FF_;
    float* gbuf = SM;
    float* dch  = SM + 4096;
    float* gate = SM + 8192;
    int*   idxb = (int*)(SM + 10240);

    rms_kernel<<<NTOK_, 256, 0, stream>>>(X, d1_ln1, BUF0);
    gemm128<0><<<dim3(16, 32), 256, 0, stream>>>(BUF0, d1_wq, BUF1, nullptr, NTOK_, D_, D_);
    gemm128<0><<<dim3(16, 32), 256, 0, stream>>>(BUF0, d1_wk, BUF2, nullptr, NTOK_, D_, D_);
    gemm128<0><<<dim3(16, 32), 256, 0, stream>>>(BUF0, d1_wv, BUF3, nullptr, NTOK_, D_, D_);
    rope_kernel<<<NTOK_*4, 256, 0, stream>>>(BUF1, NTOK_, T_);
    rope_kernel<<<NTOK_*4, 256, 0, stream>>>(BUF2, NTOK_, T_);
    attn_kernel<<<dim3(T_/32, B_*H_), 256, 0, stream>>>(BUF1, BUF2, BUF3, BUF4, T_);
    gemm128<1><<<dim3(16, 32), 256, 0, stream>>>(BUF4, d1_wo, BUF2, X, NTOK_, D_, D_);
    rms_kernel<<<NTOK_, 256, 0, stream>>>(BUF2, d1_ln2, BUF0);
    gemm128<0><<<dim3(64, 32), 256, 0, stream>>>(BUF0, d1_wg, BUFF, nullptr, NTOK_, FF_, D_);
    gemm128<2><<<dim3(64, 32), 256, 0, stream>>>(BUF0, d1_wu, BUFF, BUFF, NTOK_, FF_, D_);
    gemm128<1><<<dim3(16, 32), 256, 0, stream>>>(BUFF, d1_wd, BUF1, BUF2, NTOK_, D_, FF_);

    rms_kernel<<<NTOK_, 256, 0, stream>>>(X, p_ln, BUF0);
    gemm128<0><<<dim3(8, 32), 256, 0, stream>>>(BUF0, p_wg, BUF4, nullptr, NTOK_, PFF_, D_);
    gemm128<2><<<dim3(8, 32), 256, 0, stream>>>(BUF0, p_wu, BUF4, BUF4, NTOK_, PFF_, D_);
    gemm128<0><<<dim3(16, 32), 256, 0, stream>>>(BUF4, p_wd, BUF3, nullptr, NTOK_, D_, PFF_);

    router_kernel<<<NTOK_, 256, 0, stream>>>(X, BUF1, BUF3, gbuf, dch, out + 8388609);
    loss_kernel<<<1, 1024, 0, stream>>>(dch, out + 8388608);
    topk_kernel<<<B_, 1024, 0, stream>>>(gbuf, idxb, gate);
    gather_kernel<<<NSEL_, 256, 0, stream>>>(BUF1, idxb, BUF4);

    float* V2 = BUF4 + (size_t)NSEL_ * D_;
    rms_kernel<<<NSEL_, 256, 0, stream>>>(BUF4, d2_ln1, BUF0);
    gemm128<0><<<dim3(16, 16), 256, 0, stream>>>(BUF0, d2_wq, BUF2, nullptr, NSEL_, D_, D_);
    gemm128<0><<<dim3(16, 16), 256, 0, stream>>>(BUF0, d2_wk, BUF3, nullptr, NSEL_, D_, D_);
    gemm128<0><<<dim3(16, 16), 256, 0, stream>>>(BUF0, d2_wv, V2, nullptr, NSEL_, D_, D_);
    rope_kernel<<<NSEL_*4, 256, 0, stream>>>(BUF2, NSEL_, T2_);
    rope_kernel<<<NSEL_*4, 256, 0, stream>>>(BUF3, NSEL_, T2_);
    attn_kernel<<<dim3(T2_/32, B_*H_), 256, 0, stream>>>(BUF2, BUF3, V2, BUF0, T2_);
    gemm128<1><<<dim3(16, 16), 256, 0, stream>>>(BUF0, d2_wo, BUF2, BUF4, NSEL_, D_, D_);
    rms_kernel<<<NSEL_, 256, 0, stream>>>(BUF2, d2_ln2, BUF0);
    gemm128<0><<<dim3(64, 16), 256, 0, stream>>>(BUF0, d2_wg, BUFF, nullptr, NSEL_, FF_, D_);
    gemm128<2><<<dim3(64, 16), 256, 0, stream>>>(BUF0, d2_wu, BUFF, BUFF, NSEL_, FF_, D_);
    gemm128<1><<<dim3(16, 16), 256, 0, stream>>>(BUFF, d2_wd, BUF3, BUF2, NSEL_, D_, FF_);

    copy_kernel<<<8192, 256, 0, stream>>>(BUF1, out, (int)(BIG / 4));
    scatter_kernel<<<NSEL_, 256, 0, stream>>>(BUF4, BUF3, idxb, gate, out);
}

// Round 15
// 2975.613 us; speedup vs baseline: 1.0890x; 1.0223x over previous
//
#include <hip/hip_runtime.h>
#include <math.h>

#define D_    2048
#define H_    16
#define DH_   128
#define FF_   8192
#define PFF_  1024
#define B_    2
#define T_    2048
#define NTOK_ 4096
#define T2_   1024
#define NSEL_ 2048
#define EPS_  1e-6f
#define SCALE_QK 0.08838834764831845f  // 1/sqrt(128)

typedef __attribute__((ext_vector_type(8))) short bf16x8;
typedef __attribute__((ext_vector_type(4))) float f32x4;
typedef __attribute__((ext_vector_type(8))) unsigned short ushort8;

__device__ __forceinline__ float silu_f(float x) {
    return x / (1.0f + expf(-x));
}

__device__ __forceinline__ unsigned short bf16_rne(float f) {
    unsigned int u = __float_as_uint(f);
    unsigned int r = (u + 0x7fffu + ((u >> 16) & 1u)) >> 16;
    return (unsigned short)r;
}
__device__ __forceinline__ float bf16_tof(unsigned short h) {
    return __uint_as_float(((unsigned int)h) << 16);
}

// ---------------- RMSNorm: one block per row ----------------
__global__ __launch_bounds__(256) void rms_kernel(const float* __restrict__ x,
                                                  const float* __restrict__ w,
                                                  float* __restrict__ out) {
    int row = blockIdx.x;
    int tid = threadIdx.x;
    const float4* xr = (const float4*)(x + (size_t)row * D_);
    float4* orow = (float4*)(out + (size_t)row * D_);
    const float4* w4 = (const float4*)w;
    float4 v0 = xr[tid], v1 = xr[tid + 256];
    float s = v0.x*v0.x + v0.y*v0.y + v0.z*v0.z + v0.w*v0.w
            + v1.x*v1.x + v1.y*v1.y + v1.z*v1.z + v1.w*v1.w;
    __shared__ float red[256];
    red[tid] = s; __syncthreads();
    for (int off = 128; off > 0; off >>= 1) {
        if (tid < off) red[tid] += red[tid + off];
        __syncthreads();
    }
    float r = 1.0f / sqrtf(red[0] * (1.0f/2048.0f) + EPS_);
    float4 w0 = w4[tid], w1 = w4[tid + 256];
    float4 o0, o1;
    o0.x = v0.x*r*w0.x; o0.y = v0.y*r*w0.y; o0.z = v0.z*r*w0.z; o0.w = v0.w*r*w0.w;
    o1.x = v1.x*r*w1.x; o1.y = v1.y*r*w1.y; o1.z = v1.z*r*w1.z; o1.w = v1.w*r*w1.w;
    orow[tid] = o0; orow[tid + 256] = o1;
}

// ---------------- weight transpose+split: W[K][Wld] f32 -> Phi(/Plo)[k/8][PN][8] @ colOff ----------------
template<int WLO>
__global__ __launch_bounds__(256) void splitw_kernel(const float* __restrict__ W,
                                                     unsigned short* __restrict__ phi,
                                                     unsigned short* __restrict__ plo,
                                                     int K, int Wld, int PN, int colOff) {
    __shared__ float Ts[64][68];
    int n0 = blockIdx.x << 6, k0 = blockIdx.y << 6;
    int tid = threadIdx.x;
#pragma unroll
    for (int it = 0; it < 4; ++it) {
        int idx = tid + (it << 8);
        int kr = idx >> 4, c4 = idx & 15;
        float4 v = *(const float4*)(W + (size_t)(k0 + kr) * Wld + n0 + (c4 << 2));
        Ts[kr][c4*4+0] = v.x; Ts[kr][c4*4+1] = v.y; Ts[kr][c4*4+2] = v.z; Ts[kr][c4*4+3] = v.w;
    }
    __syncthreads();
#pragma unroll
    for (int h = 0; h < 2; ++h) {
        int c = tid + (h << 8);              // [0,512)
        int kc = c >> 6, n = c & 63;
        ushort8 hi, lo;
#pragma unroll
        for (int q = 0; q < 8; ++q) {
            float v = Ts[kc*8 + q][n];
            unsigned short hb = bf16_rne(v);
            hi[q] = hb;
            if (WLO) lo[q] = bf16_rne(v - bf16_tof(hb));
        }
        size_t off = ((size_t)((k0 >> 3) + kc) * PN + (colOff + n0 + n)) * 8;
        *(ushort8*)(phi + off) = hi;
        if (WLO) *(ushort8*)(plo + off) = lo;
    }
}

// ---------------- activation split: A[M][K] f32 -> Phi(/Plo)[k/8][m][8] bf16 ----------------
template<int WLO>
__global__ __launch_bounds__(256) void splita_kernel(const float* __restrict__ A,
                                                     unsigned short* __restrict__ phi,
                                                     unsigned short* __restrict__ plo,
                                                     int M, int K) {
    __shared__ float Ts[64][68];
    int m0 = blockIdx.x << 6, k0 = blockIdx.y << 6;
    int tid = threadIdx.x;
#pragma unroll
    for (int it = 0; it < 4; ++it) {
        int idx = tid + (it << 8);
        int mr = idx >> 4, c4 = idx & 15;
        float4 v = *(const float4*)(A + (size_t)(m0 + mr) * K + k0 + (c4 << 2));
        Ts[mr][c4*4+0] = v.x; Ts[mr][c4*4+1] = v.y; Ts[mr][c4*4+2] = v.z; Ts[mr][c4*4+3] = v.w;
    }
    __syncthreads();
#pragma unroll
    for (int h = 0; h < 2; ++h) {
        int c = tid + (h << 8);
        int kc = c >> 6, m = c & 63;
        const float* src = &Ts[m][kc << 3];
        ushort8 hi, lo;
#pragma unroll
        for (int q = 0; q < 8; ++q) {
            float v = src[q];
            unsigned short hb = bf16_rne(v);
            hi[q] = hb;
            if (WLO) lo[q] = bf16_rne(v - bf16_tof(hb));
        }
        size_t off = ((size_t)((k0 >> 3) + kc) * M + (m0 + m)) * 8;
        *(ushort8*)(phi + off) = hi;
        if (WLO) *(ushort8*)(plo + off) = lo;
    }
}

// ---------------- bf16(x3) MFMA GEMM, 128x128 tile, BK=32, 2-phase dbuf, 16x16x32 MFMA ----------------
// Block map: XCD-chunked + paired-column decode (2 B-panels L2-resident, A shared by pair).
// EPI 0: C=acc ; 1: C=acc+Rg ; 2: C=silu(Rg)*acc ;
// EPI 3: packed hi/lo panels = silu(Rg)*acc ; EPI 4: packed hi panel only ;
// EPI 5: segmented QKV output — col segment s=col>>11 routes to {C, Rg, Cph} as f32 [M][2048].
__device__ __forceinline__ void stage_panel(unsigned short* lds,
                                            const unsigned short* __restrict__ panel,
                                            int ktile, int R, int brow, int tid) {
#pragma unroll
    for (int h = 0; h < 2; ++h) {
        int c = tid + (h << 8);              // [0,512): kc = c>>7, row = c&127
        const unsigned short* g = panel + ((size_t)((ktile << 2) + (c >> 7)) * R + (brow + (c & 127))) * 8;
        __builtin_amdgcn_global_load_lds((const __attribute__((address_space(1))) void*)g,
                                         (__attribute__((address_space(3))) void*)(lds + (size_t)c * 8),
                                         16, 0, 0);
    }
}

template<int NP, int EPI>
__global__ __launch_bounds__(256) void gemm_mfma(const unsigned short* __restrict__ pah,
                                                 const unsigned short* __restrict__ pal,
                                                 const unsigned short* __restrict__ pbh,
                                                 const unsigned short* __restrict__ pbl,
                                                 float* __restrict__ C,
                                                 const float* __restrict__ Rg,
                                                 unsigned short* __restrict__ Cph,
                                                 unsigned short* __restrict__ Cpl,
                                                 int M, int N, int K) {
    constexpr int NPAN = (NP == 3) ? 2 : 1;
    __shared__ __align__(16) unsigned short As[2][NPAN][4][128][8];
    __shared__ __align__(16) unsigned short Bs[2][NPAN][4][128][8];
    const int tid = threadIdx.x;
    // T1: XCD-aware bijective block swizzle (all grids here have nwg % 8 == 0)
    int nwg = gridDim.x * gridDim.y;
    int wg = blockIdx.y * gridDim.x + blockIdx.x;
    if ((nwg & 7) == 0) {
        int cpx = nwg >> 3;
        wg = (wg & 7) * cpx + (wg >> 3);
    }
    // paired-column decode: consecutive wg alternate between 2 adjacent bn-columns
    // at the same bm-row, so each streamed A panel serves both columns while the
    // two B panels stay L2-resident. Bijective for even gridDim.x.
    const int gy2 = gridDim.y << 1;
    const int sc = wg / gy2;
    const int wr = wg - sc * gy2;
    const int bxs = (sc << 1) + (wr & 1), bys = wr >> 1;
    const int bm = bys << 7, bn = bxs << 7;
    const int lane = tid & 63, wave = tid >> 6;
    const int wm = (wave >> 1) << 6, wn = (wave & 1) << 6;
    const int fr = lane & 15, fk = lane >> 4;

    // EPI5: per-block segment routing (bn covers 128 cols, segment = bn>>11 uniform)
    float* Cseg = C;
    if (EPI == 5) {
        int seg = bn >> 11;
        Cseg = (seg == 0) ? C : ((seg == 1) ? (float*)Rg : (float*)Cph);
    }

    f32x4 acc[4][4];
#pragma unroll
    for (int i = 0; i < 4; ++i)
#pragma unroll
        for (int j = 0; j < 4; ++j) acc[i][j] = (f32x4)0.0f;

    const int nkt = K >> 5;

    // prologue stage tile 0 into buf 0
    stage_panel(&As[0][0][0][0][0], pah, 0, M, bm, tid);
    if (NP == 3) stage_panel(&As[0][1][0][0][0], pal, 0, M, bm, tid);
    stage_panel(&Bs[0][0][0][0][0], pbh, 0, N, bn, tid);
    if (NP == 3) stage_panel(&Bs[0][1][0][0][0], pbl, 0, N, bn, tid);
    __syncthreads();

    int cur = 0;
    for (int kt = 0; kt < nkt; ++kt) {
        // T3 minimum 2-phase: issue next-tile stage BEFORE ds_read+MFMA
        if (kt + 1 < nkt) {
            int nxt = cur ^ 1;
            stage_panel(&As[nxt][0][0][0][0], pah, kt + 1, M, bm, tid);
            if (NP == 3) stage_panel(&As[nxt][1][0][0][0], pal, kt + 1, M, bm, tid);
            stage_panel(&Bs[nxt][0][0][0][0], pbh, kt + 1, N, bn, tid);
            if (NP == 3) stage_panel(&Bs[nxt][1][0][0][0], pbl, kt + 1, N, bn, tid);
        }

        bf16x8 ah[4], bh[4], al[4], bl[4];
#pragma unroll
        for (int i = 0; i < 4; ++i) {
            ah[i] = *(const bf16x8*)&As[cur][0][fk][wm + (i << 4) + fr][0];
            if (NP == 3) al[i] = *(const bf16x8*)&As[cur][NPAN-1][fk][wm + (i << 4) + fr][0];
        }
#pragma unroll
        for (int j = 0; j < 4; ++j) {
            bh[j] = *(const bf16x8*)&Bs[cur][0][fk][wn + (j << 4) + fr][0];
            if (NP == 3) bl[j] = *(const bf16x8*)&Bs[cur][NPAN-1][fk][wn + (j << 4) + fr][0];
        }
#pragma unroll
        for (int i = 0; i < 4; ++i)
#pragma unroll
            for (int j = 0; j < 4; ++j) {
                acc[i][j] = __builtin_amdgcn_mfma_f32_16x16x32_bf16(ah[i], bh[j], acc[i][j], 0, 0, 0);
                if (NP == 3) {
                    acc[i][j] = __builtin_amdgcn_mfma_f32_16x16x32_bf16(ah[i], bl[j], acc[i][j], 0, 0, 0);
                    acc[i][j] = __builtin_amdgcn_mfma_f32_16x16x32_bf16(al[i], bh[j], acc[i][j], 0, 0, 0);
                }
            }
        __syncthreads();   // next-tile stage complete; buf[cur] reads all drained
        cur ^= 1;
    }

#pragma unroll
    for (int i = 0; i < 4; ++i) {
        int row0 = bm + wm + (i << 4) + (fk << 2);
#pragma unroll
        for (int j = 0; j < 4; ++j) {
            int col = bn + wn + (j << 4) + fr;
#pragma unroll
            for (int r = 0; r < 4; ++r) {
                int row = row0 + r;
                size_t off = (size_t)row * N + col;
                float v = acc[i][j][r];
                if (EPI == 0) {
                    C[off] = v;
                } else if (EPI == 1) {
                    C[off] = v + Rg[off];
                } else if (EPI == 2) {
                    C[off] = silu_f(Rg[off]) * v;
                } else if (EPI == 5) {
                    Cseg[(size_t)row * 2048 + (col & 2047)] = v;
                } else {
                    v = silu_f(Rg[off]) * v;
                    unsigned short hb = bf16_rne(v);
                    size_t poff = (((size_t)(col >> 3)) * M + row) * 8 + (col & 7);
                    Cph[poff] = hb;
                    if (EPI == 3) Cpl[poff] = bf16_rne(v - bf16_tof(hb));
                }
            }
        }
    }
}

// ---------------- fused RoPE + scale + hi/lo split ----------------
__global__ __launch_bounds__(256) void rope_split_kernel(const float* __restrict__ X,
                                                         unsigned short* __restrict__ xh,
                                                         unsigned short* __restrict__ xl,
                                                         int seqmask, float scale) {
    int tok = blockIdx.x;
    int tid = threadIdx.x;
    int h = tid >> 4, d0 = (tid & 15) << 3;
    int pos = tok & seqmask;
    const float* src = X + (size_t)tok * D_ + h * DH_;
    bool lohalf = d0 < 64;
    float out[8];
#pragma unroll
    for (int q = 0; q < 8; ++q) {
        int d = d0 + q;
        int i = lohalf ? d : (d - 64);
        float e = (float)(2 * i) * (1.0f / 128.0f);
        float inv = 1.0f / powf(10000.0f, e);
        float ang = (float)pos * inv;
        float c = cosf(ang), s = sinf(ang);
        float x1 = src[i], x2 = src[i + 64];
        out[q] = lohalf ? (x1 * c - x2 * s) : (x2 * c + x1 * s);
    }
    ushort8 hi, lo;
#pragma unroll
    for (int q = 0; q < 8; ++q) {
        float v = out[q] * scale;
        unsigned short hb = bf16_rne(v);
        hi[q] = hb;
        lo[q] = bf16_rne(v - bf16_tof(hb));
    }
    size_t off = (size_t)tok * D_ + h * DH_ + d0;
    *(ushort8*)(xh + off) = hi;
    *(ushort8*)(xl + off) = lo;
}

// ---------------- V pack: f32 [b*T+t][2048] -> Vt[bh][T/8][128][8] bf16 hi/lo ----------------
__global__ __launch_bounds__(256) void vpack_kernel(const float* __restrict__ V,
                                                    unsigned short* __restrict__ vth,
                                                    unsigned short* __restrict__ vtl,
                                                    int T) {
    __shared__ float Ts[64][132];
    int kt = blockIdx.x, bh = blockIdx.y;
    int b = bh >> 4, h = bh & 15;
    int tid = threadIdx.x;
#pragma unroll
    for (int it = 0; it < 8; ++it) {
        int idx = tid + (it << 8);          // [0,2048)
        int r = idx >> 5, c4 = idx & 31;    // r in [0,64), c4 in [0,32)
        float4 v = *(const float4*)(V + ((size_t)(b * T + kt * 64 + r)) * D_ + h * DH_ + (c4 << 2));
        Ts[r][c4*4+0] = v.x; Ts[r][c4*4+1] = v.y; Ts[r][c4*4+2] = v.z; Ts[r][c4*4+3] = v.w;
    }
    __syncthreads();
    size_t obase = ((size_t)bh * (size_t)(T >> 3) + (size_t)kt * 8) * 1024;
#pragma unroll
    for (int it = 0; it < 4; ++it) {
        int c = tid + (it << 8);            // [0,1024): kc = c>>7, dh = c&127
        int kc = c >> 7, dh = c & 127;
        ushort8 hi, lo;
#pragma unroll
        for (int q = 0; q < 8; ++q) {
            float v = Ts[kc * 8 + q][dh];
            unsigned short hb = bf16_rne(v);
            hi[q] = hb;
            lo[q] = bf16_rne(v - bf16_tof(hb));
        }
        *(ushort8*)(vth + obase + (size_t)kc * 1024 + dh * 8) = hi;
        *(ushort8*)(vtl + obase + (size_t)kc * 1024 + dh * 8) = lo;
    }
}

// ---------------- bf16x3 MFMA flash attention ----------------
// grid: (T/64, B_*H_), block 256 (4 waves, each owns 16 q-rows)
__global__ __launch_bounds__(256) void attn_mfma(const unsigned short* __restrict__ QH,
                                                 const unsigned short* __restrict__ QL,
                                                 const unsigned short* __restrict__ KH,
                                                 const unsigned short* __restrict__ KL,
                                                 const unsigned short* __restrict__ VTH,
                                                 const unsigned short* __restrict__ VTL,
                                                 float* __restrict__ O, int T) {
    __shared__ __align__(16) unsigned short KV[16384];
    __shared__ __align__(16) float Ss[4096];
    __shared__ __align__(16) float mrow[64];
    __shared__ __align__(16) float lrow[64];
    __shared__ __align__(16) float crow[64];

    const int tid = threadIdx.x;
    const int qt = blockIdx.x, bh = blockIdx.y;
    const int b = bh >> 4, h = bh & 15;
    const int lane = tid & 63, w = tid >> 6;
    const int fr = lane & 15, fk = lane >> 4;
    const size_t tok0 = (size_t)b * T;

    char* lds_kv = (char*)&KV[0];
    char* lds_sp = (char*)&Ss[0];

    bf16x8 qfh[4], qfl[4];
    {
        const size_t qoff = (tok0 + (size_t)qt * 64 + w * 16 + fr) * D_ + h * DH_ + fk * 8;
#pragma unroll
        for (int ks = 0; ks < 4; ++ks) {
            qfh[ks] = *(const bf16x8*)(QH + qoff + ks * 32);
            qfl[ks] = *(const bf16x8*)(QL + qoff + ks * 32);
        }
    }
    if (tid < 64) { mrow[tid] = -1e30f; lrow[tid] = 0.f; }

    f32x4 acc[8];
#pragma unroll
    for (int nt = 0; nt < 8; ++nt) acc[nt] = (f32x4)0.f;

    const int srow = tid >> 2, sslot = tid & 3;
    const size_t vbase = (size_t)bh * (size_t)(T >> 3) * 1024;

    for (int kt = 0; kt <= qt; ++kt) {
        __syncthreads();
#pragma unroll
        for (int it = 0; it < 4; ++it) {
            int c = tid + (it << 8);
            int t = c >> 4;
            int sp = (c & 15) ^ (t & 7);
            size_t goff = (tok0 + (size_t)kt * 64 + t) * D_ + h * DH_ + sp * 8;
            __builtin_amdgcn_global_load_lds((const __attribute__((address_space(1))) void*)(KH + goff),
                (__attribute__((address_space(3))) void*)(lds_kv + c * 16), 16, 0, 0);
            __builtin_amdgcn_global_load_lds((const __attribute__((address_space(1))) void*)(KL + goff),
                (__attribute__((address_space(3))) void*)(lds_kv + 16384 + c * 16), 16, 0, 0);
        }
        __syncthreads();
        {
            f32x4 s[4];
#pragma unroll
            for (int nt = 0; nt < 4; ++nt) s[nt] = (f32x4)0.f;
#pragma unroll
            for (int ks = 0; ks < 4; ++ks) {
#pragma unroll
                for (int nt = 0; nt < 4; ++nt) {
                    int n = nt * 16 + fr;
                    int offk = (n * 256 + ks * 64 + fk * 16) ^ ((n & 7) << 4);
                    bf16x8 kfh = *(const bf16x8*)(lds_kv + offk);
                    bf16x8 kfl = *(const bf16x8*)(lds_kv + 16384 + offk);
                    s[nt] = __builtin_amdgcn_mfma_f32_16x16x32_bf16(qfh[ks], kfh, s[nt], 0, 0, 0);
                    s[nt] = __builtin_amdgcn_mfma_f32_16x16x32_bf16(qfh[ks], kfl, s[nt], 0, 0, 0);
                    s[nt] = __builtin_amdgcn_mfma_f32_16x16x32_bf16(qfl[ks], kfh, s[nt], 0, 0, 0);
                }
            }
#pragma unroll
            for (int nt = 0; nt < 4; ++nt)
#pragma unroll
                for (int r = 0; r < 4; ++r) {
                    int row = w * 16 + fk * 4 + r;
                    int col = nt * 16 + fr;
                    *(float*)(lds_sp + ((row * 256 + col * 4) ^ ((row & 7) << 4))) = s[nt][r];
                }
        }
        __syncthreads();
#pragma unroll
        for (int it = 0; it < 4; ++it) {
            int c = tid + (it << 8);
            size_t goff = vbase + (size_t)kt * 8192 + (size_t)c * 8;
            __builtin_amdgcn_global_load_lds((const __attribute__((address_space(1))) void*)(VTH + goff),
                (__attribute__((address_space(3))) void*)(lds_kv + c * 16), 16, 0, 0);
            __builtin_amdgcn_global_load_lds((const __attribute__((address_space(1))) void*)(VTL + goff),
                (__attribute__((address_space(3))) void*)(lds_kv + 16384 + c * 16), 16, 0, 0);
        }
        float p[16];
        float newm, psum, cr, oldl;
        {
            float tmax = -1e30f;
            int colbase = sslot * 16;
#pragma unroll
            for (int q4 = 0; q4 < 4; ++q4) {
                f32x4 sv = *(const f32x4*)(lds_sp + ((srow * 256 + sslot * 64 + q4 * 16) ^ ((srow & 7) << 4)));
#pragma unroll
                for (int e = 0; e < 4; ++e) {
                    float v = sv[e];
                    if (kt == qt && (colbase + q4 * 4 + e) > srow) v = -1e30f;
                    p[q4 * 4 + e] = v;
                    tmax = fmaxf(tmax, v);
                }
            }
            tmax = fmaxf(tmax, __shfl_xor(tmax, 1, 64));
            tmax = fmaxf(tmax, __shfl_xor(tmax, 2, 64));
            float oldm = mrow[srow];
            oldl = lrow[srow];
            newm = fmaxf(oldm, tmax);
            psum = 0.f;
#pragma unroll
            for (int e = 0; e < 16; ++e) { p[e] = expf(p[e] - newm); psum += p[e]; }
            psum += __shfl_xor(psum, 1, 64);
            psum += __shfl_xor(psum, 2, 64);
            cr = expf(oldm - newm);
        }
        __syncthreads();
        {
            ushort8 h0, h1, l0, l1;
#pragma unroll
            for (int e = 0; e < 8; ++e) {
                unsigned short hb = bf16_rne(p[e]);
                h0[e] = hb; l0[e] = bf16_rne(p[e] - bf16_tof(hb));
                unsigned short hb2 = bf16_rne(p[8 + e]);
                h1[e] = hb2; l1[e] = bf16_rne(p[8 + e] - bf16_tof(hb2));
            }
            int base = srow * 128 + sslot * 32;
            int swz = (srow & 7) << 4;
            *(ushort8*)(lds_sp + (base ^ swz)) = h0;
            *(ushort8*)(lds_sp + ((base + 16) ^ swz)) = h1;
            *(ushort8*)(lds_sp + 8192 + (base ^ swz)) = l0;
            *(ushort8*)(lds_sp + 8192 + ((base + 16) ^ swz)) = l1;
            if (sslot == 0) { mrow[srow] = newm; lrow[srow] = oldl * cr + psum; crow[srow] = cr; }
        }
        __syncthreads();
        {
            f32x4 crv = *(const f32x4*)&crow[w * 16 + fk * 4];
#pragma unroll
            for (int nt = 0; nt < 8; ++nt)
#pragma unroll
                for (int r = 0; r < 4; ++r) acc[nt][r] *= crv[r];
            int m = w * 16 + fr;
#pragma unroll
            for (int ks = 0; ks < 2; ++ks) {
                int offp = (m * 128 + ks * 64 + fk * 16) ^ ((m & 7) << 4);
                bf16x8 pfh = *(const bf16x8*)(lds_sp + offp);
                bf16x8 pfl = *(const bf16x8*)(lds_sp + 8192 + offp);
#pragma unroll
                for (int nt = 0; nt < 8; ++nt) {
                    int offv = (ks * 4 + fk) * 2048 + (nt * 16 + fr) * 16;
                    bf16x8 vfh = *(const bf16x8*)(lds_kv + offv);
                    bf16x8 vfl = *(const bf16x8*)(lds_kv + 16384 + offv);
                    acc[nt] = __builtin_amdgcn_mfma_f32_16x16x32_bf16(pfh, vfh, acc[nt], 0, 0, 0);
                    acc[nt] = __builtin_amdgcn_mfma_f32_16x16x32_bf16(pfh, vfl, acc[nt], 0, 0, 0);
                    acc[nt] = __builtin_amdgcn_mfma_f32_16x16x32_bf16(pfl, vfh, acc[nt], 0, 0, 0);
                }
            }
        }
    }
    __syncthreads();
    {
        f32x4 lv = *(const f32x4*)&lrow[w * 16 + fk * 4];
        float* orow = O + (tok0 + (size_t)qt * 64 + w * 16 + fk * 4) * D_ + h * DH_;
#pragma unroll
        for (int r = 0; r < 4; ++r) {
            float inv = 1.0f / lv[r];
#pragma unroll
            for (int nt = 0; nt < 8; ++nt)
                orow[(size_t)r * D_ + nt * 16 + fr] = acc[nt][r] * inv;
        }
    }
}

// ---------------- f32 GEMM (fallback path) ----------------
template<int EPI>
__global__ __launch_bounds__(256) void gemm128(const float* __restrict__ A,
                                               const float* __restrict__ Bm,
                                               float* __restrict__ C,
                                               const float* __restrict__ Rg,
                                               int M, int N, int K) {
    __shared__ float Ast[16][132];
    __shared__ float Bs[16][132];
    int bm = blockIdx.y << 7, bn = blockIdx.x << 7;
    int tid = threadIdx.x;
    int ty = tid >> 4, tx = tid & 15;
    float acc[8][8];
#pragma unroll
    for (int i = 0; i < 8; ++i)
#pragma unroll
        for (int j = 0; j < 8; ++j) acc[i][j] = 0.f;

    for (int k0 = 0; k0 < K; k0 += 16) {
#pragma unroll
        for (int it = 0; it < 2; ++it) {
            int idx = tid + (it << 8);
            int ar = idx >> 2, ac = idx & 3;
            float4 av = *(const float4*)(A + (size_t)(bm + ar) * K + k0 + (ac << 2));
            Ast[ac*4+0][ar] = av.x; Ast[ac*4+1][ar] = av.y;
            Ast[ac*4+2][ar] = av.z; Ast[ac*4+3][ar] = av.w;
            int br = idx >> 5, bc = idx & 31;
            float4 bv = *(const float4*)(Bm + (size_t)(k0 + br) * N + bn + (bc << 2));
            *(float4*)&Bs[br][bc << 2] = bv;
        }
        __syncthreads();
#pragma unroll
        for (int kk = 0; kk < 16; ++kk) {
            float a[8], b[8];
            *(float4*)&a[0] = *(const float4*)&Ast[kk][ty*4];
            *(float4*)&a[4] = *(const float4*)&Ast[kk][64 + ty*4];
            *(float4*)&b[0] = *(const float4*)&Bs[kk][tx*4];
            *(float4*)&b[4] = *(const float4*)&Bs[kk][64 + tx*4];
#pragma unroll
            for (int i = 0; i < 8; ++i)
#pragma unroll
                for (int j = 0; j < 8; ++j)
                    acc[i][j] += a[i] * b[j];
        }
        __syncthreads();
    }
#pragma unroll
    for (int i = 0; i < 8; ++i) {
        int row = bm + ((i < 4) ? (ty*4 + i) : (64 + ty*4 + (i - 4)));
#pragma unroll
        for (int half = 0; half < 2; ++half) {
            int col = bn + half*64 + tx*4;
            size_t off = (size_t)row * N + col;
            const float* ap = &acc[i][half*4];
            float4 r;
            if (EPI == 0) {
                r.x = ap[0]; r.y = ap[1]; r.z = ap[2]; r.w = ap[3];
            } else if (EPI == 1) {
                float4 rv = *(const float4*)(Rg + off);
                r.x = ap[0] + rv.x; r.y = ap[1] + rv.y;
                r.z = ap[2] + rv.z; r.w = ap[3] + rv.w;
            } else {
                float4 gv = *(const float4*)(Rg + off);
                r.x = silu_f(gv.x) * ap[0]; r.y = silu_f(gv.y) * ap[1];
                r.z = silu_f(gv.z) * ap[2]; r.w = silu_f(gv.w) * ap[3];
            }
            *(float4*)(C + off) = r;
        }
    }
}

// ---------------- RoPE in place (f32, fallback) ----------------
__global__ __launch_bounds__(256) void rope_kernel(float* __restrict__ q, int nrows, int seqlen) {
    int gid = blockIdx.x * 256 + threadIdx.x;
    int tok = gid >> 10;
    if (tok >= nrows) return;
    int rest = gid & 1023;
    int h = rest >> 6, i = rest & 63;
    int pos = tok % seqlen;
    float e = (float)(2 * i) * (1.0f / 128.0f);
    float inv = 1.0f / powf(10000.0f, e);
    float ang = (float)pos * inv;
    float c = cosf(ang), s = sinf(ang);
    size_t base = (size_t)tok * D_ + h * 128 + i;
    float x1 = q[base], x2 = q[base + 64];
    q[base]      = x1 * c - x2 * s;
    q[base + 64] = x2 * c + x1 * s;
}

// ---------------- flash attention f32 (fallback) ----------------
__global__ __launch_bounds__(256) void attn_kernel(const float* __restrict__ Q,
                                                   const float* __restrict__ K,
                                                   const float* __restrict__ V,
                                                   float* __restrict__ O,
                                                   int T) {
    int qt = blockIdx.x;
    int bh = blockIdx.y;
    int b = bh >> 4, h = bh & 15;
    int tid = threadIdx.x;

    __shared__ float4 Qs[32][32];
    __shared__ float4 KVs[64][32];
    __shared__ float Sst[32][65];
    __shared__ float mrow[32], lrow[32], crow[32];

    const size_t headoff = (size_t)h * DH_;
    const size_t bbase = (size_t)b * T * D_;

#pragma unroll
    for (int i = 0; i < 4; ++i) {
        int idx = tid + i * 256;
        int r = idx >> 5, ch = idx & 31;
        const float4* src = (const float4*)(Q + bbase + (size_t)(qt*32 + r) * D_ + headoff);
        Qs[r][ch ^ ((r >> 2) & 7)] = src[ch];
    }
    if (tid < 32) { mrow[tid] = -1e30f; lrow[tid] = 0.f; }

    int ty16 = tid >> 4, tx16 = tid & 15;
    int r8 = tid >> 3, q8 = tid & 7;
    float o[2][8];
#pragma unroll
    for (int i = 0; i < 2; ++i)
#pragma unroll
        for (int j = 0; j < 8; ++j) o[i][j] = 0.f;

    int ktmax = (qt * 32 + 31) >> 6;
    for (int kt = 0; kt <= ktmax; ++kt) {
        __syncthreads();
#pragma unroll
        for (int i = 0; i < 8; ++i) {
            int idx = tid + i * 256;
            int r = idx >> 5, ch = idx & 31;
            const float4* src = (const float4*)(K + bbase + (size_t)(kt*64 + r) * D_ + headoff);
            KVs[r][ch ^ ((r >> 2) & 7)] = src[ch];
        }
        __syncthreads();
        {
            float s[2][4];
#pragma unroll
            for (int i = 0; i < 2; ++i)
#pragma unroll
                for (int j = 0; j < 4; ++j) s[i][j] = 0.f;
#pragma unroll
            for (int ch = 0; ch < 32; ++ch) {
                float4 qv[2], kv[4];
#pragma unroll
                for (int i = 0; i < 2; ++i) { int r = ty16*2 + i; qv[i] = Qs[r][ch ^ ((r >> 2) & 7)]; }
#pragma unroll
                for (int j = 0; j < 4; ++j) { int c = tx16*4 + j; kv[j] = KVs[c][ch ^ ((c >> 2) & 7)]; }
#pragma unroll
                for (int i = 0; i < 2; ++i)
#pragma unroll
                    for (int j = 0; j < 4; ++j)
                        s[i][j] += qv[i].x*kv[j].x + qv[i].y*kv[j].y + qv[i].z*kv[j].z + qv[i].w*kv[j].w;
            }
#pragma unroll
            for (int i = 0; i < 2; ++i) {
                int grow = qt*32 + ty16*2 + i;
#pragma unroll
                for (int j = 0; j < 4; ++j) {
                    int gcol = kt*64 + tx16*4 + j;
                    float sv = s[i][j] * SCALE_QK;
                    if (gcol > grow) sv = -1e30f;
                    Sst[ty16*2 + i][tx16*4 + j] = sv;
                }
            }
        }
        __syncthreads();
#pragma unroll
        for (int i = 0; i < 8; ++i) {
            int idx = tid + i * 256;
            int r = idx >> 5, ch = idx & 31;
            const float4* src = (const float4*)(V + bbase + (size_t)(kt*64 + r) * D_ + headoff);
            KVs[r][ch ^ ((r >> 2) & 7)] = src[ch];
        }
        {
            float pv[8];
            float tmax = -1e30f;
#pragma unroll
            for (int c = 0; c < 8; ++c) { pv[c] = Sst[r8][q8*8 + c]; tmax = fmaxf(tmax, pv[c]); }
#pragma unroll
            for (int m = 1; m < 8; m <<= 1) tmax = fmaxf(tmax, __shfl_xor(tmax, m, 64));
            float oldm = mrow[r8];
            float newm = fmaxf(oldm, tmax);
            float psum = 0.f;
#pragma unroll
            for (int c = 0; c < 8; ++c) {
                float p = expf(pv[c] - newm);
                Sst[r8][q8*8 + c] = p;
                psum += p;
            }
#pragma unroll
            for (int m = 1; m < 8; m <<= 1) psum += __shfl_xor(psum, m, 64);
            if (q8 == 0) {
                float crv = expf(oldm - newm);
                crow[r8] = crv;
                lrow[r8] = lrow[r8] * crv + psum;
                mrow[r8] = newm;
            }
        }
        __syncthreads();
        {
            float crv[2];
#pragma unroll
            for (int i = 0; i < 2; ++i) {
                crv[i] = crow[ty16*2 + i];
#pragma unroll
                for (int j = 0; j < 8; ++j) o[i][j] *= crv[i];
            }
#pragma unroll
            for (int kc = 0; kc < 64; ++kc) {
                int swz = (kc >> 2) & 7;
                float4 v0 = KVs[kc][tx16 ^ swz];
                float4 v1 = KVs[kc][(16 + tx16) ^ swz];
#pragma unroll
                for (int i = 0; i < 2; ++i) {
                    float p = Sst[ty16*2 + i][kc];
                    o[i][0] += p*v0.x; o[i][1] += p*v0.y; o[i][2] += p*v0.z; o[i][3] += p*v0.w;
                    o[i][4] += p*v1.x; o[i][5] += p*v1.y; o[i][6] += p*v1.z; o[i][7] += p*v1.w;
                }
            }
        }
    }
#pragma unroll
    for (int i = 0; i < 2; ++i) {
        int r = ty16*2 + i;
        float inv = 1.0f / lrow[r];
        float4 a, bb;
        a.x = o[i][0]*inv; a.y = o[i][1]*inv; a.z = o[i][2]*inv; a.w = o[i][3]*inv;
        bb.x = o[i][4]*inv; bb.y = o[i][5]*inv; bb.z = o[i][6]*inv; bb.w = o[i][7]*inv;
        float* dst = O + bbase + (size_t)(qt*32 + r) * D_ + headoff;
        ((float4*)dst)[tx16] = a;
        ((float4*)dst)[16 + tx16] = bb;
    }
}

// ---------------- router / loss / topk / gather / copy / scatter ----------------
__global__ __launch_bounds__(256) void router_kernel(const float* __restrict__ x,
                                                     const float* __restrict__ proc,
                                                     const float* __restrict__ prior,
                                                     float* __restrict__ gbuf,
                                                     float* __restrict__ dchbuf,
                                                     float* __restrict__ gout) {
    int row = blockIdx.x, tid = threadIdx.x;
    const float4* x4 = (const float4*)(x + (size_t)row * D_);
    const float4* p4 = (const float4*)(proc + (size_t)row * D_);
    const float4* r4 = (const float4*)(prior + (size_t)row * D_);
    float sst = 0.f, sch = 0.f;
#pragma unroll
    for (int it = 0; it < 2; ++it) {
        int i = tid + it * 256;
        float4 xv = x4[i], pv = p4[i], rv = r4[i];
        float a0 = pv.x - xv.x, a1 = pv.y - xv.y, a2 = pv.z - xv.z, a3 = pv.w - xv.w;
        sst += a0*a0 + a1*a1 + a2*a2 + a3*a3;
        float d0 = a0 - rv.x, d1 = a1 - rv.y, d2 = a2 - rv.z, d3 = a3 - rv.w;
        sch += d0*d0 + d1*d1 + d2*d2 + d3*d3;
    }
    __shared__ float rs[256], rc[256];
    rs[tid] = sst; rc[tid] = sch; __syncthreads();
    for (int off = 128; off > 0; off >>= 1) {
        if (tid < off) { rs[tid] += rs[tid + off]; rc[tid] += rc[tid + off]; }
        __syncthreads();
    }
    if (tid == 0) {
        float Dst = rs[0] * (1.0f/2048.0f);
        float Dch = rc[0] * (1.0f/2048.0f);
        float g = 1.0f / (1.0f + expf(-(Dch - Dst)));
        gbuf[row] = g; dchbuf[row] = Dch; gout[row] = g;
    }
}

__global__ __launch_bounds__(1024) void loss_kernel(const float* __restrict__ dch, float* __restrict__ out) {
    __shared__ float red[1024];
    int tid = threadIdx.x;
    red[tid] = dch[tid] + dch[tid + 1024] + dch[tid + 2048] + dch[tid + 3072];
    __syncthreads();
    for (int off = 512; off > 0; off >>= 1) {
        if (tid < off) red[tid] += red[tid + off];
        __syncthreads();
    }
    if (tid == 0) out[0] = red[0] * (1.0f / 4096.0f);
}

__global__ __launch_bounds__(1024) void topk_kernel(const float* __restrict__ gbuf,
                                                    int* __restrict__ idxout,
                                                    float* __restrict__ gateout) {
    int b = blockIdx.x, tid = threadIdx.x;
    __shared__ float val[2048];
    __shared__ int idx[2048];
    val[tid] = gbuf[b*2048 + tid];           idx[tid] = tid;
    val[tid + 1024] = gbuf[b*2048 + tid + 1024]; idx[tid + 1024] = tid + 1024;
    __syncthreads();
    for (int kk = 2; kk <= 2048; kk <<= 1) {
        for (int j = kk >> 1; j > 0; j >>= 1) {
            for (int i = tid; i < 2048; i += 1024) {
                int ixj = i ^ j;
                if (ixj > i) {
                    bool up = ((i & kk) == 0);
                    float v1 = val[i], v2 = val[ixj];
                    int i1 = idx[i], i2 = idx[ixj];
                    bool sw = up ? ((v2 > v1) || (v2 == v1 && i2 < i1))
                                 : ((v1 > v2) || (v1 == v2 && i1 < i2));
                    if (sw) { val[i] = v2; val[ixj] = v1; idx[i] = i2; idx[ixj] = i1; }
                }
            }
            __syncthreads();
        }
    }
    if (tid < 1024) {
        idxout[b*1024 + tid] = idx[tid];
        gateout[b*1024 + tid] = val[tid];
    }
}

__global__ __launch_bounds__(256) void gather_kernel(const float* __restrict__ proc,
                                                     const int* __restrict__ idx,
                                                     float* __restrict__ sel) {
    int r = blockIdx.x;
    int b = r >> 10, rr = r & 1023;
    int tok = idx[b*1024 + rr];
    const float4* src = (const float4*)(proc + ((size_t)(b*2048 + tok)) * D_);
    float4* dst = (float4*)(sel + (size_t)r * D_);
    dst[threadIdx.x] = src[threadIdx.x];
    dst[threadIdx.x + 256] = src[threadIdx.x + 256];
}

__global__ __launch_bounds__(256) void copy_kernel(const float* __restrict__ src,
                                                   float* __restrict__ dst, int n4) {
    int i = blockIdx.x * 256 + threadIdx.x;
    if (i < n4) ((float4*)dst)[i] = ((const float4*)src)[i];
}

__global__ __launch_bounds__(256) void scatter_kernel(const float* __restrict__ sel,
                                                      const float* __restrict__ selout,
                                                      const int* __restrict__ idx,
                                                      const float* __restrict__ gate,
                                                      float* __restrict__ outp) {
    int r = blockIdx.x;
    int b = r >> 10, rr = r & 1023;
    int tok = idx[b*1024 + rr];
    float g = gate[b*1024 + rr];
    const float4* s4 = (const float4*)(sel + (size_t)r * D_);
    const float4* o4 = (const float4*)(selout + (size_t)r * D_);
    float4* d4 = (float4*)(outp + ((size_t)(b*2048 + tok)) * D_);
#pragma unroll
    for (int it = 0; it < 2; ++it) {
        int i = threadIdx.x + it * 256;
        float4 a = s4[i], o = o4[i];
        float4 w;
        w.x = a.x + g*(o.x - a.x); w.y = a.y + g*(o.y - a.y);
        w.z = a.z + g*(o.z - a.z); w.w = a.w + g*(o.w - a.w);
        d4[i] = w;
    }
}

extern "C" void kernel_launch(void* const* d_in, const int* in_sizes, int n_in,
                              void* d_out, int out_size, void* d_ws, size_t ws_size,
                              hipStream_t stream) {
    const float* X      = (const float*)d_in[0];
    const float* d1_ln1 = (const float*)d_in[1];
    const float* d1_ln2 = (const float*)d_in[2];
    const float* d1_wq  = (const float*)d_in[3];
    const float* d1_wk  = (const float*)d_in[4];
    const float* d1_wv  = (const float*)d_in[5];
    const float* d1_wo  = (const float*)d_in[6];
    const float* d1_wg  = (const float*)d_in[7];
    const float* d1_wu  = (const float*)d_in[8];
    const float* d1_wd  = (const float*)d_in[9];
    const float* d2_ln1 = (const float*)d_in[10];
    const float* d2_ln2 = (const float*)d_in[11];
    const float* d2_wq  = (const float*)d_in[12];
    const float* d2_wk  = (const float*)d_in[13];
    const float* d2_wv  = (const float*)d_in[14];
    const float* d2_wo  = (const float*)d_in[15];
    const float* d2_wg  = (const float*)d_in[16];
    const float* d2_wu  = (const float*)d_in[17];
    const float* d2_wd  = (const float*)d_in[18];
    const float* p_ln   = (const float*)d_in[19];
    const float* p_wg   = (const float*)d_in[20];
    const float* p_wu   = (const float*)d_in[21];
    const float* p_wd   = (const float*)d_in[22];

    float* out = (float*)d_out;
    float* ws  = (float*)d_ws;

    const size_t BIG = (size_t)NTOK_ * D_;           // 8M f32
    const size_t MEG = 1024 * 1024;

    const size_t NEED_NEW = (128 * MEG + 16384) * 4;  // ~512 MB
    const size_t NEED_OLD = ((5*BIG + (size_t)NTOK_*FF_ + 12288) * 4);

    if (ws_size >= NEED_NEW) {
        float* BUF0 = ws;                 // 8M f32
        float* BUF1 = ws + 8*MEG;         // q
        float* BUF2 = ws + 16*MEG;        // k / h
        float* BUF3 = ws + 24*MEG;        // v / prior_out / sel_out
        float* BUF4 = ws + 32*MEG;        // attnout / sel (+V2)
        float* BUFF = ws + 40*MEG;        // 32M f32 FF
        unsigned short* PWhi  = (unsigned short*)(ws + 72*MEG);
        unsigned short* PWlo  = (unsigned short*)(ws + 80*MEG);
        unsigned short* PAhi  = (unsigned short*)(ws + 88*MEG);
        unsigned short* PAlo  = (unsigned short*)(ws + 92*MEG);
        unsigned short* PFhi  = (unsigned short*)(ws + 96*MEG);
        unsigned short* PFlo  = (unsigned short*)(ws + 112*MEG);
        // attention packed buffers (overlay PF region; disjoint in time)
        unsigned short* U   = (unsigned short*)(ws + 96*MEG);
        const size_t PK = (size_t)NTOK_ * D_;         // 8.39M ushorts
        unsigned short* QHp = U;
        unsigned short* QLp = U + PK;
        unsigned short* KHp = U + 2*PK;
        unsigned short* KLp = U + 3*PK;
        unsigned short* VTH = U + 4*PK;
        unsigned short* VTL = U + 5*PK;
        float* SM   = ws + 128*MEG;
        float* gbuf = SM;
        float* dch  = SM + 4096;
        float* gate = SM + 8192;
        int*   idxb = (int*)(SM + 10240);

        float* PROC = out;                // processed lives directly in out
        const int QKVN = 3 * D_;          // 6144

        // ---- decision decoder layer (bf16x3 GEMMs + bf16x3 MFMA attention) ----
        rms_kernel<<<NTOK_, 256, 0, stream>>>(X, d1_ln1, BUF0);
        splita_kernel<1><<<dim3(64, 32), 256, 0, stream>>>(BUF0, PAhi, PAlo, NTOK_, D_);
        splitw_kernel<1><<<dim3(32, 32), 256, 0, stream>>>(d1_wq, PWhi, PWlo, D_, D_, QKVN, 0);
        splitw_kernel<1><<<dim3(32, 32), 256, 0, stream>>>(d1_wk, PWhi, PWlo, D_, D_, QKVN, D_);
        splitw_kernel<1><<<dim3(32, 32), 256, 0, stream>>>(d1_wv, PWhi, PWlo, D_, D_, QKVN, 2*D_);
        gemm_mfma<3,5><<<dim3(48, 32), 256, 0, stream>>>(PAhi, PAlo, PWhi, PWlo, BUF1, (const float*)BUF2, (unsigned short*)BUF3, nullptr, NTOK_, QKVN, D_);  // Q,K,V
        rope_split_kernel<<<NTOK_, 256, 0, stream>>>(BUF1, QHp, QLp, T_ - 1, SCALE_QK);
        rope_split_kernel<<<NTOK_, 256, 0, stream>>>(BUF2, KHp, KLp, T_ - 1, 1.0f);
        vpack_kernel<<<dim3(T_/64, B_*H_), 256, 0, stream>>>(BUF3, VTH, VTL, T_);
        attn_mfma<<<dim3(T_/64, B_*H_), 256, 0, stream>>>(QHp, QLp, KHp, KLp, VTH, VTL, BUF4, T_);
        splita_kernel<1><<<dim3(64, 32), 256, 0, stream>>>(BUF4, PAhi, PAlo, NTOK_, D_);
        splitw_kernel<1><<<dim3(32, 32), 256, 0, stream>>>(d1_wo, PWhi, PWlo, D_, D_, D_, 0);
        gemm_mfma<3,1><<<dim3(16, 32), 256, 0, stream>>>(PAhi, PAlo, PWhi, PWlo, BUF2, X, nullptr, nullptr, NTOK_, D_, D_);  // h
        rms_kernel<<<NTOK_, 256, 0, stream>>>(BUF2, d1_ln2, BUF0);
        splita_kernel<1><<<dim3(64, 32), 256, 0, stream>>>(BUF0, PAhi, PAlo, NTOK_, D_);
        splitw_kernel<1><<<dim3(128, 32), 256, 0, stream>>>(d1_wg, PWhi, PWlo, D_, FF_, FF_, 0);
        gemm_mfma<3,0><<<dim3(64, 32), 256, 0, stream>>>(PAhi, PAlo, PWhi, PWlo, BUFF, nullptr, nullptr, nullptr, NTOK_, FF_, D_);
        splitw_kernel<1><<<dim3(128, 32), 256, 0, stream>>>(d1_wu, PWhi, PWlo, D_, FF_, FF_, 0);
        gemm_mfma<3,3><<<dim3(64, 32), 256, 0, stream>>>(PAhi, PAlo, PWhi, PWlo, nullptr, BUFF, PFhi, PFlo, NTOK_, FF_, D_);  // silu(wg)*wu -> packed
        splitw_kernel<1><<<dim3(32, 128), 256, 0, stream>>>(d1_wd, PWhi, PWlo, FF_, D_, D_, 0);
        gemm_mfma<3,1><<<dim3(16, 32), 256, 0, stream>>>(PFhi, PFlo, PWhi, PWlo, PROC, BUF2, nullptr, nullptr, NTOK_, D_, FF_); // processed -> out

        // ---- prior network (bf16x3) ----
        rms_kernel<<<NTOK_, 256, 0, stream>>>(X, p_ln, BUF0);
        splita_kernel<1><<<dim3(64, 32), 256, 0, stream>>>(BUF0, PAhi, PAlo, NTOK_, D_);
        splitw_kernel<1><<<dim3(16, 32), 256, 0, stream>>>(p_wg, PWhi, PWlo, D_, PFF_, PFF_, 0);
        gemm_mfma<3,0><<<dim3(8, 32), 256, 0, stream>>>(PAhi, PAlo, PWhi, PWlo, BUFF, nullptr, nullptr, nullptr, NTOK_, PFF_, D_);
        splitw_kernel<1><<<dim3(16, 32), 256, 0, stream>>>(p_wu, PWhi, PWlo, D_, PFF_, PFF_, 0);
        gemm_mfma<3,3><<<dim3(8, 32), 256, 0, stream>>>(PAhi, PAlo, PWhi, PWlo, nullptr, BUFF, PFhi, PFlo, NTOK_, PFF_, D_);
        splitw_kernel<1><<<dim3(32, 16), 256, 0, stream>>>(p_wd, PWhi, PWlo, PFF_, D_, D_, 0);
        gemm_mfma<3,0><<<dim3(16, 32), 256, 0, stream>>>(PFhi, PFlo, PWhi, PWlo, BUF3, nullptr, nullptr, nullptr, NTOK_, D_, PFF_); // prior_out

        // ---- router + loss + top-k + gather ----
        router_kernel<<<NTOK_, 256, 0, stream>>>(X, PROC, BUF3, gbuf, dch, out + 8388609);
        loss_kernel<<<1, 1024, 0, stream>>>(dch, out + 8388608);
        topk_kernel<<<B_, 1024, 0, stream>>>(gbuf, idxb, gate);
        gather_kernel<<<NSEL_, 256, 0, stream>>>(PROC, idxb, BUF4);   // sel

        // ---- dynamic decoder layer (bf16 NP=1 GEMMs, x3 MFMA attention) ----
        float* V2 = BUF4 + (size_t)NSEL_ * D_;
        rms_kernel<<<NSEL_, 256, 0, stream>>>(BUF4, d2_ln1, BUF0);
        splita_kernel<0><<<dim3(32, 32), 256, 0, stream>>>(BUF0, PAhi, PAlo, NSEL_, D_);
        splitw_kernel<0><<<dim3(32, 32), 256, 0, stream>>>(d2_wq, PWhi, PWlo, D_, D_, QKVN, 0);
        splitw_kernel<0><<<dim3(32, 32), 256, 0, stream>>>(d2_wk, PWhi, PWlo, D_, D_, QKVN, D_);
        splitw_kernel<0><<<dim3(32, 32), 256, 0, stream>>>(d2_wv, PWhi, PWlo, D_, D_, QKVN, 2*D_);
        gemm_mfma<1,5><<<dim3(48, 16), 256, 0, stream>>>(PAhi, PAlo, PWhi, PWlo, BUF2, (const float*)BUF3, (unsigned short*)V2, nullptr, NSEL_, QKVN, D_);  // q2,k2,v2
        rope_split_kernel<<<NSEL_, 256, 0, stream>>>(BUF2, QHp, QLp, T2_ - 1, SCALE_QK);
        rope_split_kernel<<<NSEL_, 256, 0, stream>>>(BUF3, KHp, KLp, T2_ - 1, 1.0f);
        vpack_kernel<<<dim3(T2_/64, B_*H_), 256, 0, stream>>>(V2, VTH, VTL, T2_);
        attn_mfma<<<dim3(T2_/64, B_*H_), 256, 0, stream>>>(QHp, QLp, KHp, KLp, VTH, VTL, BUF0, T2_);
        splita_kernel<0><<<dim3(32, 32), 256, 0, stream>>>(BUF0, PAhi, PAlo, NSEL_, D_);
        splitw_kernel<0><<<dim3(32, 32), 256, 0, stream>>>(d2_wo, PWhi, PWlo, D_, D_, D_, 0);
        gemm_mfma<1,1><<<dim3(16, 16), 256, 0, stream>>>(PAhi, PAlo, PWhi, PWlo, BUF2, BUF4, nullptr, nullptr, NSEL_, D_, D_); // h2
        rms_kernel<<<NSEL_, 256, 0, stream>>>(BUF2, d2_ln2, BUF0);
        splita_kernel<0><<<dim3(32, 32), 256, 0, stream>>>(BUF0, PAhi, PAlo, NSEL_, D_);
        splitw_kernel<0><<<dim3(128, 32), 256, 0, stream>>>(d2_wg, PWhi, PWlo, D_, FF_, FF_, 0);
        gemm_mfma<1,0><<<dim3(64, 16), 256, 0, stream>>>(PAhi, PAlo, PWhi, PWlo, BUFF, nullptr, nullptr, nullptr, NSEL_, FF_, D_);
        splitw_kernel<0><<<dim3(128, 32), 256, 0, stream>>>(d2_wu, PWhi, PWlo, D_, FF_, FF_, 0);
        gemm_mfma<1,4><<<dim3(64, 16), 256, 0, stream>>>(PAhi, PAlo, PWhi, PWlo, nullptr, BUFF, PFhi, nullptr, NSEL_, FF_, D_);  // silu(wg)*wu -> packed hi
        splitw_kernel<0><<<dim3(32, 128), 256, 0, stream>>>(d2_wd, PWhi, PWlo, FF_, D_, D_, 0);
        gemm_mfma<1,1><<<dim3(16, 16), 256, 0, stream>>>(PFhi, PFlo, PWhi, PWlo, BUF3, BUF2, nullptr, nullptr, NSEL_, D_, FF_); // sel_out

        scatter_kernel<<<NSEL_, 256, 0, stream>>>(BUF4, BUF3, idxb, gate, out);
        return;
    }

    if (ws_size < NEED_OLD) return;

    // ================= fallback: f32 path =================
    float* BUF0 = ws;
    float* BUF1 = ws + BIG;
    float* BUF2 = ws + 2*BIG;
    float* BUF3 = ws + 3*BIG;
    float* BUF4 = ws + 4*BIG;
    float* BUFF = ws + 5*BIG;
    float* SM   = BUFF + (size_t)NTOK_ * FF_;
    float* gbuf = SM;
    float* dch  = SM + 4096;
    float* gate = SM + 8192;
    int*   idxb = (int*)(SM + 10240);

    rms_kernel<<<NTOK_, 256, 0, stream>>>(X, d1_ln1, BUF0);
    gemm128<0><<<dim3(16, 32), 256, 0, stream>>>(BUF0, d1_wq, BUF1, nullptr, NTOK_, D_, D_);
    gemm128<0><<<dim3(16, 32), 256, 0, stream>>>(BUF0, d1_wk, BUF2, nullptr, NTOK_, D_, D_);
    gemm128<0><<<dim3(16, 32), 256, 0, stream>>>(BUF0, d1_wv, BUF3, nullptr, NTOK_, D_, D_);
    rope_kernel<<<NTOK_*4, 256, 0, stream>>>(BUF1, NTOK_, T_);
    rope_kernel<<<NTOK_*4, 256, 0, stream>>>(BUF2, NTOK_, T_);
    attn_kernel<<<dim3(T_/32, B_*H_), 256, 0, stream>>>(BUF1, BUF2, BUF3, BUF4, T_);
    gemm128<1><<<dim3(16, 32), 256, 0, stream>>>(BUF4, d1_wo, BUF2, X, NTOK_, D_, D_);
    rms_kernel<<<NTOK_, 256, 0, stream>>>(BUF2, d1_ln2, BUF0);
    gemm128<0><<<dim3(64, 32), 256, 0, stream>>>(BUF0, d1_wg, BUFF, nullptr, NTOK_, FF_, D_);
    gemm128<2><<<dim3(64, 32), 256, 0, stream>>>(BUF0, d1_wu, BUFF, BUFF, NTOK_, FF_, D_);
    gemm128<1><<<dim3(16, 32), 256, 0, stream>>>(BUFF, d1_wd, BUF1, BUF2, NTOK_, D_, FF_);

    rms_kernel<<<NTOK_, 256, 0, stream>>>(X, p_ln, BUF0);
    gemm128<0><<<dim3(8, 32), 256, 0, stream>>>(BUF0, p_wg, BUF4, nullptr, NTOK_, PFF_, D_);
    gemm128<2><<<dim3(8, 32), 256, 0, stream>>>(BUF0, p_wu, BUF4, BUF4, NTOK_, PFF_, D_);
    gemm128<0><<<dim3(16, 32), 256, 0, stream>>>(BUF4, p_wd, BUF3, nullptr, NTOK_, D_, PFF_);

    router_kernel<<<NTOK_, 256, 0, stream>>>(X, BUF1, BUF3, gbuf, dch, out + 8388609);
    loss_kernel<<<1, 1024, 0, stream>>>(dch, out + 8388608);
    topk_kernel<<<B_, 1024, 0, stream>>>(gbuf, idxb, gate);
    gather_kernel<<<NSEL_, 256, 0, stream>>>(BUF1, idxb, BUF4);

    float* V2 = BUF4 + (size_t)NSEL_ * D_;
    rms_kernel<<<NSEL_, 256, 0, stream>>>(BUF4, d2_ln1, BUF0);
    gemm128<0><<<dim3(16, 16), 256, 0, stream>>>(BUF0, d2_wq, BUF2, nullptr, NSEL_, D_, D_);
    gemm128<0><<<dim3(16, 16), 256, 0, stream>>>(BUF0, d2_wk, BUF3, nullptr, NSEL_, D_, D_);
    gemm128<0><<<dim3(16, 16), 256, 0, stream>>>(BUF0, d2_wv, V2, nullptr, NSEL_, D_, D_);
    rope_kernel<<<NSEL_*4, 256, 0, stream>>>(BUF2, NSEL_, T2_);
    rope_kernel<<<NSEL_*4, 256, 0, stream>>>(BUF3, NSEL_, T2_);
    attn_kernel<<<dim3(T2_/32, B_*H_), 256, 0, stream>>>(BUF2, BUF3, V2, BUF0, T2_);
    gemm128<1><<<dim3(16, 16), 256, 0, stream>>>(BUF0, d2_wo, BUF2, BUF4, NSEL_, D_, D_);
    rms_kernel<<<NSEL_, 256, 0, stream>>>(BUF2, d2_ln2, BUF0);
    gemm128<0><<<dim3(64, 16), 256, 0, stream>>>(BUF0, d2_wg, BUFF, nullptr, NSEL_, FF_, D_);
    gemm128<2><<<dim3(64, 16), 256, 0, stream>>>(BUF0, d2_wu, BUFF, BUFF, NSEL_, FF_, D_);
    gemm128<1><<<dim3(16, 16), 256, 0, stream>>>(BUFF, d2_wd, BUF3, BUF2, NSEL_, D_, FF_);

    copy_kernel<<<8192, 256, 0, stream>>>(BUF1, out, (int)(BIG / 4));
    scatter_kernel<<<NSEL_, 256, 0, stream>>>(BUF4, BUF3, idxb, gate, out);
}

// Round 16
// 2955.326 us; speedup vs baseline: 1.0965x; 1.0069x over previous
//
#include <hip/hip_runtime.h>
#include <math.h>

#define D_    2048
#define H_    16
#define DH_   128
#define FF_   8192
#define PFF_  1024
#define B_    2
#define T_    2048
#define NTOK_ 4096
#define T2_   1024
#define NSEL_ 2048
#define EPS_  1e-6f
#define SCALE_QK 0.08838834764831845f  // 1/sqrt(128)

typedef __attribute__((ext_vector_type(8))) short bf16x8;
typedef __attribute__((ext_vector_type(4))) float f32x4;
typedef __attribute__((ext_vector_type(8))) unsigned short ushort8;

__device__ __forceinline__ float silu_f(float x) {
    return x / (1.0f + expf(-x));
}

__device__ __forceinline__ unsigned short bf16_rne(float f) {
    unsigned int u = __float_as_uint(f);
    unsigned int r = (u + 0x7fffu + ((u >> 16) & 1u)) >> 16;
    return (unsigned short)r;
}
__device__ __forceinline__ float bf16_tof(unsigned short h) {
    return __uint_as_float(((unsigned int)h) << 16);
}

// ---------------- RMSNorm: one block per row ----------------
__global__ __launch_bounds__(256) void rms_kernel(const float* __restrict__ x,
                                                  const float* __restrict__ w,
                                                  float* __restrict__ out) {
    int row = blockIdx.x;
    int tid = threadIdx.x;
    const float4* xr = (const float4*)(x + (size_t)row * D_);
    float4* orow = (float4*)(out + (size_t)row * D_);
    const float4* w4 = (const float4*)w;
    float4 v0 = xr[tid], v1 = xr[tid + 256];
    float s = v0.x*v0.x + v0.y*v0.y + v0.z*v0.z + v0.w*v0.w
            + v1.x*v1.x + v1.y*v1.y + v1.z*v1.z + v1.w*v1.w;
    __shared__ float red[256];
    red[tid] = s; __syncthreads();
    for (int off = 128; off > 0; off >>= 1) {
        if (tid < off) red[tid] += red[tid + off];
        __syncthreads();
    }
    float r = 1.0f / sqrtf(red[0] * (1.0f/2048.0f) + EPS_);
    float4 w0 = w4[tid], w1 = w4[tid + 256];
    float4 o0, o1;
    o0.x = v0.x*r*w0.x; o0.y = v0.y*r*w0.y; o0.z = v0.z*r*w0.z; o0.w = v0.w*r*w0.w;
    o1.x = v1.x*r*w1.x; o1.y = v1.y*r*w1.y; o1.z = v1.z*r*w1.z; o1.w = v1.w*r*w1.w;
    orow[tid] = o0; orow[tid + 256] = o1;
}

// ---------------- weight transpose+split: W[K][Wld] f32 -> Phi(/Plo)[k/8][PN][8] @ colOff ----------------
template<int WLO>
__global__ __launch_bounds__(256) void splitw_kernel(const float* __restrict__ W,
                                                     unsigned short* __restrict__ phi,
                                                     unsigned short* __restrict__ plo,
                                                     int K, int Wld, int PN, int colOff) {
    __shared__ float Ts[64][68];
    int n0 = blockIdx.x << 6, k0 = blockIdx.y << 6;
    int tid = threadIdx.x;
#pragma unroll
    for (int it = 0; it < 4; ++it) {
        int idx = tid + (it << 8);
        int kr = idx >> 4, c4 = idx & 15;
        float4 v = *(const float4*)(W + (size_t)(k0 + kr) * Wld + n0 + (c4 << 2));
        Ts[kr][c4*4+0] = v.x; Ts[kr][c4*4+1] = v.y; Ts[kr][c4*4+2] = v.z; Ts[kr][c4*4+3] = v.w;
    }
    __syncthreads();
#pragma unroll
    for (int h = 0; h < 2; ++h) {
        int c = tid + (h << 8);              // [0,512)
        int kc = c >> 6, n = c & 63;
        ushort8 hi, lo;
#pragma unroll
        for (int q = 0; q < 8; ++q) {
            float v = Ts[kc*8 + q][n];
            unsigned short hb = bf16_rne(v);
            hi[q] = hb;
            if (WLO) lo[q] = bf16_rne(v - bf16_tof(hb));
        }
        size_t off = ((size_t)((k0 >> 3) + kc) * PN + (colOff + n0 + n)) * 8;
        *(ushort8*)(phi + off) = hi;
        if (WLO) *(ushort8*)(plo + off) = lo;
    }
}

// ---------------- activation split: A[M][K] f32 -> Phi(/Plo)[k/8][m][8] bf16 ----------------
template<int WLO>
__global__ __launch_bounds__(256) void splita_kernel(const float* __restrict__ A,
                                                     unsigned short* __restrict__ phi,
                                                     unsigned short* __restrict__ plo,
                                                     int M, int K) {
    __shared__ float Ts[64][68];
    int m0 = blockIdx.x << 6, k0 = blockIdx.y << 6;
    int tid = threadIdx.x;
#pragma unroll
    for (int it = 0; it < 4; ++it) {
        int idx = tid + (it << 8);
        int mr = idx >> 4, c4 = idx & 15;
        float4 v = *(const float4*)(A + (size_t)(m0 + mr) * K + k0 + (c4 << 2));
        Ts[mr][c4*4+0] = v.x; Ts[mr][c4*4+1] = v.y; Ts[mr][c4*4+2] = v.z; Ts[mr][c4*4+3] = v.w;
    }
    __syncthreads();
#pragma unroll
    for (int h = 0; h < 2; ++h) {
        int c = tid + (h << 8);
        int kc = c >> 6, m = c & 63;
        const float* src = &Ts[m][kc << 3];
        ushort8 hi, lo;
#pragma unroll
        for (int q = 0; q < 8; ++q) {
            float v = src[q];
            unsigned short hb = bf16_rne(v);
            hi[q] = hb;
            if (WLO) lo[q] = bf16_rne(v - bf16_tof(hb));
        }
        size_t off = ((size_t)((k0 >> 3) + kc) * M + (m0 + m)) * 8;
        *(ushort8*)(phi + off) = hi;
        if (WLO) *(ushort8*)(plo + off) = lo;
    }
}

// ---------------- bf16(x3) MFMA GEMM, 128x128 tile, BK=32, 2-phase dbuf, 16x16x32 MFMA ----------------
// Block map: XCD-chunked + GRP-column decode (GRP B-panels L2-resident, A shared by group).
// EPI 0: C=acc ; 1: C=acc+Rg ; 2: C=silu(Rg)*acc ;
// EPI 3: packed hi/lo panels = silu(Rg)*acc ; EPI 4: packed hi panel only ;
// EPI 5: segmented QKV output — col segment s=col>>11 routes to {C, Rg, Cph} as f32 [M][2048].
__device__ __forceinline__ void stage_panel(unsigned short* lds,
                                            const unsigned short* __restrict__ panel,
                                            int ktile, int R, int brow, int tid) {
#pragma unroll
    for (int h = 0; h < 2; ++h) {
        int c = tid + (h << 8);              // [0,512): kc = c>>7, row = c&127
        const unsigned short* g = panel + ((size_t)((ktile << 2) + (c >> 7)) * R + (brow + (c & 127))) * 8;
        __builtin_amdgcn_global_load_lds((const __attribute__((address_space(1))) void*)g,
                                         (__attribute__((address_space(3))) void*)(lds + (size_t)c * 8),
                                         16, 0, 0);
    }
}

template<int NP, int EPI, int GRP>
__global__ __launch_bounds__(256) void gemm_mfma(const unsigned short* __restrict__ pah,
                                                 const unsigned short* __restrict__ pal,
                                                 const unsigned short* __restrict__ pbh,
                                                 const unsigned short* __restrict__ pbl,
                                                 float* __restrict__ C,
                                                 const float* __restrict__ Rg,
                                                 unsigned short* __restrict__ Cph,
                                                 unsigned short* __restrict__ Cpl,
                                                 int M, int N, int K) {
    constexpr int NPAN = (NP == 3) ? 2 : 1;
    __shared__ __align__(16) unsigned short As[2][NPAN][4][128][8];
    __shared__ __align__(16) unsigned short Bs[2][NPAN][4][128][8];
    const int tid = threadIdx.x;
    // T1: XCD-aware bijective block swizzle (all grids here have nwg % 8 == 0)
    int nwg = gridDim.x * gridDim.y;
    int wg = blockIdx.y * gridDim.x + blockIdx.x;
    if ((nwg & 7) == 0) {
        int cpx = nwg >> 3;
        wg = (wg & 7) * cpx + (wg >> 3);
    }
    // GRP-column decode: consecutive wg cycle through GRP adjacent bn-columns
    // at the same bm-row; each streamed A panel serves the group while the
    // GRP B panels stay L2-resident. Bijective for gridDim.x % GRP == 0.
    const int gyG = gridDim.y * GRP;
    const int sc = wg / gyG;
    const int wr = wg - sc * gyG;
    const int bxs = sc * GRP + (wr % GRP), bys = wr / GRP;
    const int bm = bys << 7, bn = bxs << 7;
    const int lane = tid & 63, wave = tid >> 6;
    const int wm = (wave >> 1) << 6, wn = (wave & 1) << 6;
    const int fr = lane & 15, fk = lane >> 4;

    // EPI5: per-block segment routing (bn covers 128 cols, segment = bn>>11 uniform)
    float* Cseg = C;
    if (EPI == 5) {
        int seg = bn >> 11;
        Cseg = (seg == 0) ? C : ((seg == 1) ? (float*)Rg : (float*)Cph);
    }

    f32x4 acc[4][4];
#pragma unroll
    for (int i = 0; i < 4; ++i)
#pragma unroll
        for (int j = 0; j < 4; ++j) acc[i][j] = (f32x4)0.0f;

    const int nkt = K >> 5;

    // prologue stage tile 0 into buf 0
    stage_panel(&As[0][0][0][0][0], pah, 0, M, bm, tid);
    if (NP == 3) stage_panel(&As[0][1][0][0][0], pal, 0, M, bm, tid);
    stage_panel(&Bs[0][0][0][0][0], pbh, 0, N, bn, tid);
    if (NP == 3) stage_panel(&Bs[0][1][0][0][0], pbl, 0, N, bn, tid);
    __syncthreads();

    int cur = 0;
    for (int kt = 0; kt < nkt; ++kt) {
        // T3 minimum 2-phase: issue next-tile stage BEFORE ds_read+MFMA
        if (kt + 1 < nkt) {
            int nxt = cur ^ 1;
            stage_panel(&As[nxt][0][0][0][0], pah, kt + 1, M, bm, tid);
            if (NP == 3) stage_panel(&As[nxt][1][0][0][0], pal, kt + 1, M, bm, tid);
            stage_panel(&Bs[nxt][0][0][0][0], pbh, kt + 1, N, bn, tid);
            if (NP == 3) stage_panel(&Bs[nxt][1][0][0][0], pbl, kt + 1, N, bn, tid);
        }

        bf16x8 ah[4], bh[4], al[4], bl[4];
#pragma unroll
        for (int i = 0; i < 4; ++i) {
            ah[i] = *(const bf16x8*)&As[cur][0][fk][wm + (i << 4) + fr][0];
            if (NP == 3) al[i] = *(const bf16x8*)&As[cur][NPAN-1][fk][wm + (i << 4) + fr][0];
        }
#pragma unroll
        for (int j = 0; j < 4; ++j) {
            bh[j] = *(const bf16x8*)&Bs[cur][0][fk][wn + (j << 4) + fr][0];
            if (NP == 3) bl[j] = *(const bf16x8*)&Bs[cur][NPAN-1][fk][wn + (j << 4) + fr][0];
        }
#pragma unroll
        for (int i = 0; i < 4; ++i)
#pragma unroll
            for (int j = 0; j < 4; ++j) {
                acc[i][j] = __builtin_amdgcn_mfma_f32_16x16x32_bf16(ah[i], bh[j], acc[i][j], 0, 0, 0);
                if (NP == 3) {
                    acc[i][j] = __builtin_amdgcn_mfma_f32_16x16x32_bf16(ah[i], bl[j], acc[i][j], 0, 0, 0);
                    acc[i][j] = __builtin_amdgcn_mfma_f32_16x16x32_bf16(al[i], bh[j], acc[i][j], 0, 0, 0);
                }
            }
        __syncthreads();   // next-tile stage complete; buf[cur] reads all drained
        cur ^= 1;
    }

#pragma unroll
    for (int i = 0; i < 4; ++i) {
        int row0 = bm + wm + (i << 4) + (fk << 2);
#pragma unroll
        for (int j = 0; j < 4; ++j) {
            int col = bn + wn + (j << 4) + fr;
#pragma unroll
            for (int r = 0; r < 4; ++r) {
                int row = row0 + r;
                size_t off = (size_t)row * N + col;
                float v = acc[i][j][r];
                if (EPI == 0) {
                    C[off] = v;
                } else if (EPI == 1) {
                    C[off] = v + Rg[off];
                } else if (EPI == 2) {
                    C[off] = silu_f(Rg[off]) * v;
                } else if (EPI == 5) {
                    Cseg[(size_t)row * 2048 + (col & 2047)] = v;
                } else {
                    v = silu_f(Rg[off]) * v;
                    unsigned short hb = bf16_rne(v);
                    size_t poff = (((size_t)(col >> 3)) * M + row) * 8 + (col & 7);
                    Cph[poff] = hb;
                    if (EPI == 3) Cpl[poff] = bf16_rne(v - bf16_tof(hb));
                }
            }
        }
    }
}

// ---------------- fused RoPE + scale + hi/lo split ----------------
__global__ __launch_bounds__(256) void rope_split_kernel(const float* __restrict__ X,
                                                         unsigned short* __restrict__ xh,
                                                         unsigned short* __restrict__ xl,
                                                         int seqmask, float scale) {
    int tok = blockIdx.x;
    int tid = threadIdx.x;
    int h = tid >> 4, d0 = (tid & 15) << 3;
    int pos = tok & seqmask;
    const float* src = X + (size_t)tok * D_ + h * DH_;
    bool lohalf = d0 < 64;
    float out[8];
#pragma unroll
    for (int q = 0; q < 8; ++q) {
        int d = d0 + q;
        int i = lohalf ? d : (d - 64);
        float e = (float)(2 * i) * (1.0f / 128.0f);
        float inv = 1.0f / powf(10000.0f, e);
        float ang = (float)pos * inv;
        float c = cosf(ang), s = sinf(ang);
        float x1 = src[i], x2 = src[i + 64];
        out[q] = lohalf ? (x1 * c - x2 * s) : (x2 * c + x1 * s);
    }
    ushort8 hi, lo;
#pragma unroll
    for (int q = 0; q < 8; ++q) {
        float v = out[q] * scale;
        unsigned short hb = bf16_rne(v);
        hi[q] = hb;
        lo[q] = bf16_rne(v - bf16_tof(hb));
    }
    size_t off = (size_t)tok * D_ + h * DH_ + d0;
    *(ushort8*)(xh + off) = hi;
    *(ushort8*)(xl + off) = lo;
}

// ---------------- V pack: f32 [b*T+t][2048] -> Vt[bh][T/8][128][8] bf16 hi/lo ----------------
__global__ __launch_bounds__(256) void vpack_kernel(const float* __restrict__ V,
                                                    unsigned short* __restrict__ vth,
                                                    unsigned short* __restrict__ vtl,
                                                    int T) {
    __shared__ float Ts[64][132];
    int kt = blockIdx.x, bh = blockIdx.y;
    int b = bh >> 4, h = bh & 15;
    int tid = threadIdx.x;
#pragma unroll
    for (int it = 0; it < 8; ++it) {
        int idx = tid + (it << 8);          // [0,2048)
        int r = idx >> 5, c4 = idx & 31;    // r in [0,64), c4 in [0,32)
        float4 v = *(const float4*)(V + ((size_t)(b * T + kt * 64 + r)) * D_ + h * DH_ + (c4 << 2));
        Ts[r][c4*4+0] = v.x; Ts[r][c4*4+1] = v.y; Ts[r][c4*4+2] = v.z; Ts[r][c4*4+3] = v.w;
    }
    __syncthreads();
    size_t obase = ((size_t)bh * (size_t)(T >> 3) + (size_t)kt * 8) * 1024;
#pragma unroll
    for (int it = 0; it < 4; ++it) {
        int c = tid + (it << 8);            // [0,1024): kc = c>>7, dh = c&127
        int kc = c >> 7, dh = c & 127;
        ushort8 hi, lo;
#pragma unroll
        for (int q = 0; q < 8; ++q) {
            float v = Ts[kc * 8 + q][dh];
            unsigned short hb = bf16_rne(v);
            hi[q] = hb;
            lo[q] = bf16_rne(v - bf16_tof(hb));
        }
        *(ushort8*)(vth + obase + (size_t)kc * 1024 + dh * 8) = hi;
        *(ushort8*)(vtl + obase + (size_t)kc * 1024 + dh * 8) = lo;
    }
}

// ---------------- bf16x3 MFMA flash attention ----------------
// grid: (T/64, B_*H_), block 256 (4 waves, each owns 16 q-rows)
__global__ __launch_bounds__(256) void attn_mfma(const unsigned short* __restrict__ QH,
                                                 const unsigned short* __restrict__ QL,
                                                 const unsigned short* __restrict__ KH,
                                                 const unsigned short* __restrict__ KL,
                                                 const unsigned short* __restrict__ VTH,
                                                 const unsigned short* __restrict__ VTL,
                                                 float* __restrict__ O, int T) {
    __shared__ __align__(16) unsigned short KV[16384];
    __shared__ __align__(16) float Ss[4096];
    __shared__ __align__(16) float mrow[64];
    __shared__ __align__(16) float lrow[64];
    __shared__ __align__(16) float crow[64];

    const int tid = threadIdx.x;
    const int qt = blockIdx.x, bh = blockIdx.y;
    const int b = bh >> 4, h = bh & 15;
    const int lane = tid & 63, w = tid >> 6;
    const int fr = lane & 15, fk = lane >> 4;
    const size_t tok0 = (size_t)b * T;

    char* lds_kv = (char*)&KV[0];
    char* lds_sp = (char*)&Ss[0];

    bf16x8 qfh[4], qfl[4];
    {
        const size_t qoff = (tok0 + (size_t)qt * 64 + w * 16 + fr) * D_ + h * DH_ + fk * 8;
#pragma unroll
        for (int ks = 0; ks < 4; ++ks) {
            qfh[ks] = *(const bf16x8*)(QH + qoff + ks * 32);
            qfl[ks] = *(const bf16x8*)(QL + qoff + ks * 32);
        }
    }
    if (tid < 64) { mrow[tid] = -1e30f; lrow[tid] = 0.f; }

    f32x4 acc[8];
#pragma unroll
    for (int nt = 0; nt < 8; ++nt) acc[nt] = (f32x4)0.f;

    const int srow = tid >> 2, sslot = tid & 3;
    const size_t vbase = (size_t)bh * (size_t)(T >> 3) * 1024;

    for (int kt = 0; kt <= qt; ++kt) {
        __syncthreads();
#pragma unroll
        for (int it = 0; it < 4; ++it) {
            int c = tid + (it << 8);
            int t = c >> 4;
            int sp = (c & 15) ^ (t & 7);
            size_t goff = (tok0 + (size_t)kt * 64 + t) * D_ + h * DH_ + sp * 8;
            __builtin_amdgcn_global_load_lds((const __attribute__((address_space(1))) void*)(KH + goff),
                (__attribute__((address_space(3))) void*)(lds_kv + c * 16), 16, 0, 0);
            __builtin_amdgcn_global_load_lds((const __attribute__((address_space(1))) void*)(KL + goff),
                (__attribute__((address_space(3))) void*)(lds_kv + 16384 + c * 16), 16, 0, 0);
        }
        __syncthreads();
        {
            f32x4 s[4];
#pragma unroll
            for (int nt = 0; nt < 4; ++nt) s[nt] = (f32x4)0.f;
#pragma unroll
            for (int ks = 0; ks < 4; ++ks) {
#pragma unroll
                for (int nt = 0; nt < 4; ++nt) {
                    int n = nt * 16 + fr;
                    int offk = (n * 256 + ks * 64 + fk * 16) ^ ((n & 7) << 4);
                    bf16x8 kfh = *(const bf16x8*)(lds_kv + offk);
                    bf16x8 kfl = *(const bf16x8*)(lds_kv + 16384 + offk);
                    s[nt] = __builtin_amdgcn_mfma_f32_16x16x32_bf16(qfh[ks], kfh, s[nt], 0, 0, 0);
                    s[nt] = __builtin_amdgcn_mfma_f32_16x16x32_bf16(qfh[ks], kfl, s[nt], 0, 0, 0);
                    s[nt] = __builtin_amdgcn_mfma_f32_16x16x32_bf16(qfl[ks], kfh, s[nt], 0, 0, 0);
                }
            }
#pragma unroll
            for (int nt = 0; nt < 4; ++nt)
#pragma unroll
                for (int r = 0; r < 4; ++r) {
                    int row = w * 16 + fk * 4 + r;
                    int col = nt * 16 + fr;
                    *(float*)(lds_sp + ((row * 256 + col * 4) ^ ((row & 7) << 4))) = s[nt][r];
                }
        }
        __syncthreads();
#pragma unroll
        for (int it = 0; it < 4; ++it) {
            int c = tid + (it << 8);
            size_t goff = vbase + (size_t)kt * 8192 + (size_t)c * 8;
            __builtin_amdgcn_global_load_lds((const __attribute__((address_space(1))) void*)(VTH + goff),
                (__attribute__((address_space(3))) void*)(lds_kv + c * 16), 16, 0, 0);
            __builtin_amdgcn_global_load_lds((const __attribute__((address_space(1))) void*)(VTL + goff),
                (__attribute__((address_space(3))) void*)(lds_kv + 16384 + c * 16), 16, 0, 0);
        }
        float p[16];
        float newm, psum, cr, oldl;
        {
            float tmax = -1e30f;
            int colbase = sslot * 16;
#pragma unroll
            for (int q4 = 0; q4 < 4; ++q4) {
                f32x4 sv = *(const f32x4*)(lds_sp + ((srow * 256 + sslot * 64 + q4 * 16) ^ ((srow & 7) << 4)));
#pragma unroll
                for (int e = 0; e < 4; ++e) {
                    float v = sv[e];
                    if (kt == qt && (colbase + q4 * 4 + e) > srow) v = -1e30f;
                    p[q4 * 4 + e] = v;
                    tmax = fmaxf(tmax, v);
                }
            }
            tmax = fmaxf(tmax, __shfl_xor(tmax, 1, 64));
            tmax = fmaxf(tmax, __shfl_xor(tmax, 2, 64));
            float oldm = mrow[srow];
            oldl = lrow[srow];
            newm = fmaxf(oldm, tmax);
            psum = 0.f;
#pragma unroll
            for (int e = 0; e < 16; ++e) { p[e] = expf(p[e] - newm); psum += p[e]; }
            psum += __shfl_xor(psum, 1, 64);
            psum += __shfl_xor(psum, 2, 64);
            cr = expf(oldm - newm);
        }
        __syncthreads();
        {
            ushort8 h0, h1, l0, l1;
#pragma unroll
            for (int e = 0; e < 8; ++e) {
                unsigned short hb = bf16_rne(p[e]);
                h0[e] = hb; l0[e] = bf16_rne(p[e] - bf16_tof(hb));
                unsigned short hb2 = bf16_rne(p[8 + e]);
                h1[e] = hb2; l1[e] = bf16_rne(p[8 + e] - bf16_tof(hb2));
            }
            int base = srow * 128 + sslot * 32;
            int swz = (srow & 7) << 4;
            *(ushort8*)(lds_sp + (base ^ swz)) = h0;
            *(ushort8*)(lds_sp + ((base + 16) ^ swz)) = h1;
            *(ushort8*)(lds_sp + 8192 + (base ^ swz)) = l0;
            *(ushort8*)(lds_sp + 8192 + ((base + 16) ^ swz)) = l1;
            if (sslot == 0) { mrow[srow] = newm; lrow[srow] = oldl * cr + psum; crow[srow] = cr; }
        }
        __syncthreads();
        {
            f32x4 crv = *(const f32x4*)&crow[w * 16 + fk * 4];
#pragma unroll
            for (int nt = 0; nt < 8; ++nt)
#pragma unroll
                for (int r = 0; r < 4; ++r) acc[nt][r] *= crv[r];
            int m = w * 16 + fr;
#pragma unroll
            for (int ks = 0; ks < 2; ++ks) {
                int offp = (m * 128 + ks * 64 + fk * 16) ^ ((m & 7) << 4);
                bf16x8 pfh = *(const bf16x8*)(lds_sp + offp);
                bf16x8 pfl = *(const bf16x8*)(lds_sp + 8192 + offp);
#pragma unroll
                for (int nt = 0; nt < 8; ++nt) {
                    int offv = (ks * 4 + fk) * 2048 + (nt * 16 + fr) * 16;
                    bf16x8 vfh = *(const bf16x8*)(lds_kv + offv);
                    bf16x8 vfl = *(const bf16x8*)(lds_kv + 16384 + offv);
                    acc[nt] = __builtin_amdgcn_mfma_f32_16x16x32_bf16(pfh, vfh, acc[nt], 0, 0, 0);
                    acc[nt] = __builtin_amdgcn_mfma_f32_16x16x32_bf16(pfh, vfl, acc[nt], 0, 0, 0);
                    acc[nt] = __builtin_amdgcn_mfma_f32_16x16x32_bf16(pfl, vfh, acc[nt], 0, 0, 0);
                }
            }
        }
    }
    __syncthreads();
    {
        f32x4 lv = *(const f32x4*)&lrow[w * 16 + fk * 4];
        float* orow = O + (tok0 + (size_t)qt * 64 + w * 16 + fk * 4) * D_ + h * DH_;
#pragma unroll
        for (int r = 0; r < 4; ++r) {
            float inv = 1.0f / lv[r];
#pragma unroll
            for (int nt = 0; nt < 8; ++nt)
                orow[(size_t)r * D_ + nt * 16 + fr] = acc[nt][r] * inv;
        }
    }
}

// ---------------- f32 GEMM (fallback path) ----------------
template<int EPI>
__global__ __launch_bounds__(256) void gemm128(const float* __restrict__ A,
                                               const float* __restrict__ Bm,
                                               float* __restrict__ C,
                                               const float* __restrict__ Rg,
                                               int M, int N, int K) {
    __shared__ float Ast[16][132];
    __shared__ float Bs[16][132];
    int bm = blockIdx.y << 7, bn = blockIdx.x << 7;
    int tid = threadIdx.x;
    int ty = tid >> 4, tx = tid & 15;
    float acc[8][8];
#pragma unroll
    for (int i = 0; i < 8; ++i)
#pragma unroll
        for (int j = 0; j < 8; ++j) acc[i][j] = 0.f;

    for (int k0 = 0; k0 < K; k0 += 16) {
#pragma unroll
        for (int it = 0; it < 2; ++it) {
            int idx = tid + (it << 8);
            int ar = idx >> 2, ac = idx & 3;
            float4 av = *(const float4*)(A + (size_t)(bm + ar) * K + k0 + (ac << 2));
            Ast[ac*4+0][ar] = av.x; Ast[ac*4+1][ar] = av.y;
            Ast[ac*4+2][ar] = av.z; Ast[ac*4+3][ar] = av.w;
            int br = idx >> 5, bc = idx & 31;
            float4 bv = *(const float4*)(Bm + (size_t)(k0 + br) * N + bn + (bc << 2));
            *(float4*)&Bs[br][bc << 2] = bv;
        }
        __syncthreads();
#pragma unroll
        for (int kk = 0; kk < 16; ++kk) {
            float a[8], b[8];
            *(float4*)&a[0] = *(const float4*)&Ast[kk][ty*4];
            *(float4*)&a[4] = *(const float4*)&Ast[kk][64 + ty*4];
            *(float4*)&b[0] = *(const float4*)&Bs[kk][tx*4];
            *(float4*)&b[4] = *(const float4*)&Bs[kk][64 + tx*4];
#pragma unroll
            for (int i = 0; i < 8; ++i)
#pragma unroll
                for (int j = 0; j < 8; ++j)
                    acc[i][j] += a[i] * b[j];
        }
        __syncthreads();
    }
#pragma unroll
    for (int i = 0; i < 8; ++i) {
        int row = bm + ((i < 4) ? (ty*4 + i) : (64 + ty*4 + (i - 4)));
#pragma unroll
        for (int half = 0; half < 2; ++half) {
            int col = bn + half*64 + tx*4;
            size_t off = (size_t)row * N + col;
            const float* ap = &acc[i][half*4];
            float4 r;
            if (EPI == 0) {
                r.x = ap[0]; r.y = ap[1]; r.z = ap[2]; r.w = ap[3];
            } else if (EPI == 1) {
                float4 rv = *(const float4*)(Rg + off);
                r.x = ap[0] + rv.x; r.y = ap[1] + rv.y;
                r.z = ap[2] + rv.z; r.w = ap[3] + rv.w;
            } else {
                float4 gv = *(const float4*)(Rg + off);
                r.x = silu_f(gv.x) * ap[0]; r.y = silu_f(gv.y) * ap[1];
                r.z = silu_f(gv.z) * ap[2]; r.w = silu_f(gv.w) * ap[3];
            }
            *(float4*)(C + off) = r;
        }
    }
}

// ---------------- RoPE in place (f32, fallback) ----------------
__global__ __launch_bounds__(256) void rope_kernel(float* __restrict__ q, int nrows, int seqlen) {
    int gid = blockIdx.x * 256 + threadIdx.x;
    int tok = gid >> 10;
    if (tok >= nrows) return;
    int rest = gid & 1023;
    int h = rest >> 6, i = rest & 63;
    int pos = tok % seqlen;
    float e = (float)(2 * i) * (1.0f / 128.0f);
    float inv = 1.0f / powf(10000.0f, e);
    float ang = (float)pos * inv;
    float c = cosf(ang), s = sinf(ang);
    size_t base = (size_t)tok * D_ + h * 128 + i;
    float x1 = q[base], x2 = q[base + 64];
    q[base]      = x1 * c - x2 * s;
    q[base + 64] = x2 * c + x1 * s;
}

// ---------------- flash attention f32 (fallback) ----------------
__global__ __launch_bounds__(256) void attn_kernel(const float* __restrict__ Q,
                                                   const float* __restrict__ K,
                                                   const float* __restrict__ V,
                                                   float* __restrict__ O,
                                                   int T) {
    int qt = blockIdx.x;
    int bh = blockIdx.y;
    int b = bh >> 4, h = bh & 15;
    int tid = threadIdx.x;

    __shared__ float4 Qs[32][32];
    __shared__ float4 KVs[64][32];
    __shared__ float Sst[32][65];
    __shared__ float mrow[32], lrow[32], crow[32];

    const size_t headoff = (size_t)h * DH_;
    const size_t bbase = (size_t)b * T * D_;

#pragma unroll
    for (int i = 0; i < 4; ++i) {
        int idx = tid + i * 256;
        int r = idx >> 5, ch = idx & 31;
        const float4* src = (const float4*)(Q + bbase + (size_t)(qt*32 + r) * D_ + headoff);
        Qs[r][ch ^ ((r >> 2) & 7)] = src[ch];
    }
    if (tid < 32) { mrow[tid] = -1e30f; lrow[tid] = 0.f; }

    int ty16 = tid >> 4, tx16 = tid & 15;
    int r8 = tid >> 3, q8 = tid & 7;
    float o[2][8];
#pragma unroll
    for (int i = 0; i < 2; ++i)
#pragma unroll
        for (int j = 0; j < 8; ++j) o[i][j] = 0.f;

    int ktmax = (qt * 32 + 31) >> 6;
    for (int kt = 0; kt <= ktmax; ++kt) {
        __syncthreads();
#pragma unroll
        for (int i = 0; i < 8; ++i) {
            int idx = tid + i * 256;
            int r = idx >> 5, ch = idx & 31;
            const float4* src = (const float4*)(K + bbase + (size_t)(kt*64 + r) * D_ + headoff);
            KVs[r][ch ^ ((r >> 2) & 7)] = src[ch];
        }
        __syncthreads();
        {
            float s[2][4];
#pragma unroll
            for (int i = 0; i < 2; ++i)
#pragma unroll
                for (int j = 0; j < 4; ++j) s[i][j] = 0.f;
#pragma unroll
            for (int ch = 0; ch < 32; ++ch) {
                float4 qv[2], kv[4];
#pragma unroll
                for (int i = 0; i < 2; ++i) { int r = ty16*2 + i; qv[i] = Qs[r][ch ^ ((r >> 2) & 7)]; }
#pragma unroll
                for (int j = 0; j < 4; ++j) { int c = tx16*4 + j; kv[j] = KVs[c][ch ^ ((c >> 2) & 7)]; }
#pragma unroll
                for (int i = 0; i < 2; ++i)
#pragma unroll
                    for (int j = 0; j < 4; ++j)
                        s[i][j] += qv[i].x*kv[j].x + qv[i].y*kv[j].y + qv[i].z*kv[j].z + qv[i].w*kv[j].w;
            }
#pragma unroll
            for (int i = 0; i < 2; ++i) {
                int grow = qt*32 + ty16*2 + i;
#pragma unroll
                for (int j = 0; j < 4; ++j) {
                    int gcol = kt*64 + tx16*4 + j;
                    float sv = s[i][j] * SCALE_QK;
                    if (gcol > grow) sv = -1e30f;
                    Sst[ty16*2 + i][tx16*4 + j] = sv;
                }
            }
        }
        __syncthreads();
#pragma unroll
        for (int i = 0; i < 8; ++i) {
            int idx = tid + i * 256;
            int r = idx >> 5, ch = idx & 31;
            const float4* src = (const float4*)(V + bbase + (size_t)(kt*64 + r) * D_ + headoff);
            KVs[r][ch ^ ((r >> 2) & 7)] = src[ch];
        }
        {
            float pv[8];
            float tmax = -1e30f;
#pragma unroll
            for (int c = 0; c < 8; ++c) { pv[c] = Sst[r8][q8*8 + c]; tmax = fmaxf(tmax, pv[c]); }
#pragma unroll
            for (int m = 1; m < 8; m <<= 1) tmax = fmaxf(tmax, __shfl_xor(tmax, m, 64));
            float oldm = mrow[r8];
            float newm = fmaxf(oldm, tmax);
            float psum = 0.f;
#pragma unroll
            for (int c = 0; c < 8; ++c) {
                float p = expf(pv[c] - newm);
                Sst[r8][q8*8 + c] = p;
                psum += p;
            }
#pragma unroll
            for (int m = 1; m < 8; m <<= 1) psum += __shfl_xor(psum, m, 64);
            if (q8 == 0) {
                float crv = expf(oldm - newm);
                crow[r8] = crv;
                lrow[r8] = lrow[r8] * crv + psum;
                mrow[r8] = newm;
            }
        }
        __syncthreads();
        {
            float crv[2];
#pragma unroll
            for (int i = 0; i < 2; ++i) {
                crv[i] = crow[ty16*2 + i];
#pragma unroll
                for (int j = 0; j < 8; ++j) o[i][j] *= crv[i];
            }
#pragma unroll
            for (int kc = 0; kc < 64; ++kc) {
                int swz = (kc >> 2) & 7;
                float4 v0 = KVs[kc][tx16 ^ swz];
                float4 v1 = KVs[kc][(16 + tx16) ^ swz];
#pragma unroll
                for (int i = 0; i < 2; ++i) {
                    float p = Sst[ty16*2 + i][kc];
                    o[i][0] += p*v0.x; o[i][1] += p*v0.y; o[i][2] += p*v0.z; o[i][3] += p*v0.w;
                    o[i][4] += p*v1.x; o[i][5] += p*v1.y; o[i][6] += p*v1.z; o[i][7] += p*v1.w;
                }
            }
        }
    }
#pragma unroll
    for (int i = 0; i < 2; ++i) {
        int r = ty16*2 + i;
        float inv = 1.0f / lrow[r];
        float4 a, bb;
        a.x = o[i][0]*inv; a.y = o[i][1]*inv; a.z = o[i][2]*inv; a.w = o[i][3]*inv;
        bb.x = o[i][4]*inv; bb.y = o[i][5]*inv; bb.z = o[i][6]*inv; bb.w = o[i][7]*inv;
        float* dst = O + bbase + (size_t)(qt*32 + r) * D_ + headoff;
        ((float4*)dst)[tx16] = a;
        ((float4*)dst)[16 + tx16] = bb;
    }
}

// ---------------- router / loss / topk / gather / copy / scatter ----------------
__global__ __launch_bounds__(256) void router_kernel(const float* __restrict__ x,
                                                     const float* __restrict__ proc,
                                                     const float* __restrict__ prior,
                                                     float* __restrict__ gbuf,
                                                     float* __restrict__ dchbuf,
                                                     float* __restrict__ gout) {
    int row = blockIdx.x, tid = threadIdx.x;
    const float4* x4 = (const float4*)(x + (size_t)row * D_);
    const float4* p4 = (const float4*)(proc + (size_t)row * D_);
    const float4* r4 = (const float4*)(prior + (size_t)row * D_);
    float sst = 0.f, sch = 0.f;
#pragma unroll
    for (int it = 0; it < 2; ++it) {
        int i = tid + it * 256;
        float4 xv = x4[i], pv = p4[i], rv = r4[i];
        float a0 = pv.x - xv.x, a1 = pv.y - xv.y, a2 = pv.z - xv.z, a3 = pv.w - xv.w;
        sst += a0*a0 + a1*a1 + a2*a2 + a3*a3;
        float d0 = a0 - rv.x, d1 = a1 - rv.y, d2 = a2 - rv.z, d3 = a3 - rv.w;
        sch += d0*d0 + d1*d1 + d2*d2 + d3*d3;
    }
    __shared__ float rs[256], rc[256];
    rs[tid] = sst; rc[tid] = sch; __syncthreads();
    for (int off = 128; off > 0; off >>= 1) {
        if (tid < off) { rs[tid] += rs[tid + off]; rc[tid] += rc[tid + off]; }
        __syncthreads();
    }
    if (tid == 0) {
        float Dst = rs[0] * (1.0f/2048.0f);
        float Dch = rc[0] * (1.0f/2048.0f);
        float g = 1.0f / (1.0f + expf(-(Dch - Dst)));
        gbuf[row] = g; dchbuf[row] = Dch; gout[row] = g;
    }
}

__global__ __launch_bounds__(1024) void loss_kernel(const float* __restrict__ dch, float* __restrict__ out) {
    __shared__ float red[1024];
    int tid = threadIdx.x;
    red[tid] = dch[tid] + dch[tid + 1024] + dch[tid + 2048] + dch[tid + 3072];
    __syncthreads();
    for (int off = 512; off > 0; off >>= 1) {
        if (tid < off) red[tid] += red[tid + off];
        __syncthreads();
    }
    if (tid == 0) out[0] = red[0] * (1.0f / 4096.0f);
}

__global__ __launch_bounds__(1024) void topk_kernel(const float* __restrict__ gbuf,
                                                    int* __restrict__ idxout,
                                                    float* __restrict__ gateout) {
    int b = blockIdx.x, tid = threadIdx.x;
    __shared__ float val[2048];
    __shared__ int idx[2048];
    val[tid] = gbuf[b*2048 + tid];           idx[tid] = tid;
    val[tid + 1024] = gbuf[b*2048 + tid + 1024]; idx[tid + 1024] = tid + 1024;
    __syncthreads();
    for (int kk = 2; kk <= 2048; kk <<= 1) {
        for (int j = kk >> 1; j > 0; j >>= 1) {
            for (int i = tid; i < 2048; i += 1024) {
                int ixj = i ^ j;
                if (ixj > i) {
                    bool up = ((i & kk) == 0);
                    float v1 = val[i], v2 = val[ixj];
                    int i1 = idx[i], i2 = idx[ixj];
                    bool sw = up ? ((v2 > v1) || (v2 == v1 && i2 < i1))
                                 : ((v1 > v2) || (v1 == v2 && i1 < i2));
                    if (sw) { val[i] = v2; val[ixj] = v1; idx[i] = i2; idx[ixj] = i1; }
                }
            }
            __syncthreads();
        }
    }
    if (tid < 1024) {
        idxout[b*1024 + tid] = idx[tid];
        gateout[b*1024 + tid] = val[tid];
    }
}

__global__ __launch_bounds__(256) void gather_kernel(const float* __restrict__ proc,
                                                     const int* __restrict__ idx,
                                                     float* __restrict__ sel) {
    int r = blockIdx.x;
    int b = r >> 10, rr = r & 1023;
    int tok = idx[b*1024 + rr];
    const float4* src = (const float4*)(proc + ((size_t)(b*2048 + tok)) * D_);
    float4* dst = (float4*)(sel + (size_t)r * D_);
    dst[threadIdx.x] = src[threadIdx.x];
    dst[threadIdx.x + 256] = src[threadIdx.x + 256];
}

__global__ __launch_bounds__(256) void copy_kernel(const float* __restrict__ src,
                                                   float* __restrict__ dst, int n4) {
    int i = blockIdx.x * 256 + threadIdx.x;
    if (i < n4) ((float4*)dst)[i] = ((const float4*)src)[i];
}

__global__ __launch_bounds__(256) void scatter_kernel(const float* __restrict__ sel,
                                                      const float* __restrict__ selout,
                                                      const int* __restrict__ idx,
                                                      const float* __restrict__ gate,
                                                      float* __restrict__ outp) {
    int r = blockIdx.x;
    int b = r >> 10, rr = r & 1023;
    int tok = idx[b*1024 + rr];
    float g = gate[b*1024 + rr];
    const float4* s4 = (const float4*)(sel + (size_t)r * D_);
    const float4* o4 = (const float4*)(selout + (size_t)r * D_);
    float4* d4 = (float4*)(outp + ((size_t)(b*2048 + tok)) * D_);
#pragma unroll
    for (int it = 0; it < 2; ++it) {
        int i = threadIdx.x + it * 256;
        float4 a = s4[i], o = o4[i];
        float4 w;
        w.x = a.x + g*(o.x - a.x); w.y = a.y + g*(o.y - a.y);
        w.z = a.z + g*(o.z - a.z); w.w = a.w + g*(o.w - a.w);
        d4[i] = w;
    }
}

extern "C" void kernel_launch(void* const* d_in, const int* in_sizes, int n_in,
                              void* d_out, int out_size, void* d_ws, size_t ws_size,
                              hipStream_t stream) {
    const float* X      = (const float*)d_in[0];
    const float* d1_ln1 = (const float*)d_in[1];
    const float* d1_ln2 = (const float*)d_in[2];
    const float* d1_wq  = (const float*)d_in[3];
    const float* d1_wk  = (const float*)d_in[4];
    const float* d1_wv  = (const float*)d_in[5];
    const float* d1_wo  = (const float*)d_in[6];
    const float* d1_wg  = (const float*)d_in[7];
    const float* d1_wu  = (const float*)d_in[8];
    const float* d1_wd  = (const float*)d_in[9];
    const float* d2_ln1 = (const float*)d_in[10];
    const float* d2_ln2 = (const float*)d_in[11];
    const float* d2_wq  = (const float*)d_in[12];
    const float* d2_wk  = (const float*)d_in[13];
    const float* d2_wv  = (const float*)d_in[14];
    const float* d2_wo  = (const float*)d_in[15];
    const float* d2_wg  = (const float*)d_in[16];
    const float* d2_wu  = (const float*)d_in[17];
    const float* d2_wd  = (const float*)d_in[18];
    const float* p_ln   = (const float*)d_in[19];
    const float* p_wg   = (const float*)d_in[20];
    const float* p_wu   = (const float*)d_in[21];
    const float* p_wd   = (const float*)d_in[22];

    float* out = (float*)d_out;
    float* ws  = (float*)d_ws;

    const size_t BIG = (size_t)NTOK_ * D_;           // 8M f32
    const size_t MEG = 1024 * 1024;

    const size_t NEED_NEW = (128 * MEG + 16384) * 4;  // ~512 MB
    const size_t NEED_OLD = ((5*BIG + (size_t)NTOK_*FF_ + 12288) * 4);

    if (ws_size >= NEED_NEW) {
        float* BUF0 = ws;                 // 8M f32
        float* BUF1 = ws + 8*MEG;         // q
        float* BUF2 = ws + 16*MEG;        // k / h
        float* BUF3 = ws + 24*MEG;        // v / prior_out / sel_out
        float* BUF4 = ws + 32*MEG;        // attnout / sel (+V2)
        float* BUFF = ws + 40*MEG;        // 32M f32 FF
        unsigned short* PWhi  = (unsigned short*)(ws + 72*MEG);
        unsigned short* PWlo  = (unsigned short*)(ws + 80*MEG);
        unsigned short* PAhi  = (unsigned short*)(ws + 88*MEG);
        unsigned short* PAlo  = (unsigned short*)(ws + 92*MEG);
        unsigned short* PFhi  = (unsigned short*)(ws + 96*MEG);
        unsigned short* PFlo  = (unsigned short*)(ws + 112*MEG);
        // attention packed buffers (overlay PF region; disjoint in time)
        unsigned short* U   = (unsigned short*)(ws + 96*MEG);
        const size_t PK = (size_t)NTOK_ * D_;         // 8.39M ushorts
        unsigned short* QHp = U;
        unsigned short* QLp = U + PK;
        unsigned short* KHp = U + 2*PK;
        unsigned short* KLp = U + 3*PK;
        unsigned short* VTH = U + 4*PK;
        unsigned short* VTL = U + 5*PK;
        float* SM   = ws + 128*MEG;
        float* gbuf = SM;
        float* dch  = SM + 4096;
        float* gate = SM + 8192;
        int*   idxb = (int*)(SM + 10240);

        float* PROC = out;                // processed lives directly in out
        const int QKVN = 3 * D_;          // 6144

        // ---- decision decoder layer (bf16x3 GEMMs + bf16x3 MFMA attention) ----
        rms_kernel<<<NTOK_, 256, 0, stream>>>(X, d1_ln1, BUF0);
        splita_kernel<1><<<dim3(64, 32), 256, 0, stream>>>(BUF0, PAhi, PAlo, NTOK_, D_);
        splitw_kernel<1><<<dim3(32, 32), 256, 0, stream>>>(d1_wq, PWhi, PWlo, D_, D_, QKVN, 0);
        splitw_kernel<1><<<dim3(32, 32), 256, 0, stream>>>(d1_wk, PWhi, PWlo, D_, D_, QKVN, D_);
        splitw_kernel<1><<<dim3(32, 32), 256, 0, stream>>>(d1_wv, PWhi, PWlo, D_, D_, QKVN, 2*D_);
        gemm_mfma<3,5,4><<<dim3(48, 32), 256, 0, stream>>>(PAhi, PAlo, PWhi, PWlo, BUF1, (const float*)BUF2, (unsigned short*)BUF3, nullptr, NTOK_, QKVN, D_);  // Q,K,V
        rope_split_kernel<<<NTOK_, 256, 0, stream>>>(BUF1, QHp, QLp, T_ - 1, SCALE_QK);
        rope_split_kernel<<<NTOK_, 256, 0, stream>>>(BUF2, KHp, KLp, T_ - 1, 1.0f);
        vpack_kernel<<<dim3(T_/64, B_*H_), 256, 0, stream>>>(BUF3, VTH, VTL, T_);
        attn_mfma<<<dim3(T_/64, B_*H_), 256, 0, stream>>>(QHp, QLp, KHp, KLp, VTH, VTL, BUF4, T_);
        splita_kernel<1><<<dim3(64, 32), 256, 0, stream>>>(BUF4, PAhi, PAlo, NTOK_, D_);
        splitw_kernel<1><<<dim3(32, 32), 256, 0, stream>>>(d1_wo, PWhi, PWlo, D_, D_, D_, 0);
        gemm_mfma<3,1,4><<<dim3(16, 32), 256, 0, stream>>>(PAhi, PAlo, PWhi, PWlo, BUF2, X, nullptr, nullptr, NTOK_, D_, D_);  // h
        rms_kernel<<<NTOK_, 256, 0, stream>>>(BUF2, d1_ln2, BUF0);
        splita_kernel<1><<<dim3(64, 32), 256, 0, stream>>>(BUF0, PAhi, PAlo, NTOK_, D_);
        splitw_kernel<1><<<dim3(128, 32), 256, 0, stream>>>(d1_wg, PWhi, PWlo, D_, FF_, FF_, 0);
        gemm_mfma<3,0,4><<<dim3(64, 32), 256, 0, stream>>>(PAhi, PAlo, PWhi, PWlo, BUFF, nullptr, nullptr, nullptr, NTOK_, FF_, D_);
        splitw_kernel<1><<<dim3(128, 32), 256, 0, stream>>>(d1_wu, PWhi, PWlo, D_, FF_, FF_, 0);
        gemm_mfma<3,3,4><<<dim3(64, 32), 256, 0, stream>>>(PAhi, PAlo, PWhi, PWlo, nullptr, BUFF, PFhi, PFlo, NTOK_, FF_, D_);  // silu(wg)*wu -> packed
        splitw_kernel<1><<<dim3(32, 128), 256, 0, stream>>>(d1_wd, PWhi, PWlo, FF_, D_, D_, 0);
        gemm_mfma<3,1,2><<<dim3(16, 32), 256, 0, stream>>>(PFhi, PFlo, PWhi, PWlo, PROC, BUF2, nullptr, nullptr, NTOK_, D_, FF_); // processed -> out

        // ---- prior network (bf16x3) ----
        rms_kernel<<<NTOK_, 256, 0, stream>>>(X, p_ln, BUF0);
        splita_kernel<1><<<dim3(64, 32), 256, 0, stream>>>(BUF0, PAhi, PAlo, NTOK_, D_);
        splitw_kernel<1><<<dim3(16, 32), 256, 0, stream>>>(p_wg, PWhi, PWlo, D_, PFF_, PFF_, 0);
        gemm_mfma<3,0,4><<<dim3(8, 32), 256, 0, stream>>>(PAhi, PAlo, PWhi, PWlo, BUFF, nullptr, nullptr, nullptr, NTOK_, PFF_, D_);
        splitw_kernel<1><<<dim3(16, 32), 256, 0, stream>>>(p_wu, PWhi, PWlo, D_, PFF_, PFF_, 0);
        gemm_mfma<3,3,4><<<dim3(8, 32), 256, 0, stream>>>(PAhi, PAlo, PWhi, PWlo, nullptr, BUFF, PFhi, PFlo, NTOK_, PFF_, D_);
        splitw_kernel<1><<<dim3(32, 16), 256, 0, stream>>>(p_wd, PWhi, PWlo, PFF_, D_, D_, 0);
        gemm_mfma<3,0,4><<<dim3(16, 32), 256, 0, stream>>>(PFhi, PFlo, PWhi, PWlo, BUF3, nullptr, nullptr, nullptr, NTOK_, D_, PFF_); // prior_out

        // ---- router + loss + top-k + gather ----
        router_kernel<<<NTOK_, 256, 0, stream>>>(X, PROC, BUF3, gbuf, dch, out + 8388609);
        loss_kernel<<<1, 1024, 0, stream>>>(dch, out + 8388608);
        topk_kernel<<<B_, 1024, 0, stream>>>(gbuf, idxb, gate);
        gather_kernel<<<NSEL_, 256, 0, stream>>>(PROC, idxb, BUF4);   // sel

        // ---- dynamic decoder layer (bf16 NP=1 GEMMs, x3 MFMA attention) ----
        float* V2 = BUF4 + (size_t)NSEL_ * D_;
        rms_kernel<<<NSEL_, 256, 0, stream>>>(BUF4, d2_ln1, BUF0);
        splita_kernel<0><<<dim3(32, 32), 256, 0, stream>>>(BUF0, PAhi, PAlo, NSEL_, D_);
        splitw_kernel<0><<<dim3(32, 32), 256, 0, stream>>>(d2_wq, PWhi, PWlo, D_, D_, QKVN, 0);
        splitw_kernel<0><<<dim3(32, 32), 256, 0, stream>>>(d2_wk, PWhi, PWlo, D_, D_, QKVN, D_);
        splitw_kernel<0><<<dim3(32, 32), 256, 0, stream>>>(d2_wv, PWhi, PWlo, D_, D_, QKVN, 2*D_);
        gemm_mfma<1,5,4><<<dim3(48, 16), 256, 0, stream>>>(PAhi, PAlo, PWhi, PWlo, BUF2, (const float*)BUF3, (unsigned short*)V2, nullptr, NSEL_, QKVN, D_);  // q2,k2,v2
        rope_split_kernel<<<NSEL_, 256, 0, stream>>>(BUF2, QHp, QLp, T2_ - 1, SCALE_QK);
        rope_split_kernel<<<NSEL_, 256, 0, stream>>>(BUF3, KHp, KLp, T2_ - 1, 1.0f);
        vpack_kernel<<<dim3(T2_/64, B_*H_), 256, 0, stream>>>(V2, VTH, VTL, T2_);
        attn_mfma<<<dim3(T2_/64, B_*H_), 256, 0, stream>>>(QHp, QLp, KHp, KLp, VTH, VTL, BUF0, T2_);
        splita_kernel<0><<<dim3(32, 32), 256, 0, stream>>>(BUF0, PAhi, PAlo, NSEL_, D_);
        splitw_kernel<0><<<dim3(32, 32), 256, 0, stream>>>(d2_wo, PWhi, PWlo, D_, D_, D_, 0);
        gemm_mfma<1,1,4><<<dim3(16, 16), 256, 0, stream>>>(PAhi, PAlo, PWhi, PWlo, BUF2, BUF4, nullptr, nullptr, NSEL_, D_, D_); // h2
        rms_kernel<<<NSEL_, 256, 0, stream>>>(BUF2, d2_ln2, BUF0);
        splita_kernel<0><<<dim3(32, 32), 256, 0, stream>>>(BUF0, PAhi, PAlo, NSEL_, D_);
        splitw_kernel<0><<<dim3(128, 32), 256, 0, stream>>>(d2_wg, PWhi, PWlo, D_, FF_, FF_, 0);
        gemm_mfma<1,0,4><<<dim3(64, 16), 256, 0, stream>>>(PAhi, PAlo, PWhi, PWlo, BUFF, nullptr, nullptr, nullptr, NSEL_, FF_, D_);
        splitw_kernel<0><<<dim3(128, 32), 256, 0, stream>>>(d2_wu, PWhi, PWlo, D_, FF_, FF_, 0);
        gemm_mfma<1,4,4><<<dim3(64, 16), 256, 0, stream>>>(PAhi, PAlo, PWhi, PWlo, nullptr, BUFF, PFhi, nullptr, NSEL_, FF_, D_);  // silu(wg)*wu -> packed hi
        splitw_kernel<0><<<dim3(32, 128), 256, 0, stream>>>(d2_wd, PWhi, PWlo, FF_, D_, D_, 0);
        gemm_mfma<1,1,2><<<dim3(16, 16), 256, 0, stream>>>(PFhi, PFlo, PWhi, PWlo, BUF3, BUF2, nullptr, nullptr, NSEL_, D_, FF_); // sel_out

        scatter_kernel<<<NSEL_, 256, 0, stream>>>(BUF4, BUF3, idxb, gate, out);
        return;
    }

    if (ws_size < NEED_OLD) return;

    // ================= fallback: f32 path =================
    float* BUF0 = ws;
    float* BUF1 = ws + BIG;
    float* BUF2 = ws + 2*BIG;
    float* BUF3 = ws + 3*BIG;
    float* BUF4 = ws + 4*BIG;
    float* BUFF = ws + 5*BIG;
    float* SM   = BUFF + (size_t)NTOK_ * FF_;
    float* gbuf = SM;
    float* dch  = SM + 4096;
    float* gate = SM + 8192;
    int*   idxb = (int*)(SM + 10240);

    rms_kernel<<<NTOK_, 256, 0, stream>>>(X, d1_ln1, BUF0);
    gemm128<0><<<dim3(16, 32), 256, 0, stream>>>(BUF0, d1_wq, BUF1, nullptr, NTOK_, D_, D_);
    gemm128<0><<<dim3(16, 32), 256, 0, stream>>>(BUF0, d1_wk, BUF2, nullptr, NTOK_, D_, D_);
    gemm128<0><<<dim3(16, 32), 256, 0, stream>>>(BUF0, d1_wv, BUF3, nullptr, NTOK_, D_, D_);
    rope_kernel<<<NTOK_*4, 256, 0, stream>>>(BUF1, NTOK_, T_);
    rope_kernel<<<NTOK_*4, 256, 0, stream>>>(BUF2, NTOK_, T_);
    attn_kernel<<<dim3(T_/32, B_*H_), 256, 0, stream>>>(BUF1, BUF2, BUF3, BUF4, T_);
    gemm128<1><<<dim3(16, 32), 256, 0, stream>>>(BUF4, d1_wo, BUF2, X, NTOK_, D_, D_);
    rms_kernel<<<NTOK_, 256, 0, stream>>>(BUF2, d1_ln2, BUF0);
    gemm128<0><<<dim3(64, 32), 256, 0, stream>>>(BUF0, d1_wg, BUFF, nullptr, NTOK_, FF_, D_);
    gemm128<2><<<dim3(64, 32), 256, 0, stream>>>(BUF0, d1_wu, BUFF, BUFF, NTOK_, FF_, D_);
    gemm128<1><<<dim3(16, 32), 256, 0, stream>>>(BUFF, d1_wd, BUF1, BUF2, NTOK_, D_, FF_);

    rms_kernel<<<NTOK_, 256, 0, stream>>>(X, p_ln, BUF0);
    gemm128<0><<<dim3(8, 32), 256, 0, stream>>>(BUF0, p_wg, BUF4, nullptr, NTOK_, PFF_, D_);
    gemm128<2><<<dim3(8, 32), 256, 0, stream>>>(BUF0, p_wu, BUF4, BUF4, NTOK_, PFF_, D_);
    gemm128<0><<<dim3(16, 32), 256, 0, stream>>>(BUF4, p_wd, BUF3, nullptr, NTOK_, D_, PFF_);

    router_kernel<<<NTOK_, 256, 0, stream>>>(X, BUF1, BUF3, gbuf, dch, out + 8388609);
    loss_kernel<<<1, 1024, 0, stream>>>(dch, out + 8388608);
    topk_kernel<<<B_, 1024, 0, stream>>>(gbuf, idxb, gate);
    gather_kernel<<<NSEL_, 256, 0, stream>>>(BUF1, idxb, BUF4);

    float* V2 = BUF4 + (size_t)NSEL_ * D_;
    rms_kernel<<<NSEL_, 256, 0, stream>>>(BUF4, d2_ln1, BUF0);
    gemm128<0><<<dim3(16, 16), 256, 0, stream>>>(BUF0, d2_wq, BUF2, nullptr, NSEL_, D_, D_);
    gemm128<0><<<dim3(16, 16), 256, 0, stream>>>(BUF0, d2_wk, BUF3, nullptr, NSEL_, D_, D_);
    gemm128<0><<<dim3(16, 16), 256, 0, stream>>>(BUF0, d2_wv, V2, nullptr, NSEL_, D_, D_);
    rope_kernel<<<NSEL_*4, 256, 0, stream>>>(BUF2, NSEL_, T2_);
    rope_kernel<<<NSEL_*4, 256, 0, stream>>>(BUF3, NSEL_, T2_);
    attn_kernel<<<dim3(T2_/32, B_*H_), 256, 0, stream>>>(BUF2, BUF3, V2, BUF0, T2_);
    gemm128<1><<<dim3(16, 16), 256, 0, stream>>>(BUF0, d2_wo, BUF2, BUF4, NSEL_, D_, D_);
    rms_kernel<<<NSEL_, 256, 0, stream>>>(BUF2, d2_ln2, BUF0);
    gemm128<0><<<dim3(64, 16), 256, 0, stream>>>(BUF0, d2_wg, BUFF, nullptr, NSEL_, FF_, D_);
    gemm128<2><<<dim3(64, 16), 256, 0, stream>>>(BUF0, d2_wu, BUFF, BUFF, NSEL_, FF_, D_);
    gemm128<1><<<dim3(16, 16), 256, 0, stream>>>(BUFF, d2_wd, BUF3, BUF2, NSEL_, D_, FF_);

    copy_kernel<<<8192, 256, 0, stream>>>(BUF1, out, (int)(BIG / 4));
    scatter_kernel<<<NSEL_, 256, 0, stream>>>(BUF4, BUF3, idxb, gate, out);
}